// Round 7
// baseline (2480.571 us; speedup 1.0000x reference)
//
#include <hip/hip_runtime.h>
#include <math.h>
#include <stdint.h>
#include <limits.h>

#define NN 100000
#define NE 1600000
#define HH 64
#define THF 0.7f
#define ATTTH 0.2f
#define EPSF 1e-5f
#define SCAN_B ((NN + 255) / 256)   // 391
#define EM2CAP 1000000

typedef unsigned long long u64;

// ---------------- setup: histogram, degree, scans, CSR fill ----------------

__global__ void hist_k(const int* __restrict__ dst, const int* __restrict__ mask,
                       int* __restrict__ cnt_all, int* __restrict__ cnt_mask) {
    int e = blockIdx.x * 256 + threadIdx.x;
    if (e >= NE) return;
    int d = dst[e];
    atomicAdd(&cnt_all[d], 1);          // integer atomics: value-deterministic
    if (mask[e]) atomicAdd(&cnt_mask[d], 1);
}

__global__ void deg_inv_k(const int* __restrict__ cnt, float* __restrict__ dis,
                          float* __restrict__ d2i) {
    int i = blockIdx.x * 256 + threadIdx.x;
    if (i < NN) {
        float deg = (float)(cnt[i] + 1);   // +1 self loop
        dis[i] = 1.0f / sqrtf(deg);
        d2i[i] = 1.0f / deg;
    }
}

__global__ void scan1_k(const int* __restrict__ counts, int* __restrict__ rp,
                        int* __restrict__ bsum) {
    __shared__ int ls[256];
    int i = blockIdx.x * 256 + threadIdx.x;
    int v = (i < NN) ? counts[i] : 0;
    ls[threadIdx.x] = v;
    __syncthreads();
    for (int off = 1; off < 256; off <<= 1) {
        int t = (threadIdx.x >= off) ? ls[threadIdx.x - off] : 0;
        __syncthreads();
        ls[threadIdx.x] += t;
        __syncthreads();
    }
    if (i < NN) rp[i] = ls[threadIdx.x] - v;
    if (threadIdx.x == 255) bsum[blockIdx.x] = ls[255];
}

__global__ void scan2_k(int* __restrict__ bsum, int* __restrict__ rp) {
    int acc = 0;
    for (int b = 0; b < SCAN_B; b++) { int t = bsum[b]; bsum[b] = acc; acc += t; }
    rp[NN] = acc;
}

__global__ void scan3_k(int* __restrict__ rp, const int* __restrict__ bsum) {
    int i = blockIdx.x * 256 + threadIdx.x;
    if (i < NN) rp[i] += bsum[blockIdx.x];
}

// fills both CSRs; also records original edge index as sort key
__global__ void csr_fill_k(const int* __restrict__ src, const int* __restrict__ dst,
                           const int* __restrict__ mask,
                           const float* __restrict__ dis1, const float* __restrict__ dis2m,
                           const int* __restrict__ rp1, const int* __restrict__ rp2,
                           int* __restrict__ cur1, int* __restrict__ cur2,
                           int2* __restrict__ em1, int2* __restrict__ em2,
                           int* __restrict__ key1, int* __restrict__ key2) {
    int e = blockIdx.x * 256 + threadIdx.x;
    if (e >= NE) return;
    int s = src[e], d = dst[e];
    float n1 = dis1[s] * dis1[d];
    int p1 = rp1[d] + atomicAdd(&cur1[d], 1);
    em1[p1] = make_int2(s, __float_as_int(n1));
    key1[p1] = e;
    if (mask[e]) {
        float n2 = dis2m[s] * dis2m[d];
        int p2 = rp2[d] + atomicAdd(&cur2[d], 1);
        em2[p2] = make_int2(s, __float_as_int(n2));
        key2[p2] = e;
    }
}

// sort each dst segment by original edge index -> run-invariant layout,
// and per-dst ascending-e order (matches np.add.at accumulation order).
__global__ __launch_bounds__(256) void seg_sort_k(int2* __restrict__ em,
                                                  int* __restrict__ key,
                                                  const int* __restrict__ rp) {
    __shared__ int skey[4][512];
    __shared__ int2 spl[4][512];
    int tid = threadIdx.x, lane = tid & 63, w = tid >> 6;
    int n = blockIdx.x * 4 + w;
    int beg = rp[n], end = rp[n + 1];
    int L = end - beg;
    if (L <= 1) return;
    if (L <= 64) {
        // all reads before any write; keys (edge indices) are distinct
        int k = INT_MAX; int2 pl = make_int2(0, 0);
        if (lane < L) { k = key[beg + lane]; pl = em[beg + lane]; }
        for (int r = 0; r < L; r++) {
            int mn = k;
#pragma unroll
            for (int off = 32; off > 0; off >>= 1)
                mn = min(mn, __shfl_xor(mn, off, 64));
            if (k == mn) { em[beg + r] = pl; k = INT_MAX; }
        }
    } else if (L <= 512) {
        for (int i = lane; i < L; i += 64) {
            skey[w][i] = key[beg + i];
            spl[w][i] = em[beg + i];
        }
        for (int it = 0; it < L; it++) {
            int par = it & 1;
            for (int p = par + 2 * lane; p + 1 < L; p += 128) {
                int ka = skey[w][p], kb = skey[w][p + 1];
                if (kb < ka) {
                    skey[w][p] = kb; skey[w][p + 1] = ka;
                    int2 t = spl[w][p]; spl[w][p] = spl[w][p + 1]; spl[w][p + 1] = t;
                }
            }
        }
        for (int i = lane; i < L; i += 64) em[beg + i] = spl[w][i];
    }
    // L > 512 impossible for this graph (max in-degree ~45)
}

// ---------------- GEMM (float input, layer 0 only) ----------------

__global__ __launch_bounds__(256) void gemm_k(const float* __restrict__ in,
                                              const float* __restrict__ W,
                                              float* __restrict__ xw) {
    __shared__ float sW[64 * 64];
    __shared__ float sx[32 * 65];
    int tid = threadIdx.x;
    const float4* W4 = (const float4*)W;
    float4* sW4 = (float4*)sW;
    for (int i = tid; i < 1024; i += 256) sW4[i] = W4[i];
    const float* inb = in + (size_t)blockIdx.x * 2048;
    for (int i = tid; i < 2048; i += 256) sx[(i >> 6) * 65 + (i & 63)] = inb[i];
    __syncthreads();
    int cg = tid & 15, rr = tid >> 4;
    float a0 = 0, a1 = 0, a2 = 0, a3 = 0, c0 = 0, c1 = 0, c2 = 0, c3 = 0;
#pragma unroll
    for (int k = 0; k < 64; k++) {
        float4 wv = *(const float4*)&sW[k * 64 + cg * 4];
        float xa = sx[rr * 65 + k];
        float xb = sx[(rr + 16) * 65 + k];
        a0 += xa * wv.x; a1 += xa * wv.y; a2 += xa * wv.z; a3 += xa * wv.w;
        c0 += xb * wv.x; c1 += xb * wv.y; c2 += xb * wv.z; c3 += xb * wv.w;
    }
    size_t r0 = (size_t)(blockIdx.x * 32 + rr) * 64 + cg * 4;
    size_t r1 = (size_t)(blockIdx.x * 32 + rr + 16) * 64 + cg * 4;
    *(float4*)&xw[r0] = make_float4(a0, a1, a2, a3);
    *(float4*)&xw[r1] = make_float4(c0, c1, c2, c3);
}

// ---------------- bit GEMM: xw[n,c] = sum over set bits k of W[k,c] ----------------
// Ascending-k summation == float gemm with 0/1 inputs (exact-zero terms no-ops).

__global__ __launch_bounds__(256) void bitgemm_k(const u64* __restrict__ bits,
                                                 const float* __restrict__ W,
                                                 float* __restrict__ xw) {
    __shared__ float sW[64 * 64];
    int tid = threadIdx.x;
    const float4* W4 = (const float4*)W;
    float4* sW4 = (float4*)sW;
    for (int i = tid; i < 1024; i += 256) sW4[i] = W4[i];
    __syncthreads();
    int lane = tid & 63, w = tid >> 6;
    int n0 = blockIdx.x * 64 + w * 16;
    for (int t = 0; t < 16; t++) {
        int n = n0 + t;
        if (n >= NN) return;
        u64 m = bits[n];
        float acc = 0.0f;
        while (m) {
            int k = (int)__builtin_ctzll(m);
            m &= m - 1;
            acc += sW[k * 64 + lane];
        }
        xw[(size_t)n * 64 + lane] = acc;
    }
}

__global__ __launch_bounds__(256) void bitgemm2_k(const u64* __restrict__ bits,
                                                  const float* __restrict__ Wa,
                                                  const float* __restrict__ Wb,
                                                  float* __restrict__ oa,
                                                  float* __restrict__ ob) {
    __shared__ float sA[64 * 64];
    __shared__ float sB[64 * 64];
    int tid = threadIdx.x;
    const float4* A4 = (const float4*)Wa;
    const float4* B4 = (const float4*)Wb;
    float4* sA4 = (float4*)sA;
    float4* sB4 = (float4*)sB;
    for (int i = tid; i < 1024; i += 256) { sA4[i] = A4[i]; sB4[i] = B4[i]; }
    __syncthreads();
    int lane = tid & 63, w = tid >> 6;
    int n0 = blockIdx.x * 64 + w * 16;
    for (int t = 0; t < 16; t++) {
        int n = n0 + t;
        if (n >= NN) return;
        u64 m = bits[n];
        float a = 0.0f, b = 0.0f;
        while (m) {
            int k = (int)__builtin_ctzll(m);
            m &= m - 1;
            a += sA[k * 64 + lane];
            b += sB[k * 64 + lane];
        }
        size_t o = (size_t)n * 64 + lane;
        oa[o] = a;
        ob[o] = b;
    }
}

// ---------------- gathers: out[n] = sum_e norm_e*xw[src_e] + d2i[n]*xw[n] + b ----

__global__ __launch_bounds__(256) void gather_k(const float* __restrict__ xw,
                                                const int2* __restrict__ em,
                                                const int* __restrict__ rp,
                                                const float* __restrict__ d2i,
                                                const float* __restrict__ bias,
                                                float* __restrict__ out) {
    int tid = threadIdx.x, lane = tid & 63;
    int n = blockIdx.x * 4 + (tid >> 6);
    int beg = rp[n], end = rp[n + 1];
    float self = d2i[n] * xw[(size_t)n * 64 + lane] + bias[lane];
    float acc = 0.0f;
    for (int base = beg; base < end; base += 64) {
        int cnt = min(64, end - base);
        int2 m = make_int2(0, 0);
        if (base + lane < end) m = em[base + lane];
        int j = 0;
        for (; j + 8 <= cnt; j += 8) {
            int s0 = __shfl(m.x, j, 64),     s1 = __shfl(m.x, j + 1, 64);
            int s2 = __shfl(m.x, j + 2, 64), s3 = __shfl(m.x, j + 3, 64);
            int s4 = __shfl(m.x, j + 4, 64), s5 = __shfl(m.x, j + 5, 64);
            int s6 = __shfl(m.x, j + 6, 64), s7 = __shfl(m.x, j + 7, 64);
            float n0 = __int_as_float(__shfl(m.y, j, 64));
            float n1 = __int_as_float(__shfl(m.y, j + 1, 64));
            float n2 = __int_as_float(__shfl(m.y, j + 2, 64));
            float n3 = __int_as_float(__shfl(m.y, j + 3, 64));
            float n4 = __int_as_float(__shfl(m.y, j + 4, 64));
            float n5 = __int_as_float(__shfl(m.y, j + 5, 64));
            float n6 = __int_as_float(__shfl(m.y, j + 6, 64));
            float n7 = __int_as_float(__shfl(m.y, j + 7, 64));
            float v0 = xw[(size_t)s0 * 64 + lane];
            float v1 = xw[(size_t)s1 * 64 + lane];
            float v2 = xw[(size_t)s2 * 64 + lane];
            float v3 = xw[(size_t)s3 * 64 + lane];
            float v4 = xw[(size_t)s4 * 64 + lane];
            float v5 = xw[(size_t)s5 * 64 + lane];
            float v6 = xw[(size_t)s6 * 64 + lane];
            float v7 = xw[(size_t)s7 * 64 + lane];
            acc += n0 * v0; acc += n1 * v1; acc += n2 * v2; acc += n3 * v3;
            acc += n4 * v4; acc += n5 * v5; acc += n6 * v6; acc += n7 * v7;
        }
        for (; j < cnt; j++) {
            int s = __shfl(m.x, j, 64);
            float nv = __int_as_float(__shfl(m.y, j, 64));
            acc += nv * xw[(size_t)s * 64 + lane];
        }
    }
    out[(size_t)n * 64 + lane] = acc + self;
}

__global__ __launch_bounds__(256) void gather2_k(const float* __restrict__ xa,
                                                 const float* __restrict__ xb,
                                                 const int2* __restrict__ em,
                                                 const int* __restrict__ rp,
                                                 const float* __restrict__ d2i,
                                                 const float* __restrict__ ba,
                                                 const float* __restrict__ bb,
                                                 float* __restrict__ oa,
                                                 float* __restrict__ ob) {
    int tid = threadIdx.x, lane = tid & 63;
    int n = blockIdx.x * 4 + (tid >> 6);
    int beg = rp[n], end = rp[n + 1];
    float selfa = d2i[n] * xa[(size_t)n * 64 + lane] + ba[lane];
    float selfb = d2i[n] * xb[(size_t)n * 64 + lane] + bb[lane];
    float acca = 0.0f, accb = 0.0f;
    for (int base = beg; base < end; base += 64) {
        int cnt = min(64, end - base);
        int2 m = make_int2(0, 0);
        if (base + lane < end) m = em[base + lane];
        int j = 0;
        for (; j + 4 <= cnt; j += 4) {
            int s0 = __shfl(m.x, j, 64),     s1 = __shfl(m.x, j + 1, 64);
            int s2 = __shfl(m.x, j + 2, 64), s3 = __shfl(m.x, j + 3, 64);
            float n0 = __int_as_float(__shfl(m.y, j, 64));
            float n1 = __int_as_float(__shfl(m.y, j + 1, 64));
            float n2 = __int_as_float(__shfl(m.y, j + 2, 64));
            float n3 = __int_as_float(__shfl(m.y, j + 3, 64));
            float a0 = xa[(size_t)s0 * 64 + lane];
            float b0 = xb[(size_t)s0 * 64 + lane];
            float a1 = xa[(size_t)s1 * 64 + lane];
            float b1 = xb[(size_t)s1 * 64 + lane];
            float a2 = xa[(size_t)s2 * 64 + lane];
            float b2 = xb[(size_t)s2 * 64 + lane];
            float a3 = xa[(size_t)s3 * 64 + lane];
            float b3 = xb[(size_t)s3 * 64 + lane];
            acca += n0 * a0; accb += n0 * b0;
            acca += n1 * a1; accb += n1 * b1;
            acca += n2 * a2; accb += n2 * b2;
            acca += n3 * a3; accb += n3 * b3;
        }
        for (; j < cnt; j++) {
            int s = __shfl(m.x, j, 64);
            float nv = __int_as_float(__shfl(m.y, j, 64));
            acca += nv * xa[(size_t)s * 64 + lane];
            accb += nv * xb[(size_t)s * 64 + lane];
        }
    }
    size_t o = (size_t)n * 64 + lane;
    oa[o] = acca + selfa;
    ob[o] = accb + selfb;
}

// ---------------- batchnorm stats: deterministic partials + fixed-order reduce ----

__global__ __launch_bounds__(256) void bn_part_k(const float* __restrict__ x,
                                                 double* __restrict__ part) {
    int tid = threadIdx.x;
    int c = tid & 63, g = tid >> 6;
    double s = 0.0, s2 = 0.0;
    for (int row = blockIdx.x * 4 + g; row < NN; row += gridDim.x * 4) {
        float v = x[(size_t)row * 64 + c];
        s += (double)v;
        s2 += (double)v * (double)v;
    }
    __shared__ double ls[256], ls2[256];
    ls[tid] = s; ls2[tid] = s2;
    __syncthreads();
    if (tid < 128) { ls[tid] += ls[tid + 128]; ls2[tid] += ls2[tid + 128]; }
    __syncthreads();
    if (tid < 64) {
        part[(size_t)blockIdx.x * 128 + c] = ls[tid] + ls[tid + 64];
        part[(size_t)blockIdx.x * 128 + 64 + c] = ls2[tid] + ls2[tid + 64];
    }
}

__global__ void bn_red_k(const double* __restrict__ part, double* __restrict__ st) {
    int c = threadIdx.x;   // 128
    double s = 0.0;
    for (int b = 0; b < 256; b++) s += part[(size_t)b * 128 + c];
    st[c] = s;
}

__global__ __launch_bounds__(256) void bn_part2_k(const float* __restrict__ xa,
                                                  const float* __restrict__ xb,
                                                  double* __restrict__ part) {
    int tid = threadIdx.x;
    int c = tid & 63, g = tid >> 6;
    double sa = 0.0, sa2 = 0.0, sb = 0.0, sb2 = 0.0;
    for (int row = blockIdx.x * 4 + g; row < NN; row += gridDim.x * 4) {
        float va = xa[(size_t)row * 64 + c];
        sa += (double)va; sa2 += (double)va * (double)va;
        float vb = xb[(size_t)row * 64 + c];
        sb += (double)vb; sb2 += (double)vb * (double)vb;
    }
    __shared__ double l1[256], l2[256], l3[256], l4[256];
    l1[tid] = sa; l2[tid] = sa2; l3[tid] = sb; l4[tid] = sb2;
    __syncthreads();
    if (tid < 128) {
        l1[tid] += l1[tid + 128]; l2[tid] += l2[tid + 128];
        l3[tid] += l3[tid + 128]; l4[tid] += l4[tid + 128];
    }
    __syncthreads();
    if (tid < 64) {
        size_t o = (size_t)blockIdx.x * 256;
        part[o + c] = l1[tid] + l1[tid + 64];
        part[o + 64 + c] = l2[tid] + l2[tid + 64];
        part[o + 128 + c] = l3[tid] + l3[tid + 64];
        part[o + 192 + c] = l4[tid] + l4[tid + 64];
    }
}

__global__ void bn_red2_k(const double* __restrict__ part, double* __restrict__ sta,
                          double* __restrict__ stb) {
    int c = threadIdx.x;   // 256
    double s = 0.0;
    for (int b = 0; b < 256; b++) s += part[(size_t)b * 256 + c];
    if (c < 128) sta[c] = s;
    else stb[c - 128] = s;
}

// per-block bn scale/shift preamble (c < 64)
__device__ inline void bn_ss(const double* __restrict__ st, const float* __restrict__ gam,
                             const float* __restrict__ bet, int c,
                             float* __restrict__ ssc, float* __restrict__ ssh) {
    double m = st[c] * (1.0 / NN);
    double v = st[64 + c] * (1.0 / NN) - m * m;
    float scale = (float)((double)gam[c] / sqrt(v + (double)EPSF));
    ssc[c] = scale;
    ssh[c] = bet[c] - (float)m * scale;
}

// ---------------- fused elementwise steps (bit spike outputs) ----------------

__global__ __launch_bounds__(256) void lif_conv_bits_k(const float* __restrict__ G,
                                                       const double* __restrict__ st,
                                                       const float* __restrict__ gam,
                                                       const float* __restrict__ bet,
                                                       float* __restrict__ vconv,
                                                       u64* __restrict__ bits) {
    __shared__ float ssc[64], ssh[64];
    int tid = threadIdx.x;
    if (tid < 64) bn_ss(st, gam, bet, tid, ssc, ssh);
    __syncthreads();
    size_t i = (size_t)blockIdx.x * 256 + tid;
    int c = tid & 63;
    float v = vconv[i] + (G[i] * ssc[c] + ssh[c]);
    bool sp = (v - THF >= 0.0f);
    u64 bal = __ballot(sp);
    vconv[i] = sp ? 0.0f : v;
    if (c == 0) bits[i >> 6] = bal;
}

__global__ __launch_bounds__(256) void bn_spike_bits_k(const float* __restrict__ G,
                                                       const double* __restrict__ st,
                                                       const float* __restrict__ gam,
                                                       const float* __restrict__ bet,
                                                       float* __restrict__ x3,
                                                       u64* __restrict__ bits) {
    __shared__ float ssc[64], ssh[64];
    int tid = threadIdx.x;
    if (tid < 64) bn_ss(st, gam, bet, tid, ssc, ssh);
    __syncthreads();
    size_t i = (size_t)blockIdx.x * 256 + tid;
    int c = tid & 63;
    float xv = G[i] * ssc[c] + ssh[c];
    x3[i] = xv;
    u64 bal = __ballot(xv - THF >= 0.0f);
    if (c == 0) bits[i >> 6] = bal;
}

__global__ __launch_bounds__(256) void bn_add_k(const float* __restrict__ G,
                                                const double* __restrict__ st,
                                                const float* __restrict__ gam,
                                                const float* __restrict__ bet,
                                                const float* __restrict__ x3,
                                                float* __restrict__ F) {
    __shared__ float ssc[64], ssh[64];
    int tid = threadIdx.x;
    if (tid < 64) bn_ss(st, gam, bet, tid, ssc, ssh);
    __syncthreads();
    size_t i = (size_t)blockIdx.x * 256 + tid;
    int c = tid & 63;
    F[i] = (G[i] * ssc[c] + ssh[c]) + x3[i];
}

__global__ __launch_bounds__(256) void bn_lif_bits_k(const float* __restrict__ F,
                                                     const double* __restrict__ st,
                                                     const float* __restrict__ gam,
                                                     const float* __restrict__ bet,
                                                     float* __restrict__ vconv,
                                                     float* __restrict__ x4,
                                                     u64* __restrict__ bits) {
    __shared__ float ssc[64], ssh[64];
    int tid = threadIdx.x;
    if (tid < 64) bn_ss(st, gam, bet, tid, ssc, ssh);
    __syncthreads();
    size_t i = (size_t)blockIdx.x * 256 + tid;
    int c = tid & 63;
    float xv = F[i] * ssc[c] + ssh[c];
    x4[i] = xv;
    float v = vconv[i] + xv;
    bool sp = (v - THF >= 0.0f);
    u64 bal = __ballot(sp);
    vconv[i] = sp ? 0.0f : v;
    if (c == 0) bits[i >> 6] = bal;
}

__global__ __launch_bounds__(256) void qk_bits_k(const float* __restrict__ Gq,
                                                 const float* __restrict__ Gk,
                                                 const double* __restrict__ st4,
                                                 const double* __restrict__ st5,
                                                 const float* __restrict__ gam4,
                                                 const float* __restrict__ bet4,
                                                 const float* __restrict__ gam5,
                                                 const float* __restrict__ bet5,
                                                 float* __restrict__ qs) {
    __shared__ float sc4[64], sh4[64], sc5[64], sh5[64];
    int tid = threadIdx.x;
    if (tid < 64) {
        bn_ss(st4, gam4, bet4, tid, sc4, sh4);
        bn_ss(st5, gam5, bet5, tid, sc5, sh5);
    }
    __syncthreads();
    size_t i = (size_t)blockIdx.x * 256 + tid;
    int c = tid & 63;
    bool qb = (Gq[i] * sc4[c] + sh4[c] - THF >= 0.0f);
    bool kb = (Gk[i] * sc5[c] + sh5[c] - THF >= 0.0f);
    int pc = __popcll(__ballot(qb && kb));
    if (c == 0)
        qs[i >> 6] = ((float)pc * (1.0f / 64.0f) - ATTTH >= 0.0f) ? 1.0f : 0.0f;
}

__global__ __launch_bounds__(256) void att_bits_k(const float* __restrict__ Gv,
                                                  const double* __restrict__ st6,
                                                  const float* __restrict__ gam,
                                                  const float* __restrict__ bet,
                                                  const float* __restrict__ qs,
                                                  u64* __restrict__ bits) {
    __shared__ float ssc[64], ssh[64];
    int tid = threadIdx.x;
    if (tid < 64) bn_ss(st6, gam, bet, tid, ssc, ssh);
    __syncthreads();
    size_t i = (size_t)blockIdx.x * 256 + tid;
    int c = tid & 63;
    bool vb = (Gv[i] * ssc[c] + ssh[c] - THF >= 0.0f);
    bool ab = vb && (qs[i >> 6] != 0.0f);
    u64 bal = __ballot(ab);
    if (c == 0) bits[i >> 6] = bal;
}

__global__ __launch_bounds__(256) void bn_scale_add_k(const float* __restrict__ G,
                                                      const double* __restrict__ st,
                                                      const float* __restrict__ gam,
                                                      const float* __restrict__ bet,
                                                      const float* __restrict__ x4,
                                                      float* __restrict__ tmp2) {
    __shared__ float ssc[64], ssh[64];
    int tid = threadIdx.x;
    if (tid < 64) bn_ss(st, gam, bet, tid, ssc, ssh);
    __syncthreads();
    size_t i = (size_t)blockIdx.x * 256 + tid;
    int c = tid & 63;
    tmp2[i] = x4[i] + 0.125f * (G[i] * ssc[c] + ssh[c]);
}

__global__ __launch_bounds__(256) void decode_k(const float* __restrict__ tmp2,
                                                const double* __restrict__ st,
                                                const float* __restrict__ gam,
                                                const float* __restrict__ bet,
                                                const float* __restrict__ wrow,
                                                float* __restrict__ z) {
    __shared__ float ssc[64], ssh[64];
    int tid = threadIdx.x;
    if (tid < 64) bn_ss(st, gam, bet, tid, ssc, ssh);
    __syncthreads();
    int lane = tid & 63;
    int row = blockIdx.x * 4 + (tid >> 6);
    float sv = tmp2[(size_t)row * 64 + lane] * ssc[lane] + ssh[lane];
    float p = sv * wrow[lane];
#pragma unroll
    for (int off = 32; off > 0; off >>= 1) p += __shfl_xor(p, off, 64);
    if (lane == 0) z[row] = p;
}

__global__ void wrow_k(const float* __restrict__ W_lin, float* __restrict__ wrow) {
    int h = threadIdx.x;
    if (h >= 64) return;
    float s = 0.0f;
    for (int j = 0; j < 64; j++) s += W_lin[h * 64 + j];
    wrow[h] = s;
}

// ---------------- host driver ----------------

extern "C" void kernel_launch(void* const* d_in, const int* in_sizes, int n_in,
                              void* d_out, int out_size, void* d_ws, size_t ws_size,
                              hipStream_t stream) {
    const float* x    = (const float*)d_in[0];
    const int* eidx   = (const int*)d_in[1];
    const int* emask  = (const int*)d_in[2];
    const float* Wg   = (const float*)d_in[3];
    const float* bg   = (const float*)d_in[4];
    const float* bng  = (const float*)d_in[5];
    const float* bnb  = (const float*)d_in[6];
    const float* Wlin = (const float*)d_in[7];
    float* zout = (float*)d_out;

    const int* srcp = eidx;
    const int* dstp = eidx + NE;
    const size_t NH = (size_t)NN * HH;

    // ---- workspace layout (8B-aligned chain) ----
    float* fb = (float*)d_ws;
    float* P1 = fb;
    float* P2 = P1 + NH;
    float* P3 = P2 + NH;
    float* P4 = P3 + NH;
    float* P5 = P4 + NH;
    float* vconv = P5 + NH;                      // 6*NH floats
    int2* em1 = (int2*)(vconv + NH);             // NE (8B aligned: 6*NH even)
    int2* em2 = em1 + NE;                        // EM2CAP
    u64* sbits = (u64*)(em2 + EM2CAP);           // NN
    double* part = (double*)(sbits + NN);        // 256*256 doubles
    double* stats = part + 256 * 256;            // 18*128 doubles
    float* dis1 = (float*)(stats + 18 * 128);
    float* d21  = dis1 + NN;
    float* dis2m = d21 + NN;
    float* d22  = dis2m + NN;
    float* qs   = d22 + NN;                      // NN
    float* wrow = qs + NN;                       // 64
    int* key1 = (int*)(wrow + 64);               // NE
    int* key2 = key1 + NE;                       // EM2CAP
    int* rp1 = key2 + EM2CAP;                    // NN+1
    int* rp2 = rp1 + NN + 2;                     // NN+1
    int* cnt1 = rp2 + NN + 2;                    // 4*NN contiguous (one memset)
    int* cnt2 = cnt1 + NN;
    int* cur1 = cnt2 + NN;
    int* cur2 = cur1 + NN;
    int* bsum = cur2 + NN;                       // SCAN_B

    hipMemsetAsync(cnt1, 0, 4 * NN * sizeof(int), stream);
    hipMemsetAsync(vconv, 0, NH * sizeof(float), stream);

    const int NB_EDGE = NE / 256;        // 6250
    const int NB_NODE = SCAN_B;          // 391
    const int NB_ROW4 = NN / 4;          // 25000
    const int NB_GEMM = NN / 32;         // 3125
    const int NB_BG   = (NN + 63) / 64;  // 1563

    wrow_k<<<1, 64, 0, stream>>>(Wlin, wrow);
    hist_k<<<NB_EDGE, 256, 0, stream>>>(dstp, emask, cnt1, cnt2);
    deg_inv_k<<<NB_NODE, 256, 0, stream>>>(cnt1, dis1, d21);
    deg_inv_k<<<NB_NODE, 256, 0, stream>>>(cnt2, dis2m, d22);
    scan1_k<<<NB_NODE, 256, 0, stream>>>(cnt1, rp1, bsum);
    scan2_k<<<1, 1, 0, stream>>>(bsum, rp1);
    scan3_k<<<NB_NODE, 256, 0, stream>>>(rp1, bsum);
    scan1_k<<<NB_NODE, 256, 0, stream>>>(cnt2, rp2, bsum);
    scan2_k<<<1, 1, 0, stream>>>(bsum, rp2);
    scan3_k<<<NB_NODE, 256, 0, stream>>>(rp2, bsum);
    csr_fill_k<<<NB_EDGE, 256, 0, stream>>>(srcp, dstp, emask, dis1, dis2m,
                                            rp1, rp2, cur1, cur2, em1, em2,
                                            key1, key2);
    seg_sort_k<<<NB_ROW4, 256, 0, stream>>>(em1, key1, rp1);
    seg_sort_k<<<NB_ROW4, 256, 0, stream>>>(em2, key2, rp2);

    auto enc = [&](const int2* em, const int* rp, const float* d2i, int bnbase,
                   float* zo) {
        auto ST = [&](int bni) { return stats + (bnbase + bni) * 128; };
        auto W = [&](int wi) { return Wg + wi * 4096; };
        auto BI = [&](int wi) { return bg + wi * 64; };
        auto GM = [&](int bi) { return bng + bi * 64; };
        auto BT = [&](int bi) { return bnb + bi * 64; };
        auto stats_run = [&](const float* buf, int bni) {
            bn_part_k<<<256, 256, 0, stream>>>(buf, part);
            bn_red_k<<<1, 128, 0, stream>>>(part, ST(bni));
        };

        // layer 0 (float input)
        gemm_k<<<NB_GEMM, 256, 0, stream>>>(x, W(0), P1);
        gather_k<<<NB_ROW4, 256, 0, stream>>>(P1, em, rp, d2i, BI(0), P2);
        stats_run(P2, 0);
        lif_conv_bits_k<<<NB_ROW4, 256, 0, stream>>>(P2, ST(0), GM(0), BT(0),
                                                     vconv, sbits);
        // layer 1
        bitgemm_k<<<NB_BG, 256, 0, stream>>>(sbits, W(1), P1);
        gather_k<<<NB_ROW4, 256, 0, stream>>>(P1, em, rp, d2i, BI(1), P2);
        stats_run(P2, 1);
        bn_spike_bits_k<<<NB_ROW4, 256, 0, stream>>>(P2, ST(1), GM(1), BT(1),
                                                     P3, sbits);    // x3=P3
        // pos layer
        bitgemm_k<<<NB_BG, 256, 0, stream>>>(sbits, W(2), P1);
        gather_k<<<NB_ROW4, 256, 0, stream>>>(P1, em, rp, d2i, BI(2), P2);
        stats_run(P2, 2);
        bn_add_k<<<NB_ROW4, 256, 0, stream>>>(P2, ST(2), GM(2), BT(2), P3, P4); // F=P4
        stats_run(P4, 3);
        bn_lif_bits_k<<<NB_ROW4, 256, 0, stream>>>(P4, ST(3), GM(3), BT(3),
                                                   vconv, P2, sbits); // x4=P2
        // q,k (pair-fused)
        bitgemm2_k<<<NB_BG, 256, 0, stream>>>(sbits, W(3), W(4), P1, P3);
        gather2_k<<<NB_ROW4, 256, 0, stream>>>(P1, P3, em, rp, d2i, BI(3), BI(4),
                                               P4, P5);
        bn_part2_k<<<256, 256, 0, stream>>>(P4, P5, part);
        bn_red2_k<<<1, 256, 0, stream>>>(part, ST(4), ST(5));
        qk_bits_k<<<NB_ROW4, 256, 0, stream>>>(P4, P5, ST(4), ST(5),
                                               GM(4), BT(4), GM(5), BT(5), qs);
        // v
        bitgemm_k<<<NB_BG, 256, 0, stream>>>(sbits, W(5), P1);
        gather_k<<<NB_ROW4, 256, 0, stream>>>(P1, em, rp, d2i, BI(5), P3);
        stats_run(P3, 6);
        att_bits_k<<<NB_ROW4, 256, 0, stream>>>(P3, ST(6), GM(6), BT(6), qs, sbits);
        // att gcn
        bitgemm_k<<<NB_BG, 256, 0, stream>>>(sbits, W(6), P1);
        gather_k<<<NB_ROW4, 256, 0, stream>>>(P1, em, rp, d2i, BI(6), P3);
        stats_run(P3, 7);
        bn_scale_add_k<<<NB_ROW4, 256, 0, stream>>>(P3, ST(7), GM(7), BT(7),
                                                    P2, P4);   // tmp2=P4 (x4=P2)
        stats_run(P4, 8);
        decode_k<<<NB_ROW4, 256, 0, stream>>>(P4, ST(8), GM(8), BT(8), wrow, zo);
    };

    enc(em1, rp1, d21, 0, zout);
    enc(em2, rp2, d22, 9, zout + NN);
}

// Round 8
// 2278.711 us; speedup vs baseline: 1.0886x; 1.0886x over previous
//
#include <hip/hip_runtime.h>
#include <math.h>
#include <stdint.h>
#include <limits.h>

#define NN 100000
#define NE 1600000
#define HH 64
#define THF 0.7f
#define ATTTH 0.2f
#define EPSF 1e-5f
#define SCAN_B ((NN + 255) / 256)   // 391
#define EM2CAP 1000000

typedef unsigned long long u64;

// ---------------- setup: histogram, degree, scans, CSR fill ----------------

__global__ void hist_k(const int* __restrict__ dst, const int* __restrict__ mask,
                       int* __restrict__ cnt_all, int* __restrict__ cnt_mask) {
    int e = blockIdx.x * 256 + threadIdx.x;
    if (e >= NE) return;
    int d = dst[e];
    atomicAdd(&cnt_all[d], 1);          // integer atomics: value-deterministic
    if (mask[e]) atomicAdd(&cnt_mask[d], 1);
}

__global__ void deg_inv2_k(const int* __restrict__ cnt1, const int* __restrict__ cnt2,
                           float* __restrict__ dis1, float* __restrict__ d21,
                           float* __restrict__ dis2m, float* __restrict__ d22) {
    int i = blockIdx.x * 256 + threadIdx.x;
    if (i < NN) {
        float dg1 = (float)(cnt1[i] + 1);   // +1 self loop
        dis1[i] = 1.0f / sqrtf(dg1);
        d21[i] = 1.0f / dg1;
        float dg2 = (float)(cnt2[i] + 1);
        dis2m[i] = 1.0f / sqrtf(dg2);
        d22[i] = 1.0f / dg2;
    }
}

__global__ void scan1_k(const int* __restrict__ counts, int* __restrict__ rp,
                        int* __restrict__ bsum) {
    __shared__ int ls[256];
    int i = blockIdx.x * 256 + threadIdx.x;
    int v = (i < NN) ? counts[i] : 0;
    ls[threadIdx.x] = v;
    __syncthreads();
    for (int off = 1; off < 256; off <<= 1) {
        int t = (threadIdx.x >= off) ? ls[threadIdx.x - off] : 0;
        __syncthreads();
        ls[threadIdx.x] += t;
        __syncthreads();
    }
    if (i < NN) rp[i] = ls[threadIdx.x] - v;
    if (threadIdx.x == 255) bsum[blockIdx.x] = ls[255];
}

// parallel block-sum scan: one 512-thread block (SCAN_B=391 < 512), fixed order
__global__ __launch_bounds__(512) void scan2_k(int* __restrict__ bsum,
                                               int* __restrict__ rp) {
    __shared__ int ls[512];
    int i = threadIdx.x;
    int v = (i < SCAN_B) ? bsum[i] : 0;
    ls[i] = v;
    __syncthreads();
    for (int off = 1; off < 512; off <<= 1) {
        int t = (i >= off) ? ls[i - off] : 0;
        __syncthreads();
        ls[i] += t;
        __syncthreads();
    }
    if (i < SCAN_B) bsum[i] = ls[i] - v;      // exclusive
    if (i == SCAN_B - 1) rp[NN] = ls[i];
}

__global__ void scan3_k(int* __restrict__ rp, const int* __restrict__ bsum) {
    int i = blockIdx.x * 256 + threadIdx.x;
    if (i < NN) rp[i] += bsum[blockIdx.x];
}

// fills both CSRs (atomic cursors; layout made deterministic by seg_sort)
__global__ void csr_fill_k(const int* __restrict__ src, const int* __restrict__ dst,
                           const int* __restrict__ mask,
                           const float* __restrict__ dis1, const float* __restrict__ dis2m,
                           const int* __restrict__ rp1, const int* __restrict__ rp2,
                           int* __restrict__ cur1, int* __restrict__ cur2,
                           int2* __restrict__ em1, int2* __restrict__ em2) {
    int e = blockIdx.x * 256 + threadIdx.x;
    if (e >= NE) return;
    int s = src[e], d = dst[e];
    float n1 = dis1[s] * dis1[d];
    int p1 = rp1[d] + atomicAdd(&cur1[d], 1);
    em1[p1] = make_int2(s, __float_as_int(n1));
    if (mask[e]) {
        float n2 = dis2m[s] * dis2m[d];
        int p2 = rp2[d] + atomicAdd(&cur2[d], 1);
        em2[p2] = make_int2(s, __float_as_int(n2));
    }
}

// sort each dst segment by src (= em.x). Duplicate srcs have identical payloads
// (same norm), so leader-pick loses nothing. Result: run-invariant layout.
__global__ __launch_bounds__(256) void seg_sort_k(int2* __restrict__ em,
                                                  const int* __restrict__ rp) {
    __shared__ int skey[4][512];
    __shared__ int snrm[4][512];
    int tid = threadIdx.x, lane = tid & 63, w = tid >> 6;
    int n = blockIdx.x * 4 + w;
    int beg = rp[n], end = rp[n + 1];
    int L = end - beg;
    if (L <= 1) return;
    if (L <= 64) {
        int k = INT_MAX; int2 pl = make_int2(0, 0);
        if (lane < L) { pl = em[beg + lane]; k = pl.x; }
        for (int r = 0; r < L; r++) {
            int mn = k;
#pragma unroll
            for (int off = 32; off > 0; off >>= 1)
                mn = min(mn, __shfl_xor(mn, off, 64));
            u64 msk = __ballot(k == mn);
            int leader = (int)__ffsll((unsigned long long)msk) - 1;
            if (lane == leader) { em[beg + r] = pl; k = INT_MAX; }
        }
    } else if (L <= 512) {
        for (int i = lane; i < L; i += 64) {
            int2 p = em[beg + i];
            skey[w][i] = p.x;
            snrm[w][i] = p.y;
        }
        for (int it = 0; it < L; it++) {
            int par = it & 1;
            for (int p = par + 2 * lane; p + 1 < L; p += 128) {
                int ka = skey[w][p], kb = skey[w][p + 1];
                if (kb < ka) {   // strict: stable, duplicates untouched
                    skey[w][p] = kb; skey[w][p + 1] = ka;
                    int t = snrm[w][p]; snrm[w][p] = snrm[w][p + 1]; snrm[w][p + 1] = t;
                }
            }
        }
        for (int i = lane; i < L; i += 64)
            em[beg + i] = make_int2(skey[w][i], snrm[w][i]);
    }
    // L > 512 impossible for this graph (max in-degree ~50)
}

// ---------------- GEMM (float input, layer 0 only) ----------------

__global__ __launch_bounds__(256) void gemm_k(const float* __restrict__ in,
                                              const float* __restrict__ W,
                                              float* __restrict__ xw) {
    __shared__ float sW[64 * 64];
    __shared__ float sx[32 * 65];
    int tid = threadIdx.x;
    const float4* W4 = (const float4*)W;
    float4* sW4 = (float4*)sW;
    for (int i = tid; i < 1024; i += 256) sW4[i] = W4[i];
    const float* inb = in + (size_t)blockIdx.x * 2048;
    for (int i = tid; i < 2048; i += 256) sx[(i >> 6) * 65 + (i & 63)] = inb[i];
    __syncthreads();
    int cg = tid & 15, rr = tid >> 4;
    float a0 = 0, a1 = 0, a2 = 0, a3 = 0, c0 = 0, c1 = 0, c2 = 0, c3 = 0;
#pragma unroll
    for (int k = 0; k < 64; k++) {
        float4 wv = *(const float4*)&sW[k * 64 + cg * 4];
        float xa = sx[rr * 65 + k];
        float xb = sx[(rr + 16) * 65 + k];
        a0 += xa * wv.x; a1 += xa * wv.y; a2 += xa * wv.z; a3 += xa * wv.w;
        c0 += xb * wv.x; c1 += xb * wv.y; c2 += xb * wv.z; c3 += xb * wv.w;
    }
    size_t r0 = (size_t)(blockIdx.x * 32 + rr) * 64 + cg * 4;
    size_t r1 = (size_t)(blockIdx.x * 32 + rr + 16) * 64 + cg * 4;
    *(float4*)&xw[r0] = make_float4(a0, a1, a2, a3);
    *(float4*)&xw[r1] = make_float4(c0, c1, c2, c3);
}

// ---------------- bit GEMM: xw[n,c] = sum over set bits k of W[k,c] ----------------
// Ascending-k summation == float gemm with 0/1 inputs (exact-zero terms no-ops).

__global__ __launch_bounds__(256) void bitgemm_k(const u64* __restrict__ bits,
                                                 const float* __restrict__ W,
                                                 float* __restrict__ xw) {
    __shared__ float sW[64 * 64];
    int tid = threadIdx.x;
    const float4* W4 = (const float4*)W;
    float4* sW4 = (float4*)sW;
    for (int i = tid; i < 1024; i += 256) sW4[i] = W4[i];
    __syncthreads();
    int lane = tid & 63, w = tid >> 6;
    int n0 = blockIdx.x * 64 + w * 16;
    for (int t = 0; t < 16; t++) {
        int n = n0 + t;
        if (n >= NN) return;
        u64 m = bits[n];
        float acc = 0.0f;
        while (m) {
            int k = (int)__builtin_ctzll(m);
            m &= m - 1;
            acc += sW[k * 64 + lane];
        }
        xw[(size_t)n * 64 + lane] = acc;
    }
}

__global__ __launch_bounds__(256) void bitgemm2_k(const u64* __restrict__ bits,
                                                  const float* __restrict__ Wa,
                                                  const float* __restrict__ Wb,
                                                  float* __restrict__ oa,
                                                  float* __restrict__ ob) {
    __shared__ float sA[64 * 64];
    __shared__ float sB[64 * 64];
    int tid = threadIdx.x;
    const float4* A4 = (const float4*)Wa;
    const float4* B4 = (const float4*)Wb;
    float4* sA4 = (float4*)sA;
    float4* sB4 = (float4*)sB;
    for (int i = tid; i < 1024; i += 256) { sA4[i] = A4[i]; sB4[i] = B4[i]; }
    __syncthreads();
    int lane = tid & 63, w = tid >> 6;
    int n0 = blockIdx.x * 64 + w * 16;
    for (int t = 0; t < 16; t++) {
        int n = n0 + t;
        if (n >= NN) return;
        u64 m = bits[n];
        float a = 0.0f, b = 0.0f;
        while (m) {
            int k = (int)__builtin_ctzll(m);
            m &= m - 1;
            a += sA[k * 64 + lane];
            b += sB[k * 64 + lane];
        }
        size_t o = (size_t)n * 64 + lane;
        oa[o] = a;
        ob[o] = b;
    }
}

// ---------------- gathers: out[n] = sum_e norm_e*xw[src_e] + d2i[n]*xw[n] + b ----

__global__ __launch_bounds__(256) void gather_k(const float* __restrict__ xw,
                                                const int2* __restrict__ em,
                                                const int* __restrict__ rp,
                                                const float* __restrict__ d2i,
                                                const float* __restrict__ bias,
                                                float* __restrict__ out) {
    int tid = threadIdx.x, lane = tid & 63;
    int n = blockIdx.x * 4 + (tid >> 6);
    int beg = rp[n], end = rp[n + 1];
    float self = d2i[n] * xw[(size_t)n * 64 + lane] + bias[lane];
    float acc = 0.0f;
    for (int base = beg; base < end; base += 64) {
        int cnt = min(64, end - base);
        int2 m = make_int2(0, 0);
        if (base + lane < end) m = em[base + lane];
        int j = 0;
        for (; j + 8 <= cnt; j += 8) {
            int s0 = __shfl(m.x, j, 64),     s1 = __shfl(m.x, j + 1, 64);
            int s2 = __shfl(m.x, j + 2, 64), s3 = __shfl(m.x, j + 3, 64);
            int s4 = __shfl(m.x, j + 4, 64), s5 = __shfl(m.x, j + 5, 64);
            int s6 = __shfl(m.x, j + 6, 64), s7 = __shfl(m.x, j + 7, 64);
            float n0 = __int_as_float(__shfl(m.y, j, 64));
            float n1 = __int_as_float(__shfl(m.y, j + 1, 64));
            float n2 = __int_as_float(__shfl(m.y, j + 2, 64));
            float n3 = __int_as_float(__shfl(m.y, j + 3, 64));
            float n4 = __int_as_float(__shfl(m.y, j + 4, 64));
            float n5 = __int_as_float(__shfl(m.y, j + 5, 64));
            float n6 = __int_as_float(__shfl(m.y, j + 6, 64));
            float n7 = __int_as_float(__shfl(m.y, j + 7, 64));
            float v0 = xw[(size_t)s0 * 64 + lane];
            float v1 = xw[(size_t)s1 * 64 + lane];
            float v2 = xw[(size_t)s2 * 64 + lane];
            float v3 = xw[(size_t)s3 * 64 + lane];
            float v4 = xw[(size_t)s4 * 64 + lane];
            float v5 = xw[(size_t)s5 * 64 + lane];
            float v6 = xw[(size_t)s6 * 64 + lane];
            float v7 = xw[(size_t)s7 * 64 + lane];
            acc += n0 * v0; acc += n1 * v1; acc += n2 * v2; acc += n3 * v3;
            acc += n4 * v4; acc += n5 * v5; acc += n6 * v6; acc += n7 * v7;
        }
        for (; j < cnt; j++) {
            int s = __shfl(m.x, j, 64);
            float nv = __int_as_float(__shfl(m.y, j, 64));
            acc += nv * xw[(size_t)s * 64 + lane];
        }
    }
    out[(size_t)n * 64 + lane] = acc + self;
}

__global__ __launch_bounds__(256) void gather2_k(const float* __restrict__ xa,
                                                 const float* __restrict__ xb,
                                                 const int2* __restrict__ em,
                                                 const int* __restrict__ rp,
                                                 const float* __restrict__ d2i,
                                                 const float* __restrict__ ba,
                                                 const float* __restrict__ bb,
                                                 float* __restrict__ oa,
                                                 float* __restrict__ ob) {
    int tid = threadIdx.x, lane = tid & 63;
    int n = blockIdx.x * 4 + (tid >> 6);
    int beg = rp[n], end = rp[n + 1];
    float selfa = d2i[n] * xa[(size_t)n * 64 + lane] + ba[lane];
    float selfb = d2i[n] * xb[(size_t)n * 64 + lane] + bb[lane];
    float acca = 0.0f, accb = 0.0f;
    for (int base = beg; base < end; base += 64) {
        int cnt = min(64, end - base);
        int2 m = make_int2(0, 0);
        if (base + lane < end) m = em[base + lane];
        int j = 0;
        for (; j + 4 <= cnt; j += 4) {
            int s0 = __shfl(m.x, j, 64),     s1 = __shfl(m.x, j + 1, 64);
            int s2 = __shfl(m.x, j + 2, 64), s3 = __shfl(m.x, j + 3, 64);
            float n0 = __int_as_float(__shfl(m.y, j, 64));
            float n1 = __int_as_float(__shfl(m.y, j + 1, 64));
            float n2 = __int_as_float(__shfl(m.y, j + 2, 64));
            float n3 = __int_as_float(__shfl(m.y, j + 3, 64));
            float a0 = xa[(size_t)s0 * 64 + lane];
            float b0 = xb[(size_t)s0 * 64 + lane];
            float a1 = xa[(size_t)s1 * 64 + lane];
            float b1 = xb[(size_t)s1 * 64 + lane];
            float a2 = xa[(size_t)s2 * 64 + lane];
            float b2 = xb[(size_t)s2 * 64 + lane];
            float a3 = xa[(size_t)s3 * 64 + lane];
            float b3 = xb[(size_t)s3 * 64 + lane];
            acca += n0 * a0; accb += n0 * b0;
            acca += n1 * a1; accb += n1 * b1;
            acca += n2 * a2; accb += n2 * b2;
            acca += n3 * a3; accb += n3 * b3;
        }
        for (; j < cnt; j++) {
            int s = __shfl(m.x, j, 64);
            float nv = __int_as_float(__shfl(m.y, j, 64));
            acca += nv * xa[(size_t)s * 64 + lane];
            accb += nv * xb[(size_t)s * 64 + lane];
        }
    }
    size_t o = (size_t)n * 64 + lane;
    oa[o] = acca + selfa;
    ob[o] = accb + selfb;
}

// ---------------- batchnorm stats: deterministic partials + parallel reduce ----

__global__ __launch_bounds__(256) void bn_part_k(const float* __restrict__ x,
                                                 double* __restrict__ part) {
    int tid = threadIdx.x;
    int c = tid & 63, g = tid >> 6;
    double s = 0.0, s2 = 0.0;
    for (int row = blockIdx.x * 4 + g; row < NN; row += gridDim.x * 4) {
        float v = x[(size_t)row * 64 + c];
        s += (double)v;
        s2 += (double)v * (double)v;
    }
    __shared__ double ls[256], ls2[256];
    ls[tid] = s; ls2[tid] = s2;
    __syncthreads();
    if (tid < 128) { ls[tid] += ls[tid + 128]; ls2[tid] += ls2[tid + 128]; }
    __syncthreads();
    if (tid < 64) {
        part[(size_t)blockIdx.x * 128 + c] = ls[tid] + ls[tid + 64];
        part[(size_t)blockIdx.x * 128 + 64 + c] = ls2[tid] + ls2[tid + 64];
    }
}

// one block per stat column; fixed LDS tree over the 256 partials
__global__ __launch_bounds__(256) void bn_red_k(const double* __restrict__ part,
                                                double* __restrict__ st) {
    __shared__ double tr[256];
    int t = threadIdx.x, c = blockIdx.x;     // c in [0,128)
    tr[t] = part[(size_t)t * 128 + c];
    __syncthreads();
    for (int off = 128; off > 0; off >>= 1) {
        if (t < off) tr[t] += tr[t + off];
        __syncthreads();
    }
    if (t == 0) st[c] = tr[0];
}

__global__ __launch_bounds__(256) void bn_part2_k(const float* __restrict__ xa,
                                                  const float* __restrict__ xb,
                                                  double* __restrict__ part) {
    int tid = threadIdx.x;
    int c = tid & 63, g = tid >> 6;
    double sa = 0.0, sa2 = 0.0, sb = 0.0, sb2 = 0.0;
    for (int row = blockIdx.x * 4 + g; row < NN; row += gridDim.x * 4) {
        float va = xa[(size_t)row * 64 + c];
        sa += (double)va; sa2 += (double)va * (double)va;
        float vb = xb[(size_t)row * 64 + c];
        sb += (double)vb; sb2 += (double)vb * (double)vb;
    }
    __shared__ double l1[256], l2[256], l3[256], l4[256];
    l1[tid] = sa; l2[tid] = sa2; l3[tid] = sb; l4[tid] = sb2;
    __syncthreads();
    if (tid < 128) {
        l1[tid] += l1[tid + 128]; l2[tid] += l2[tid + 128];
        l3[tid] += l3[tid + 128]; l4[tid] += l4[tid + 128];
    }
    __syncthreads();
    if (tid < 64) {
        size_t o = (size_t)blockIdx.x * 256;
        part[o + c] = l1[tid] + l1[tid + 64];
        part[o + 64 + c] = l2[tid] + l2[tid + 64];
        part[o + 128 + c] = l3[tid] + l3[tid + 64];
        part[o + 192 + c] = l4[tid] + l4[tid + 64];
    }
}

__global__ __launch_bounds__(256) void bn_red2_k(const double* __restrict__ part,
                                                 double* __restrict__ sta,
                                                 double* __restrict__ stb) {
    __shared__ double tr[256];
    int t = threadIdx.x, c = blockIdx.x;     // c in [0,256)
    tr[t] = part[(size_t)t * 256 + c];
    __syncthreads();
    for (int off = 128; off > 0; off >>= 1) {
        if (t < off) tr[t] += tr[t + off];
        __syncthreads();
    }
    if (t == 0) {
        if (c < 128) sta[c] = tr[0];
        else stb[c - 128] = tr[0];
    }
}

// per-block bn scale/shift preamble (c < 64)
__device__ inline void bn_ss(const double* __restrict__ st, const float* __restrict__ gam,
                             const float* __restrict__ bet, int c,
                             float* __restrict__ ssc, float* __restrict__ ssh) {
    double m = st[c] * (1.0 / NN);
    double v = st[64 + c] * (1.0 / NN) - m * m;
    float scale = (float)((double)gam[c] / sqrt(v + (double)EPSF));
    ssc[c] = scale;
    ssh[c] = bet[c] - (float)m * scale;
}

// ---------------- fused elementwise steps (bit spike outputs) ----------------

__global__ __launch_bounds__(256) void lif_conv_bits_k(const float* __restrict__ G,
                                                       const double* __restrict__ st,
                                                       const float* __restrict__ gam,
                                                       const float* __restrict__ bet,
                                                       float* __restrict__ vconv,
                                                       u64* __restrict__ bits) {
    __shared__ float ssc[64], ssh[64];
    int tid = threadIdx.x;
    if (tid < 64) bn_ss(st, gam, bet, tid, ssc, ssh);
    __syncthreads();
    size_t i = (size_t)blockIdx.x * 256 + tid;
    int c = tid & 63;
    float v = vconv[i] + (G[i] * ssc[c] + ssh[c]);
    bool sp = (v - THF >= 0.0f);
    u64 bal = __ballot(sp);
    vconv[i] = sp ? 0.0f : v;
    if (c == 0) bits[i >> 6] = bal;
}

__global__ __launch_bounds__(256) void bn_spike_bits_k(const float* __restrict__ G,
                                                       const double* __restrict__ st,
                                                       const float* __restrict__ gam,
                                                       const float* __restrict__ bet,
                                                       float* __restrict__ x3,
                                                       u64* __restrict__ bits) {
    __shared__ float ssc[64], ssh[64];
    int tid = threadIdx.x;
    if (tid < 64) bn_ss(st, gam, bet, tid, ssc, ssh);
    __syncthreads();
    size_t i = (size_t)blockIdx.x * 256 + tid;
    int c = tid & 63;
    float xv = G[i] * ssc[c] + ssh[c];
    x3[i] = xv;
    u64 bal = __ballot(xv - THF >= 0.0f);
    if (c == 0) bits[i >> 6] = bal;
}

__global__ __launch_bounds__(256) void bn_add_k(const float* __restrict__ G,
                                                const double* __restrict__ st,
                                                const float* __restrict__ gam,
                                                const float* __restrict__ bet,
                                                const float* __restrict__ x3,
                                                float* __restrict__ F) {
    __shared__ float ssc[64], ssh[64];
    int tid = threadIdx.x;
    if (tid < 64) bn_ss(st, gam, bet, tid, ssc, ssh);
    __syncthreads();
    size_t i = (size_t)blockIdx.x * 256 + tid;
    int c = tid & 63;
    F[i] = (G[i] * ssc[c] + ssh[c]) + x3[i];
}

__global__ __launch_bounds__(256) void bn_lif_bits_k(const float* __restrict__ F,
                                                     const double* __restrict__ st,
                                                     const float* __restrict__ gam,
                                                     const float* __restrict__ bet,
                                                     float* __restrict__ vconv,
                                                     float* __restrict__ x4,
                                                     u64* __restrict__ bits) {
    __shared__ float ssc[64], ssh[64];
    int tid = threadIdx.x;
    if (tid < 64) bn_ss(st, gam, bet, tid, ssc, ssh);
    __syncthreads();
    size_t i = (size_t)blockIdx.x * 256 + tid;
    int c = tid & 63;
    float xv = F[i] * ssc[c] + ssh[c];
    x4[i] = xv;
    float v = vconv[i] + xv;
    bool sp = (v - THF >= 0.0f);
    u64 bal = __ballot(sp);
    vconv[i] = sp ? 0.0f : v;
    if (c == 0) bits[i >> 6] = bal;
}

// fused q,k,v spikes + qk popcount + att bits (one wave per node)
__global__ __launch_bounds__(256) void qkv_att_bits_k(const float* __restrict__ Gq,
                                                      const float* __restrict__ Gk,
                                                      const float* __restrict__ Gv,
                                                      const double* __restrict__ st4,
                                                      const double* __restrict__ st5,
                                                      const double* __restrict__ st6,
                                                      const float* __restrict__ gam4,
                                                      const float* __restrict__ bet4,
                                                      const float* __restrict__ gam5,
                                                      const float* __restrict__ bet5,
                                                      const float* __restrict__ gam6,
                                                      const float* __restrict__ bet6,
                                                      u64* __restrict__ bits) {
    __shared__ float sc4[64], sh4[64], sc5[64], sh5[64], sc6[64], sh6[64];
    int tid = threadIdx.x;
    if (tid < 64) {
        bn_ss(st4, gam4, bet4, tid, sc4, sh4);
        bn_ss(st5, gam5, bet5, tid, sc5, sh5);
        bn_ss(st6, gam6, bet6, tid, sc6, sh6);
    }
    __syncthreads();
    size_t i = (size_t)blockIdx.x * 256 + tid;
    int c = tid & 63;
    bool qb = (Gq[i] * sc4[c] + sh4[c] - THF >= 0.0f);
    bool kb = (Gk[i] * sc5[c] + sh5[c] - THF >= 0.0f);
    bool vb = (Gv[i] * sc6[c] + sh6[c] - THF >= 0.0f);
    int pc = __popcll(__ballot(qb && kb));
    bool qs = ((float)pc * (1.0f / 64.0f) - ATTTH >= 0.0f);
    u64 bal = __ballot(vb && qs);
    if (c == 0) bits[i >> 6] = bal;
}

__global__ __launch_bounds__(256) void bn_scale_add_k(const float* __restrict__ G,
                                                      const double* __restrict__ st,
                                                      const float* __restrict__ gam,
                                                      const float* __restrict__ bet,
                                                      const float* __restrict__ x4,
                                                      float* __restrict__ tmp2) {
    __shared__ float ssc[64], ssh[64];
    int tid = threadIdx.x;
    if (tid < 64) bn_ss(st, gam, bet, tid, ssc, ssh);
    __syncthreads();
    size_t i = (size_t)blockIdx.x * 256 + tid;
    int c = tid & 63;
    tmp2[i] = x4[i] + 0.125f * (G[i] * ssc[c] + ssh[c]);
}

__global__ __launch_bounds__(256) void decode_k(const float* __restrict__ tmp2,
                                                const double* __restrict__ st,
                                                const float* __restrict__ gam,
                                                const float* __restrict__ bet,
                                                const float* __restrict__ wrow,
                                                float* __restrict__ z) {
    __shared__ float ssc[64], ssh[64];
    int tid = threadIdx.x;
    if (tid < 64) bn_ss(st, gam, bet, tid, ssc, ssh);
    __syncthreads();
    int lane = tid & 63;
    int row = blockIdx.x * 4 + (tid >> 6);
    float sv = tmp2[(size_t)row * 64 + lane] * ssc[lane] + ssh[lane];
    float p = sv * wrow[lane];
#pragma unroll
    for (int off = 32; off > 0; off >>= 1) p += __shfl_xor(p, off, 64);
    if (lane == 0) z[row] = p;
}

__global__ void wrow_k(const float* __restrict__ W_lin, float* __restrict__ wrow) {
    int h = threadIdx.x;
    if (h >= 64) return;
    float s = 0.0f;
    for (int j = 0; j < 64; j++) s += W_lin[h * 64 + j];
    wrow[h] = s;
}

// ---------------- host driver ----------------

extern "C" void kernel_launch(void* const* d_in, const int* in_sizes, int n_in,
                              void* d_out, int out_size, void* d_ws, size_t ws_size,
                              hipStream_t stream) {
    const float* x    = (const float*)d_in[0];
    const int* eidx   = (const int*)d_in[1];
    const int* emask  = (const int*)d_in[2];
    const float* Wg   = (const float*)d_in[3];
    const float* bg   = (const float*)d_in[4];
    const float* bng  = (const float*)d_in[5];
    const float* bnb  = (const float*)d_in[6];
    const float* Wlin = (const float*)d_in[7];
    float* zout = (float*)d_out;

    const int* srcp = eidx;
    const int* dstp = eidx + NE;
    const size_t NH = (size_t)NN * HH;

    // ---- workspace layout (8B-aligned chain: all counts before doubles are even) ----
    float* fb = (float*)d_ws;
    float* P1 = fb;
    float* P2 = P1 + NH;
    float* P3 = P2 + NH;
    float* P4 = P3 + NH;
    float* P5 = P4 + NH;
    float* vconv = P5 + NH;                      // 6*NH floats (even)
    int2* em1 = (int2*)(vconv + NH);             // NE
    int2* em2 = em1 + NE;                        // EM2CAP
    u64* sbits = (u64*)(em2 + EM2CAP);           // NN
    double* part = (double*)(sbits + NN);        // 256*256 doubles
    double* stats = part + 256 * 256;            // 18*128 doubles
    float* dis1 = (float*)(stats + 18 * 128);
    float* d21  = dis1 + NN;
    float* dis2m = d21 + NN;
    float* d22  = dis2m + NN;
    float* wrow = d22 + NN;                      // 64
    int* rp1 = (int*)(wrow + 64);                // NN+1
    int* rp2 = rp1 + NN + 2;                     // NN+1
    int* cnt1 = rp2 + NN + 2;                    // 4*NN contiguous (one memset)
    int* cnt2 = cnt1 + NN;
    int* cur1 = cnt2 + NN;
    int* cur2 = cur1 + NN;
    int* bsum = cur2 + NN;                       // SCAN_B

    hipMemsetAsync(cnt1, 0, 4 * NN * sizeof(int), stream);
    hipMemsetAsync(vconv, 0, NH * sizeof(float), stream);

    const int NB_EDGE = NE / 256;        // 6250
    const int NB_NODE = SCAN_B;          // 391
    const int NB_ROW4 = NN / 4;          // 25000
    const int NB_GEMM = NN / 32;         // 3125
    const int NB_BG   = (NN + 63) / 64;  // 1563

    wrow_k<<<1, 64, 0, stream>>>(Wlin, wrow);
    hist_k<<<NB_EDGE, 256, 0, stream>>>(dstp, emask, cnt1, cnt2);
    deg_inv2_k<<<NB_NODE, 256, 0, stream>>>(cnt1, cnt2, dis1, d21, dis2m, d22);
    scan1_k<<<NB_NODE, 256, 0, stream>>>(cnt1, rp1, bsum);
    scan2_k<<<1, 512, 0, stream>>>(bsum, rp1);
    scan3_k<<<NB_NODE, 256, 0, stream>>>(rp1, bsum);
    scan1_k<<<NB_NODE, 256, 0, stream>>>(cnt2, rp2, bsum);
    scan2_k<<<1, 512, 0, stream>>>(bsum, rp2);
    scan3_k<<<NB_NODE, 256, 0, stream>>>(rp2, bsum);
    csr_fill_k<<<NB_EDGE, 256, 0, stream>>>(srcp, dstp, emask, dis1, dis2m,
                                            rp1, rp2, cur1, cur2, em1, em2);
    seg_sort_k<<<NB_ROW4, 256, 0, stream>>>(em1, rp1);
    seg_sort_k<<<NB_ROW4, 256, 0, stream>>>(em2, rp2);

    auto enc = [&](const int2* em, const int* rp, const float* d2i, int bnbase,
                   float* zo) {
        auto ST = [&](int bni) { return stats + (bnbase + bni) * 128; };
        auto W = [&](int wi) { return Wg + wi * 4096; };
        auto BI = [&](int wi) { return bg + wi * 64; };
        auto GM = [&](int bi) { return bng + bi * 64; };
        auto BT = [&](int bi) { return bnb + bi * 64; };
        auto stats_run = [&](const float* buf, int bni) {
            bn_part_k<<<256, 256, 0, stream>>>(buf, part);
            bn_red_k<<<128, 256, 0, stream>>>(part, ST(bni));
        };

        // layer 0 (float input)
        gemm_k<<<NB_GEMM, 256, 0, stream>>>(x, W(0), P1);
        gather_k<<<NB_ROW4, 256, 0, stream>>>(P1, em, rp, d2i, BI(0), P2);
        stats_run(P2, 0);
        lif_conv_bits_k<<<NB_ROW4, 256, 0, stream>>>(P2, ST(0), GM(0), BT(0),
                                                     vconv, sbits);
        // layer 1
        bitgemm_k<<<NB_BG, 256, 0, stream>>>(sbits, W(1), P1);
        gather_k<<<NB_ROW4, 256, 0, stream>>>(P1, em, rp, d2i, BI(1), P2);
        stats_run(P2, 1);
        bn_spike_bits_k<<<NB_ROW4, 256, 0, stream>>>(P2, ST(1), GM(1), BT(1),
                                                     P3, sbits);    // x3=P3
        // pos layer
        bitgemm_k<<<NB_BG, 256, 0, stream>>>(sbits, W(2), P1);
        gather_k<<<NB_ROW4, 256, 0, stream>>>(P1, em, rp, d2i, BI(2), P2);
        stats_run(P2, 2);
        bn_add_k<<<NB_ROW4, 256, 0, stream>>>(P2, ST(2), GM(2), BT(2), P3, P4); // F=P4
        stats_run(P4, 3);
        bn_lif_bits_k<<<NB_ROW4, 256, 0, stream>>>(P4, ST(3), GM(3), BT(3),
                                                   vconv, P2, sbits); // x4=P2
        // q,k (pair-fused)
        bitgemm2_k<<<NB_BG, 256, 0, stream>>>(sbits, W(3), W(4), P1, P3);
        gather2_k<<<NB_ROW4, 256, 0, stream>>>(P1, P3, em, rp, d2i, BI(3), BI(4),
                                               P4, P5);
        bn_part2_k<<<256, 256, 0, stream>>>(P4, P5, part);
        bn_red2_k<<<256, 256, 0, stream>>>(part, ST(4), ST(5));
        // v
        bitgemm_k<<<NB_BG, 256, 0, stream>>>(sbits, W(5), P1);
        gather_k<<<NB_ROW4, 256, 0, stream>>>(P1, em, rp, d2i, BI(5), P3);
        stats_run(P3, 6);
        // fused q,k,v spikes -> att bits
        qkv_att_bits_k<<<NB_ROW4, 256, 0, stream>>>(P4, P5, P3, ST(4), ST(5), ST(6),
                                                    GM(4), BT(4), GM(5), BT(5),
                                                    GM(6), BT(6), sbits);
        // att gcn
        bitgemm_k<<<NB_BG, 256, 0, stream>>>(sbits, W(6), P1);
        gather_k<<<NB_ROW4, 256, 0, stream>>>(P1, em, rp, d2i, BI(6), P3);
        stats_run(P3, 7);
        bn_scale_add_k<<<NB_ROW4, 256, 0, stream>>>(P3, ST(7), GM(7), BT(7),
                                                    P2, P4);   // tmp2=P4 (x4=P2)
        stats_run(P4, 8);
        decode_k<<<NB_ROW4, 256, 0, stream>>>(P4, ST(8), GM(8), BT(8), wrow, zo);
    };

    enc(em1, rp1, d21, 0, zout);
    enc(em2, rp2, d22, 9, zout + NN);
}

// Round 9
// 1892.899 us; speedup vs baseline: 1.3105x; 1.2038x over previous
//
#include <hip/hip_runtime.h>
#include <math.h>
#include <stdint.h>
#include <limits.h>

#define NN 100000
#define NE 1600000
#define HH 64
#define THF 0.7f
#define ATTTH 0.2f
#define EPSF 1e-5f
#define SCAN_B ((NN + 255) / 256)   // 391
#define EM2CAP 1000000
#define NBE 2048                    // stats-fused producer grid
#define NHTOT ((size_t)NN * 64)

typedef unsigned long long u64;

// ---------------- setup: histogram, degree, scans, CSR fill ----------------

__global__ void hist_k(const int* __restrict__ dst, const int* __restrict__ mask,
                       int* __restrict__ cnt_all, int* __restrict__ cnt_mask) {
    int e = blockIdx.x * 256 + threadIdx.x;
    if (e >= NE) return;
    int d = dst[e];
    atomicAdd(&cnt_all[d], 1);          // integer atomics: value-deterministic
    if (mask[e]) atomicAdd(&cnt_mask[d], 1);
}

__global__ void deg_inv2_k(const int* __restrict__ cnt1, const int* __restrict__ cnt2,
                           float* __restrict__ dis1, float* __restrict__ d21,
                           float* __restrict__ dis2m, float* __restrict__ d22) {
    int i = blockIdx.x * 256 + threadIdx.x;
    if (i < NN) {
        float dg1 = (float)(cnt1[i] + 1);   // +1 self loop
        dis1[i] = 1.0f / sqrtf(dg1);
        d21[i] = 1.0f / dg1;
        float dg2 = (float)(cnt2[i] + 1);
        dis2m[i] = 1.0f / sqrtf(dg2);
        d22[i] = 1.0f / dg2;
    }
}

__global__ void scan1_k(const int* __restrict__ counts, int* __restrict__ rp,
                        int* __restrict__ bsum) {
    __shared__ int ls[256];
    int i = blockIdx.x * 256 + threadIdx.x;
    int v = (i < NN) ? counts[i] : 0;
    ls[threadIdx.x] = v;
    __syncthreads();
    for (int off = 1; off < 256; off <<= 1) {
        int t = (threadIdx.x >= off) ? ls[threadIdx.x - off] : 0;
        __syncthreads();
        ls[threadIdx.x] += t;
        __syncthreads();
    }
    if (i < NN) rp[i] = ls[threadIdx.x] - v;
    if (threadIdx.x == 255) bsum[blockIdx.x] = ls[255];
}

// parallel block-sum scan: one 512-thread block (SCAN_B=391 < 512), fixed order
__global__ __launch_bounds__(512) void scan2_k(int* __restrict__ bsum,
                                               int* __restrict__ rp) {
    __shared__ int ls[512];
    int i = threadIdx.x;
    int v = (i < SCAN_B) ? bsum[i] : 0;
    ls[i] = v;
    __syncthreads();
    for (int off = 1; off < 512; off <<= 1) {
        int t = (i >= off) ? ls[i - off] : 0;
        __syncthreads();
        ls[i] += t;
        __syncthreads();
    }
    if (i < SCAN_B) bsum[i] = ls[i] - v;      // exclusive
    if (i == SCAN_B - 1) rp[NN] = ls[i];
}

__global__ void scan3_k(int* __restrict__ rp, const int* __restrict__ bsum) {
    int i = blockIdx.x * 256 + threadIdx.x;
    if (i < NN) rp[i] += bsum[blockIdx.x];
}

// fills both CSRs (atomic cursors; layout made deterministic by seg_sort)
__global__ void csr_fill_k(const int* __restrict__ src, const int* __restrict__ dst,
                           const int* __restrict__ mask,
                           const float* __restrict__ dis1, const float* __restrict__ dis2m,
                           const int* __restrict__ rp1, const int* __restrict__ rp2,
                           int* __restrict__ cur1, int* __restrict__ cur2,
                           int2* __restrict__ em1, int2* __restrict__ em2) {
    int e = blockIdx.x * 256 + threadIdx.x;
    if (e >= NE) return;
    int s = src[e], d = dst[e];
    float n1 = dis1[s] * dis1[d];
    int p1 = rp1[d] + atomicAdd(&cur1[d], 1);
    em1[p1] = make_int2(s, __float_as_int(n1));
    if (mask[e]) {
        float n2 = dis2m[s] * dis2m[d];
        int p2 = rp2[d] + atomicAdd(&cur2[d], 1);
        em2[p2] = make_int2(s, __float_as_int(n2));
    }
}

// sort each dst segment by src (= em.x). Duplicate srcs have identical payloads
// (same norm), so leader-pick loses nothing. Result: run-invariant layout.
__global__ __launch_bounds__(256) void seg_sort_k(int2* __restrict__ em,
                                                  const int* __restrict__ rp) {
    __shared__ int skey[4][512];
    __shared__ int snrm[4][512];
    int tid = threadIdx.x, lane = tid & 63, w = tid >> 6;
    int n = blockIdx.x * 4 + w;
    int beg = rp[n], end = rp[n + 1];
    int L = end - beg;
    if (L <= 1) return;
    if (L <= 64) {
        int k = INT_MAX; int2 pl = make_int2(0, 0);
        if (lane < L) { pl = em[beg + lane]; k = pl.x; }
        for (int r = 0; r < L; r++) {
            int mn = k;
#pragma unroll
            for (int off = 32; off > 0; off >>= 1)
                mn = min(mn, __shfl_xor(mn, off, 64));
            u64 msk = __ballot(k == mn);
            int leader = (int)__ffsll((unsigned long long)msk) - 1;
            if (lane == leader) { em[beg + r] = pl; k = INT_MAX; }
        }
    } else if (L <= 512) {
        for (int i = lane; i < L; i += 64) {
            int2 p = em[beg + i];
            skey[w][i] = p.x;
            snrm[w][i] = p.y;
        }
        for (int it = 0; it < L; it++) {
            int par = it & 1;
            for (int p = par + 2 * lane; p + 1 < L; p += 128) {
                int ka = skey[w][p], kb = skey[w][p + 1];
                if (kb < ka) {
                    skey[w][p] = kb; skey[w][p + 1] = ka;
                    int t = snrm[w][p]; snrm[w][p] = snrm[w][p + 1]; snrm[w][p + 1] = t;
                }
            }
        }
        for (int i = lane; i < L; i += 64)
            em[beg + i] = make_int2(skey[w][i], snrm[w][i]);
    }
}

// ---------------- GEMM (float input, layer 0 only) ----------------

__global__ __launch_bounds__(256) void gemm_k(const float* __restrict__ in,
                                              const float* __restrict__ W,
                                              float* __restrict__ xw) {
    __shared__ float sW[64 * 64];
    __shared__ float sx[32 * 65];
    int tid = threadIdx.x;
    const float4* W4 = (const float4*)W;
    float4* sW4 = (float4*)sW;
    for (int i = tid; i < 1024; i += 256) sW4[i] = W4[i];
    const float* inb = in + (size_t)blockIdx.x * 2048;
    for (int i = tid; i < 2048; i += 256) sx[(i >> 6) * 65 + (i & 63)] = inb[i];
    __syncthreads();
    int cg = tid & 15, rr = tid >> 4;
    float a0 = 0, a1 = 0, a2 = 0, a3 = 0, c0 = 0, c1 = 0, c2 = 0, c3 = 0;
#pragma unroll
    for (int k = 0; k < 64; k++) {
        float4 wv = *(const float4*)&sW[k * 64 + cg * 4];
        float xa = sx[rr * 65 + k];
        float xb = sx[(rr + 16) * 65 + k];
        a0 += xa * wv.x; a1 += xa * wv.y; a2 += xa * wv.z; a3 += xa * wv.w;
        c0 += xb * wv.x; c1 += xb * wv.y; c2 += xb * wv.z; c3 += xb * wv.w;
    }
    size_t r0 = (size_t)(blockIdx.x * 32 + rr) * 64 + cg * 4;
    size_t r1 = (size_t)(blockIdx.x * 32 + rr + 16) * 64 + cg * 4;
    *(float4*)&xw[r0] = make_float4(a0, a1, a2, a3);
    *(float4*)&xw[r1] = make_float4(c0, c1, c2, c3);
}

// ---------------- bit GEMM ----------------

__global__ __launch_bounds__(256) void bitgemm_k(const u64* __restrict__ bits,
                                                 const float* __restrict__ W,
                                                 float* __restrict__ xw) {
    __shared__ float sW[64 * 64];
    int tid = threadIdx.x;
    const float4* W4 = (const float4*)W;
    float4* sW4 = (float4*)sW;
    for (int i = tid; i < 1024; i += 256) sW4[i] = W4[i];
    __syncthreads();
    int lane = tid & 63, w = tid >> 6;
    int n0 = blockIdx.x * 64 + w * 16;
    for (int t = 0; t < 16; t++) {
        int n = n0 + t;
        if (n >= NN) return;
        u64 m = bits[n];
        float acc = 0.0f;
        while (m) {
            int k = (int)__builtin_ctzll(m);
            m &= m - 1;
            acc += sW[k * 64 + lane];
        }
        xw[(size_t)n * 64 + lane] = acc;
    }
}

__global__ __launch_bounds__(256) void bitgemm2_k(const u64* __restrict__ bits,
                                                  const float* __restrict__ Wa,
                                                  const float* __restrict__ Wb,
                                                  float* __restrict__ oa,
                                                  float* __restrict__ ob) {
    __shared__ float sA[64 * 64];
    __shared__ float sB[64 * 64];
    int tid = threadIdx.x;
    const float4* A4 = (const float4*)Wa;
    const float4* B4 = (const float4*)Wb;
    float4* sA4 = (float4*)sA;
    float4* sB4 = (float4*)sB;
    for (int i = tid; i < 1024; i += 256) { sA4[i] = A4[i]; sB4[i] = B4[i]; }
    __syncthreads();
    int lane = tid & 63, w = tid >> 6;
    int n0 = blockIdx.x * 64 + w * 16;
    for (int t = 0; t < 16; t++) {
        int n = n0 + t;
        if (n >= NN) return;
        u64 m = bits[n];
        float a = 0.0f, b = 0.0f;
        while (m) {
            int k = (int)__builtin_ctzll(m);
            m &= m - 1;
            a += sA[k * 64 + lane];
            b += sB[k * 64 + lane];
        }
        size_t o = (size_t)n * 64 + lane;
        oa[o] = a;
        ob[o] = b;
    }
}

// ---------------- stats-fused gathers ----------------
// out[n] = sum_e norm_e*xw[src_e] + d2i[n]*xw[n] + b ; per-node order unchanged.
// Grid NBE blocks x 4 waves, node-strided; deterministic per-block partials.

__global__ __launch_bounds__(256) void gather_stats_k(const float* __restrict__ xw,
                                                      const int2* __restrict__ em,
                                                      const int* __restrict__ rp,
                                                      const float* __restrict__ d2i,
                                                      const float* __restrict__ bias,
                                                      float* __restrict__ out,
                                                      double* __restrict__ part) {
    int tid = threadIdx.x, lane = tid & 63, w = tid >> 6;
    double ps = 0.0, pq = 0.0;
    for (int n = blockIdx.x * 4 + w; n < NN; n += NBE * 4) {
        int beg = rp[n], end = rp[n + 1];
        float self = d2i[n] * xw[(size_t)n * 64 + lane] + bias[lane];
        float acc = 0.0f;
        for (int base = beg; base < end; base += 64) {
            int cnt = min(64, end - base);
            int2 m = make_int2(0, 0);
            if (base + lane < end) m = em[base + lane];
            int j = 0;
            for (; j + 8 <= cnt; j += 8) {
                int s0 = __shfl(m.x, j, 64),     s1 = __shfl(m.x, j + 1, 64);
                int s2 = __shfl(m.x, j + 2, 64), s3 = __shfl(m.x, j + 3, 64);
                int s4 = __shfl(m.x, j + 4, 64), s5 = __shfl(m.x, j + 5, 64);
                int s6 = __shfl(m.x, j + 6, 64), s7 = __shfl(m.x, j + 7, 64);
                float n0 = __int_as_float(__shfl(m.y, j, 64));
                float n1 = __int_as_float(__shfl(m.y, j + 1, 64));
                float n2 = __int_as_float(__shfl(m.y, j + 2, 64));
                float n3 = __int_as_float(__shfl(m.y, j + 3, 64));
                float n4 = __int_as_float(__shfl(m.y, j + 4, 64));
                float n5 = __int_as_float(__shfl(m.y, j + 5, 64));
                float n6 = __int_as_float(__shfl(m.y, j + 6, 64));
                float n7 = __int_as_float(__shfl(m.y, j + 7, 64));
                float v0 = xw[(size_t)s0 * 64 + lane];
                float v1 = xw[(size_t)s1 * 64 + lane];
                float v2 = xw[(size_t)s2 * 64 + lane];
                float v3 = xw[(size_t)s3 * 64 + lane];
                float v4 = xw[(size_t)s4 * 64 + lane];
                float v5 = xw[(size_t)s5 * 64 + lane];
                float v6 = xw[(size_t)s6 * 64 + lane];
                float v7 = xw[(size_t)s7 * 64 + lane];
                acc += n0 * v0; acc += n1 * v1; acc += n2 * v2; acc += n3 * v3;
                acc += n4 * v4; acc += n5 * v5; acc += n6 * v6; acc += n7 * v7;
            }
            for (; j < cnt; j++) {
                int s = __shfl(m.x, j, 64);
                float nv = __int_as_float(__shfl(m.y, j, 64));
                acc += nv * xw[(size_t)s * 64 + lane];
            }
        }
        float o = acc + self;
        out[(size_t)n * 64 + lane] = o;
        ps += (double)o;
        pq += (double)o * (double)o;
    }
    __shared__ double ls[4][64], lq[4][64];
    ls[w][lane] = ps; lq[w][lane] = pq;
    __syncthreads();
    if (tid < 64) {
        double a = ls[0][tid] + ls[1][tid] + ls[2][tid] + ls[3][tid];
        double b = lq[0][tid] + lq[1][tid] + lq[2][tid] + lq[3][tid];
        part[(size_t)blockIdx.x * 128 + tid] = a;
        part[(size_t)blockIdx.x * 128 + 64 + tid] = b;
    }
}

__global__ __launch_bounds__(256) void gather2_stats_k(const float* __restrict__ xa,
                                                       const float* __restrict__ xb,
                                                       const int2* __restrict__ em,
                                                       const int* __restrict__ rp,
                                                       const float* __restrict__ d2i,
                                                       const float* __restrict__ ba,
                                                       const float* __restrict__ bb,
                                                       float* __restrict__ oa,
                                                       float* __restrict__ ob,
                                                       double* __restrict__ part) {
    int tid = threadIdx.x, lane = tid & 63, w = tid >> 6;
    double sa = 0.0, sa2 = 0.0, sb = 0.0, sb2 = 0.0;
    for (int n = blockIdx.x * 4 + w; n < NN; n += NBE * 4) {
        int beg = rp[n], end = rp[n + 1];
        float selfa = d2i[n] * xa[(size_t)n * 64 + lane] + ba[lane];
        float selfb = d2i[n] * xb[(size_t)n * 64 + lane] + bb[lane];
        float acca = 0.0f, accb = 0.0f;
        for (int base = beg; base < end; base += 64) {
            int cnt = min(64, end - base);
            int2 m = make_int2(0, 0);
            if (base + lane < end) m = em[base + lane];
            int j = 0;
            for (; j + 4 <= cnt; j += 4) {
                int s0 = __shfl(m.x, j, 64),     s1 = __shfl(m.x, j + 1, 64);
                int s2 = __shfl(m.x, j + 2, 64), s3 = __shfl(m.x, j + 3, 64);
                float n0 = __int_as_float(__shfl(m.y, j, 64));
                float n1 = __int_as_float(__shfl(m.y, j + 1, 64));
                float n2 = __int_as_float(__shfl(m.y, j + 2, 64));
                float n3 = __int_as_float(__shfl(m.y, j + 3, 64));
                float a0 = xa[(size_t)s0 * 64 + lane];
                float b0 = xb[(size_t)s0 * 64 + lane];
                float a1 = xa[(size_t)s1 * 64 + lane];
                float b1 = xb[(size_t)s1 * 64 + lane];
                float a2 = xa[(size_t)s2 * 64 + lane];
                float b2 = xb[(size_t)s2 * 64 + lane];
                float a3 = xa[(size_t)s3 * 64 + lane];
                float b3 = xb[(size_t)s3 * 64 + lane];
                acca += n0 * a0; accb += n0 * b0;
                acca += n1 * a1; accb += n1 * b1;
                acca += n2 * a2; accb += n2 * b2;
                acca += n3 * a3; accb += n3 * b3;
            }
            for (; j < cnt; j++) {
                int s = __shfl(m.x, j, 64);
                float nv = __int_as_float(__shfl(m.y, j, 64));
                acca += nv * xa[(size_t)s * 64 + lane];
                accb += nv * xb[(size_t)s * 64 + lane];
            }
        }
        size_t o = (size_t)n * 64 + lane;
        float va = acca + selfa;
        float vb = accb + selfb;
        oa[o] = va;
        ob[o] = vb;
        sa += (double)va; sa2 += (double)va * (double)va;
        sb += (double)vb; sb2 += (double)vb * (double)vb;
    }
    __shared__ double l1[4][64], l2[4][64], l3[4][64], l4[4][64];
    l1[w][lane] = sa; l2[w][lane] = sa2; l3[w][lane] = sb; l4[w][lane] = sb2;
    __syncthreads();
    if (tid < 64) {
        size_t o = (size_t)blockIdx.x * 256;
        part[o + tid]       = l1[0][tid] + l1[1][tid] + l1[2][tid] + l1[3][tid];
        part[o + 64 + tid]  = l2[0][tid] + l2[1][tid] + l2[2][tid] + l2[3][tid];
        part[o + 128 + tid] = l3[0][tid] + l3[1][tid] + l3[2][tid] + l3[3][tid];
        part[o + 192 + tid] = l4[0][tid] + l4[1][tid] + l4[2][tid] + l4[3][tid];
    }
}

// ---------------- deterministic partial reduces ----------------

__global__ __launch_bounds__(256) void bn_red_k(const double* __restrict__ part,
                                                double* __restrict__ st) {
    __shared__ double tr[256];
    int t = threadIdx.x, c = blockIdx.x;     // c in [0,128)
    double s = 0.0;
    for (int b = t; b < NBE; b += 256) s += part[(size_t)b * 128 + c];
    tr[t] = s;
    __syncthreads();
    for (int off = 128; off > 0; off >>= 1) {
        if (t < off) tr[t] += tr[t + off];
        __syncthreads();
    }
    if (t == 0) st[c] = tr[0];
}

__global__ __launch_bounds__(256) void bn_red2_k(const double* __restrict__ part,
                                                 double* __restrict__ sta,
                                                 double* __restrict__ stb) {
    __shared__ double tr[256];
    int t = threadIdx.x, c = blockIdx.x;     // c in [0,256)
    double s = 0.0;
    for (int b = t; b < NBE; b += 256) s += part[(size_t)b * 256 + c];
    tr[t] = s;
    __syncthreads();
    for (int off = 128; off > 0; off >>= 1) {
        if (t < off) tr[t] += tr[t + off];
        __syncthreads();
    }
    if (t == 0) {
        if (c < 128) sta[c] = tr[0];
        else stb[c - 128] = tr[0];
    }
}

// per-block bn scale/shift preamble (c < 64)
__device__ inline void bn_ss(const double* __restrict__ st, const float* __restrict__ gam,
                             const float* __restrict__ bet, int c,
                             float* __restrict__ ssc, float* __restrict__ ssh) {
    double m = st[c] * (1.0 / NN);
    double v = st[64 + c] * (1.0 / NN) - m * m;
    float scale = (float)((double)gam[c] / sqrt(v + (double)EPSF));
    ssc[c] = scale;
    ssh[c] = bet[c] - (float)m * scale;
}

// ---------------- fused elementwise steps ----------------

__global__ __launch_bounds__(256) void lif_conv_bits_k(const float* __restrict__ G,
                                                       const double* __restrict__ st,
                                                       const float* __restrict__ gam,
                                                       const float* __restrict__ bet,
                                                       float* __restrict__ vconv,
                                                       u64* __restrict__ bits) {
    __shared__ float ssc[64], ssh[64];
    int tid = threadIdx.x;
    if (tid < 64) bn_ss(st, gam, bet, tid, ssc, ssh);
    __syncthreads();
    size_t i = (size_t)blockIdx.x * 256 + tid;
    int c = tid & 63;
    float v = vconv[i] + (G[i] * ssc[c] + ssh[c]);
    bool sp = (v - THF >= 0.0f);
    u64 bal = __ballot(sp);
    vconv[i] = sp ? 0.0f : v;
    if (c == 0) bits[i >> 6] = bal;
}

__global__ __launch_bounds__(256) void bn_spike_bits_k(const float* __restrict__ G,
                                                       const double* __restrict__ st,
                                                       const float* __restrict__ gam,
                                                       const float* __restrict__ bet,
                                                       float* __restrict__ x3,
                                                       u64* __restrict__ bits) {
    __shared__ float ssc[64], ssh[64];
    int tid = threadIdx.x;
    if (tid < 64) bn_ss(st, gam, bet, tid, ssc, ssh);
    __syncthreads();
    size_t i = (size_t)blockIdx.x * 256 + tid;
    int c = tid & 63;
    float xv = G[i] * ssc[c] + ssh[c];
    x3[i] = xv;
    u64 bal = __ballot(xv - THF >= 0.0f);
    if (c == 0) bits[i >> 6] = bal;
}

// F = bn(G) + x3, with fused deterministic stats partials
__global__ __launch_bounds__(256) void bn_add_stats_k(const float* __restrict__ G,
                                                      const double* __restrict__ st,
                                                      const float* __restrict__ gam,
                                                      const float* __restrict__ bet,
                                                      const float* __restrict__ x3,
                                                      float* __restrict__ F,
                                                      double* __restrict__ part) {
    __shared__ float ssc[64], ssh[64];
    int tid = threadIdx.x;
    if (tid < 64) bn_ss(st, gam, bet, tid, ssc, ssh);
    __syncthreads();
    int c = tid & 63;
    double s = 0.0, s2 = 0.0;
    for (size_t i = (size_t)blockIdx.x * 256 + tid; i < NHTOT; i += (size_t)NBE * 256) {
        float f = (G[i] * ssc[c] + ssh[c]) + x3[i];
        F[i] = f;
        s += (double)f;
        s2 += (double)f * (double)f;
    }
    __shared__ double ls[256], lq[256];
    ls[tid] = s; lq[tid] = s2;
    __syncthreads();
    if (tid < 64) {
        double a = ls[tid] + ls[tid + 64] + ls[tid + 128] + ls[tid + 192];
        double b = lq[tid] + lq[tid + 64] + lq[tid + 128] + lq[tid + 192];
        part[(size_t)blockIdx.x * 128 + tid] = a;
        part[(size_t)blockIdx.x * 128 + 64 + tid] = b;
    }
}

__global__ __launch_bounds__(256) void bn_lif_bits_k(const float* __restrict__ F,
                                                     const double* __restrict__ st,
                                                     const float* __restrict__ gam,
                                                     const float* __restrict__ bet,
                                                     float* __restrict__ vconv,
                                                     float* __restrict__ x4,
                                                     u64* __restrict__ bits) {
    __shared__ float ssc[64], ssh[64];
    int tid = threadIdx.x;
    if (tid < 64) bn_ss(st, gam, bet, tid, ssc, ssh);
    __syncthreads();
    size_t i = (size_t)blockIdx.x * 256 + tid;
    int c = tid & 63;
    float xv = F[i] * ssc[c] + ssh[c];
    x4[i] = xv;
    float v = vconv[i] + xv;
    bool sp = (v - THF >= 0.0f);
    u64 bal = __ballot(sp);
    vconv[i] = sp ? 0.0f : v;
    if (c == 0) bits[i >> 6] = bal;
}

// fused q,k,v spikes + qk popcount + att bits (one wave per node)
__global__ __launch_bounds__(256) void qkv_att_bits_k(const float* __restrict__ Gq,
                                                      const float* __restrict__ Gk,
                                                      const float* __restrict__ Gv,
                                                      const double* __restrict__ st4,
                                                      const double* __restrict__ st5,
                                                      const double* __restrict__ st6,
                                                      const float* __restrict__ gam4,
                                                      const float* __restrict__ bet4,
                                                      const float* __restrict__ gam5,
                                                      const float* __restrict__ bet5,
                                                      const float* __restrict__ gam6,
                                                      const float* __restrict__ bet6,
                                                      u64* __restrict__ bits) {
    __shared__ float sc4[64], sh4[64], sc5[64], sh5[64], sc6[64], sh6[64];
    int tid = threadIdx.x;
    if (tid < 64) {
        bn_ss(st4, gam4, bet4, tid, sc4, sh4);
        bn_ss(st5, gam5, bet5, tid, sc5, sh5);
        bn_ss(st6, gam6, bet6, tid, sc6, sh6);
    }
    __syncthreads();
    size_t i = (size_t)blockIdx.x * 256 + tid;
    int c = tid & 63;
    bool qb = (Gq[i] * sc4[c] + sh4[c] - THF >= 0.0f);
    bool kb = (Gk[i] * sc5[c] + sh5[c] - THF >= 0.0f);
    bool vb = (Gv[i] * sc6[c] + sh6[c] - THF >= 0.0f);
    int pc = __popcll(__ballot(qb && kb));
    bool qs = ((float)pc * (1.0f / 64.0f) - ATTTH >= 0.0f);
    u64 bal = __ballot(vb && qs);
    if (c == 0) bits[i >> 6] = bal;
}

// tmp2 = x4 + 0.125*bn(G), with fused deterministic stats partials
__global__ __launch_bounds__(256) void bn_scale_add_stats_k(const float* __restrict__ G,
                                                            const double* __restrict__ st,
                                                            const float* __restrict__ gam,
                                                            const float* __restrict__ bet,
                                                            const float* __restrict__ x4,
                                                            float* __restrict__ tmp2,
                                                            double* __restrict__ part) {
    __shared__ float ssc[64], ssh[64];
    int tid = threadIdx.x;
    if (tid < 64) bn_ss(st, gam, bet, tid, ssc, ssh);
    __syncthreads();
    int c = tid & 63;
    double s = 0.0, s2 = 0.0;
    for (size_t i = (size_t)blockIdx.x * 256 + tid; i < NHTOT; i += (size_t)NBE * 256) {
        float f = x4[i] + 0.125f * (G[i] * ssc[c] + ssh[c]);
        tmp2[i] = f;
        s += (double)f;
        s2 += (double)f * (double)f;
    }
    __shared__ double ls[256], lq[256];
    ls[tid] = s; lq[tid] = s2;
    __syncthreads();
    if (tid < 64) {
        double a = ls[tid] + ls[tid + 64] + ls[tid + 128] + ls[tid + 192];
        double b = lq[tid] + lq[tid + 64] + lq[tid + 128] + lq[tid + 192];
        part[(size_t)blockIdx.x * 128 + tid] = a;
        part[(size_t)blockIdx.x * 128 + 64 + tid] = b;
    }
}

__global__ __launch_bounds__(256) void decode_k(const float* __restrict__ tmp2,
                                                const double* __restrict__ st,
                                                const float* __restrict__ gam,
                                                const float* __restrict__ bet,
                                                const float* __restrict__ wrow,
                                                float* __restrict__ z) {
    __shared__ float ssc[64], ssh[64];
    int tid = threadIdx.x;
    if (tid < 64) bn_ss(st, gam, bet, tid, ssc, ssh);
    __syncthreads();
    int lane = tid & 63;
    int row = blockIdx.x * 4 + (tid >> 6);
    float sv = tmp2[(size_t)row * 64 + lane] * ssc[lane] + ssh[lane];
    float p = sv * wrow[lane];
#pragma unroll
    for (int off = 32; off > 0; off >>= 1) p += __shfl_xor(p, off, 64);
    if (lane == 0) z[row] = p;
}

__global__ void wrow_k(const float* __restrict__ W_lin, float* __restrict__ wrow) {
    int h = threadIdx.x;
    if (h >= 64) return;
    float s = 0.0f;
    for (int j = 0; j < 64; j++) s += W_lin[h * 64 + j];
    wrow[h] = s;
}

// ---------------- host driver ----------------

extern "C" void kernel_launch(void* const* d_in, const int* in_sizes, int n_in,
                              void* d_out, int out_size, void* d_ws, size_t ws_size,
                              hipStream_t stream) {
    const float* x    = (const float*)d_in[0];
    const int* eidx   = (const int*)d_in[1];
    const int* emask  = (const int*)d_in[2];
    const float* Wg   = (const float*)d_in[3];
    const float* bg   = (const float*)d_in[4];
    const float* bng  = (const float*)d_in[5];
    const float* bnb  = (const float*)d_in[6];
    const float* Wlin = (const float*)d_in[7];
    float* zout = (float*)d_out;

    const int* srcp = eidx;
    const int* dstp = eidx + NE;
    const size_t NH = (size_t)NN * HH;

    // ---- workspace layout (8B-aligned chain) ----
    float* fb = (float*)d_ws;
    float* P1 = fb;
    float* P2 = P1 + NH;
    float* P3 = P2 + NH;
    float* P4 = P3 + NH;
    float* P5 = P4 + NH;
    float* vconv = P5 + NH;                      // 6*NH floats (even)
    int2* em1 = (int2*)(vconv + NH);             // NE
    int2* em2 = em1 + NE;                        // EM2CAP
    u64* sbits = (u64*)(em2 + EM2CAP);           // NN
    double* part = (double*)(sbits + NN);        // NBE*256 doubles (4 MB)
    double* stats = part + (size_t)NBE * 256;    // 18*128 doubles
    float* dis1 = (float*)(stats + 18 * 128);
    float* d21  = dis1 + NN;
    float* dis2m = d21 + NN;
    float* d22  = dis2m + NN;
    float* wrow = d22 + NN;                      // 64
    int* rp1 = (int*)(wrow + 64);                // NN+1
    int* rp2 = rp1 + NN + 2;                     // NN+1
    int* cnt1 = rp2 + NN + 2;                    // 4*NN contiguous (one memset)
    int* cnt2 = cnt1 + NN;
    int* cur1 = cnt2 + NN;
    int* cur2 = cur1 + NN;
    int* bsum = cur2 + NN;                       // SCAN_B

    hipMemsetAsync(cnt1, 0, 4 * NN * sizeof(int), stream);
    hipMemsetAsync(vconv, 0, NH * sizeof(float), stream);

    const int NB_EDGE = NE / 256;        // 6250
    const int NB_NODE = SCAN_B;          // 391
    const int NB_ROW4 = NN / 4;          // 25000
    const int NB_GEMM = NN / 32;         // 3125
    const int NB_BG   = (NN + 63) / 64;  // 1563

    wrow_k<<<1, 64, 0, stream>>>(Wlin, wrow);
    hist_k<<<NB_EDGE, 256, 0, stream>>>(dstp, emask, cnt1, cnt2);
    deg_inv2_k<<<NB_NODE, 256, 0, stream>>>(cnt1, cnt2, dis1, d21, dis2m, d22);
    scan1_k<<<NB_NODE, 256, 0, stream>>>(cnt1, rp1, bsum);
    scan2_k<<<1, 512, 0, stream>>>(bsum, rp1);
    scan3_k<<<NB_NODE, 256, 0, stream>>>(rp1, bsum);
    scan1_k<<<NB_NODE, 256, 0, stream>>>(cnt2, rp2, bsum);
    scan2_k<<<1, 512, 0, stream>>>(bsum, rp2);
    scan3_k<<<NB_NODE, 256, 0, stream>>>(rp2, bsum);
    csr_fill_k<<<NB_EDGE, 256, 0, stream>>>(srcp, dstp, emask, dis1, dis2m,
                                            rp1, rp2, cur1, cur2, em1, em2);
    seg_sort_k<<<NB_ROW4, 256, 0, stream>>>(em1, rp1);
    seg_sort_k<<<NB_ROW4, 256, 0, stream>>>(em2, rp2);

    auto enc = [&](const int2* em, const int* rp, const float* d2i, int bnbase,
                   float* zo) {
        auto ST = [&](int bni) { return stats + (bnbase + bni) * 128; };
        auto W = [&](int wi) { return Wg + wi * 4096; };
        auto BI = [&](int wi) { return bg + wi * 64; };
        auto GM = [&](int bi) { return bng + bi * 64; };
        auto BT = [&](int bi) { return bnb + bi * 64; };
        auto gatherS = [&](const float* xw, int wi, float* out, int bni) {
            gather_stats_k<<<NBE, 256, 0, stream>>>(xw, em, rp, d2i, BI(wi), out, part);
            bn_red_k<<<128, 256, 0, stream>>>(part, ST(bni));
        };

        // layer 0 (float input)
        gemm_k<<<NB_GEMM, 256, 0, stream>>>(x, W(0), P1);
        gatherS(P1, 0, P2, 0);
        lif_conv_bits_k<<<NB_ROW4, 256, 0, stream>>>(P2, ST(0), GM(0), BT(0),
                                                     vconv, sbits);
        // layer 1
        bitgemm_k<<<NB_BG, 256, 0, stream>>>(sbits, W(1), P1);
        gatherS(P1, 1, P2, 1);
        bn_spike_bits_k<<<NB_ROW4, 256, 0, stream>>>(P2, ST(1), GM(1), BT(1),
                                                     P3, sbits);    // x3=P3
        // pos layer
        bitgemm_k<<<NB_BG, 256, 0, stream>>>(sbits, W(2), P1);
        gatherS(P1, 2, P2, 2);
        bn_add_stats_k<<<NBE, 256, 0, stream>>>(P2, ST(2), GM(2), BT(2), P3, P4, part);
        bn_red_k<<<128, 256, 0, stream>>>(part, ST(3));
        bn_lif_bits_k<<<NB_ROW4, 256, 0, stream>>>(P4, ST(3), GM(3), BT(3),
                                                   vconv, P2, sbits); // x4=P2
        // q,k (pair-fused)
        bitgemm2_k<<<NB_BG, 256, 0, stream>>>(sbits, W(3), W(4), P1, P3);
        gather2_stats_k<<<NBE, 256, 0, stream>>>(P1, P3, em, rp, d2i, BI(3), BI(4),
                                                 P4, P5, part);
        bn_red2_k<<<256, 256, 0, stream>>>(part, ST(4), ST(5));
        // v
        bitgemm_k<<<NB_BG, 256, 0, stream>>>(sbits, W(5), P1);
        gatherS(P1, 5, P3, 6);
        // fused q,k,v spikes -> att bits
        qkv_att_bits_k<<<NB_ROW4, 256, 0, stream>>>(P4, P5, P3, ST(4), ST(5), ST(6),
                                                    GM(4), BT(4), GM(5), BT(5),
                                                    GM(6), BT(6), sbits);
        // att gcn
        bitgemm_k<<<NB_BG, 256, 0, stream>>>(sbits, W(6), P1);
        gatherS(P1, 6, P3, 7);
        bn_scale_add_stats_k<<<NBE, 256, 0, stream>>>(P3, ST(7), GM(7), BT(7),
                                                      P2, P4, part);   // tmp2=P4
        bn_red_k<<<128, 256, 0, stream>>>(part, ST(8));
        decode_k<<<NB_ROW4, 256, 0, stream>>>(P4, ST(8), GM(8), BT(8), wrow, zo);
    };

    enc(em1, rp1, d21, 0, zout);
    enc(em2, rp2, d22, 9, zout + NN);
}

// Round 10
// 1863.292 us; speedup vs baseline: 1.3313x; 1.0159x over previous
//
#include <hip/hip_runtime.h>
#include <math.h>
#include <stdint.h>
#include <limits.h>

#define NN 100000
#define NE 1600000
#define HH 64
#define THF 0.7f
#define ATTTH 0.2f
#define EPSF 1e-5f
#define SCAN_B ((NN + 255) / 256)   // 391
#define EM2CAP 1000000
#define NBE 2048                    // stats-fused producer grid
#define NHTOT ((size_t)NN * 64)

typedef unsigned long long u64;

// ---------------- setup: histogram, degree, scans, CSR fill ----------------

__global__ void hist_k(const int* __restrict__ dst, const int* __restrict__ mask,
                       int* __restrict__ cnt_all, int* __restrict__ cnt_mask) {
    int e = blockIdx.x * 256 + threadIdx.x;
    if (e >= NE) return;
    int d = dst[e];
    atomicAdd(&cnt_all[d], 1);          // integer atomics: value-deterministic
    if (mask[e]) atomicAdd(&cnt_mask[d], 1);
}

__global__ void deg_inv2_k(const int* __restrict__ cnt1, const int* __restrict__ cnt2,
                           float* __restrict__ dis1, float* __restrict__ d21,
                           float* __restrict__ dis2m, float* __restrict__ d22) {
    int i = blockIdx.x * 256 + threadIdx.x;
    if (i < NN) {
        float dg1 = (float)(cnt1[i] + 1);   // +1 self loop
        dis1[i] = 1.0f / sqrtf(dg1);
        d21[i] = 1.0f / dg1;
        float dg2 = (float)(cnt2[i] + 1);
        dis2m[i] = 1.0f / sqrtf(dg2);
        d22[i] = 1.0f / dg2;
    }
}

__global__ void scan1_k(const int* __restrict__ counts, int* __restrict__ rp,
                        int* __restrict__ bsum) {
    __shared__ int ls[256];
    int i = blockIdx.x * 256 + threadIdx.x;
    int v = (i < NN) ? counts[i] : 0;
    ls[threadIdx.x] = v;
    __syncthreads();
    for (int off = 1; off < 256; off <<= 1) {
        int t = (threadIdx.x >= off) ? ls[threadIdx.x - off] : 0;
        __syncthreads();
        ls[threadIdx.x] += t;
        __syncthreads();
    }
    if (i < NN) rp[i] = ls[threadIdx.x] - v;
    if (threadIdx.x == 255) bsum[blockIdx.x] = ls[255];
}

__global__ __launch_bounds__(512) void scan2_k(int* __restrict__ bsum,
                                               int* __restrict__ rp) {
    __shared__ int ls[512];
    int i = threadIdx.x;
    int v = (i < SCAN_B) ? bsum[i] : 0;
    ls[i] = v;
    __syncthreads();
    for (int off = 1; off < 512; off <<= 1) {
        int t = (i >= off) ? ls[i - off] : 0;
        __syncthreads();
        ls[i] += t;
        __syncthreads();
    }
    if (i < SCAN_B) bsum[i] = ls[i] - v;      // exclusive
    if (i == SCAN_B - 1) rp[NN] = ls[i];
}

__global__ void scan3_k(int* __restrict__ rp, const int* __restrict__ bsum) {
    int i = blockIdx.x * 256 + threadIdx.x;
    if (i < NN) rp[i] += bsum[blockIdx.x];
}

// fills both CSRs (atomic cursors; layout made deterministic by seg_sort)
__global__ void csr_fill_k(const int* __restrict__ src, const int* __restrict__ dst,
                           const int* __restrict__ mask,
                           const float* __restrict__ dis1, const float* __restrict__ dis2m,
                           const int* __restrict__ rp1, const int* __restrict__ rp2,
                           int* __restrict__ cur1, int* __restrict__ cur2,
                           int2* __restrict__ em1, int2* __restrict__ em2) {
    int e = blockIdx.x * 256 + threadIdx.x;
    if (e >= NE) return;
    int s = src[e], d = dst[e];
    float n1 = dis1[s] * dis1[d];
    int p1 = rp1[d] + atomicAdd(&cur1[d], 1);
    em1[p1] = make_int2(s, __float_as_int(n1));
    if (mask[e]) {
        float n2 = dis2m[s] * dis2m[d];
        int p2 = rp2[d] + atomicAdd(&cur2[d], 1);
        em2[p2] = make_int2(s, __float_as_int(n2));
    }
}

// sort each dst segment by src (= em.x). Duplicate srcs have identical payloads
// (same norm), so leader-pick loses nothing. Result: run-invariant layout.
__global__ __launch_bounds__(256) void seg_sort_k(int2* __restrict__ em,
                                                  const int* __restrict__ rp) {
    __shared__ int skey[4][512];
    __shared__ int snrm[4][512];
    int tid = threadIdx.x, lane = tid & 63, w = tid >> 6;
    int n = blockIdx.x * 4 + w;
    int beg = rp[n], end = rp[n + 1];
    int L = end - beg;
    if (L <= 1) return;
    if (L <= 64) {
        int k = INT_MAX; int2 pl = make_int2(0, 0);
        if (lane < L) { pl = em[beg + lane]; k = pl.x; }
        for (int r = 0; r < L; r++) {
            int mn = k;
#pragma unroll
            for (int off = 32; off > 0; off >>= 1)
                mn = min(mn, __shfl_xor(mn, off, 64));
            u64 msk = __ballot(k == mn);
            int leader = (int)__ffsll((unsigned long long)msk) - 1;
            if (lane == leader) { em[beg + r] = pl; k = INT_MAX; }
        }
    } else if (L <= 512) {
        for (int i = lane; i < L; i += 64) {
            int2 p = em[beg + i];
            skey[w][i] = p.x;
            snrm[w][i] = p.y;
        }
        for (int it = 0; it < L; it++) {
            int par = it & 1;
            for (int p = par + 2 * lane; p + 1 < L; p += 128) {
                int ka = skey[w][p], kb = skey[w][p + 1];
                if (kb < ka) {
                    skey[w][p] = kb; skey[w][p + 1] = ka;
                    int t = snrm[w][p]; snrm[w][p] = snrm[w][p + 1]; snrm[w][p + 1] = t;
                }
            }
        }
        for (int i = lane; i < L; i += 64)
            em[beg + i] = make_int2(skey[w][i], snrm[w][i]);
    }
}

// ---------------- GEMM (float input, layer 0 only) ----------------

__global__ __launch_bounds__(256) void gemm_k(const float* __restrict__ in,
                                              const float* __restrict__ W,
                                              float* __restrict__ xw) {
    __shared__ float sW[64 * 64];
    __shared__ float sx[32 * 65];
    int tid = threadIdx.x;
    const float4* W4 = (const float4*)W;
    float4* sW4 = (float4*)sW;
    for (int i = tid; i < 1024; i += 256) sW4[i] = W4[i];
    const float* inb = in + (size_t)blockIdx.x * 2048;
    for (int i = tid; i < 2048; i += 256) sx[(i >> 6) * 65 + (i & 63)] = inb[i];
    __syncthreads();
    int cg = tid & 15, rr = tid >> 4;
    float a0 = 0, a1 = 0, a2 = 0, a3 = 0, c0 = 0, c1 = 0, c2 = 0, c3 = 0;
#pragma unroll
    for (int k = 0; k < 64; k++) {
        float4 wv = *(const float4*)&sW[k * 64 + cg * 4];
        float xa = sx[rr * 65 + k];
        float xb = sx[(rr + 16) * 65 + k];
        a0 += xa * wv.x; a1 += xa * wv.y; a2 += xa * wv.z; a3 += xa * wv.w;
        c0 += xb * wv.x; c1 += xb * wv.y; c2 += xb * wv.z; c3 += xb * wv.w;
    }
    size_t r0 = (size_t)(blockIdx.x * 32 + rr) * 64 + cg * 4;
    size_t r1 = (size_t)(blockIdx.x * 32 + rr + 16) * 64 + cg * 4;
    *(float4*)&xw[r0] = make_float4(a0, a1, a2, a3);
    *(float4*)&xw[r1] = make_float4(c0, c1, c2, c3);
}

// ---------------- standalone bit GEMM (W5, reads sbits) ----------------

__global__ __launch_bounds__(256) void bitgemm_k(const u64* __restrict__ bits,
                                                 const float* __restrict__ W,
                                                 float* __restrict__ xw) {
    __shared__ float sW[64 * 64];
    int tid = threadIdx.x;
    const float4* W4 = (const float4*)W;
    float4* sW4 = (float4*)sW;
    for (int i = tid; i < 1024; i += 256) sW4[i] = W4[i];
    __syncthreads();
    int lane = tid & 63, w = tid >> 6;
    int n0 = blockIdx.x * 64 + w * 16;
    for (int t = 0; t < 16; t++) {
        int n = n0 + t;
        if (n >= NN) return;
        u64 m = bits[n];
        float acc = 0.0f;
        while (m) {
            int k = (int)__builtin_ctzll(m);
            m &= m - 1;
            acc += sW[k * 64 + lane];
        }
        xw[(size_t)n * 64 + lane] = acc;
    }
}

// ---------------- stats-fused gathers (unchanged math from R9) ----------------

__global__ __launch_bounds__(256) void gather_stats_k(const float* __restrict__ xw,
                                                      const int2* __restrict__ em,
                                                      const int* __restrict__ rp,
                                                      const float* __restrict__ d2i,
                                                      const float* __restrict__ bias,
                                                      float* __restrict__ out,
                                                      double* __restrict__ part) {
    int tid = threadIdx.x, lane = tid & 63, w = tid >> 6;
    double ps = 0.0, pq = 0.0;
    for (int n = blockIdx.x * 4 + w; n < NN; n += NBE * 4) {
        int beg = rp[n], end = rp[n + 1];
        float self = d2i[n] * xw[(size_t)n * 64 + lane] + bias[lane];
        float acc = 0.0f;
        for (int base = beg; base < end; base += 64) {
            int cnt = min(64, end - base);
            int2 m = make_int2(0, 0);
            if (base + lane < end) m = em[base + lane];
            int j = 0;
            for (; j + 8 <= cnt; j += 8) {
                int s0 = __shfl(m.x, j, 64),     s1 = __shfl(m.x, j + 1, 64);
                int s2 = __shfl(m.x, j + 2, 64), s3 = __shfl(m.x, j + 3, 64);
                int s4 = __shfl(m.x, j + 4, 64), s5 = __shfl(m.x, j + 5, 64);
                int s6 = __shfl(m.x, j + 6, 64), s7 = __shfl(m.x, j + 7, 64);
                float n0 = __int_as_float(__shfl(m.y, j, 64));
                float n1 = __int_as_float(__shfl(m.y, j + 1, 64));
                float n2 = __int_as_float(__shfl(m.y, j + 2, 64));
                float n3 = __int_as_float(__shfl(m.y, j + 3, 64));
                float n4 = __int_as_float(__shfl(m.y, j + 4, 64));
                float n5 = __int_as_float(__shfl(m.y, j + 5, 64));
                float n6 = __int_as_float(__shfl(m.y, j + 6, 64));
                float n7 = __int_as_float(__shfl(m.y, j + 7, 64));
                float v0 = xw[(size_t)s0 * 64 + lane];
                float v1 = xw[(size_t)s1 * 64 + lane];
                float v2 = xw[(size_t)s2 * 64 + lane];
                float v3 = xw[(size_t)s3 * 64 + lane];
                float v4 = xw[(size_t)s4 * 64 + lane];
                float v5 = xw[(size_t)s5 * 64 + lane];
                float v6 = xw[(size_t)s6 * 64 + lane];
                float v7 = xw[(size_t)s7 * 64 + lane];
                acc += n0 * v0; acc += n1 * v1; acc += n2 * v2; acc += n3 * v3;
                acc += n4 * v4; acc += n5 * v5; acc += n6 * v6; acc += n7 * v7;
            }
            for (; j < cnt; j++) {
                int s = __shfl(m.x, j, 64);
                float nv = __int_as_float(__shfl(m.y, j, 64));
                acc += nv * xw[(size_t)s * 64 + lane];
            }
        }
        float o = acc + self;
        out[(size_t)n * 64 + lane] = o;
        ps += (double)o;
        pq += (double)o * (double)o;
    }
    __shared__ double ls[4][64], lq[4][64];
    ls[w][lane] = ps; lq[w][lane] = pq;
    __syncthreads();
    if (tid < 64) {
        double a = ls[0][tid] + ls[1][tid] + ls[2][tid] + ls[3][tid];
        double b = lq[0][tid] + lq[1][tid] + lq[2][tid] + lq[3][tid];
        part[(size_t)blockIdx.x * 128 + tid] = a;
        part[(size_t)blockIdx.x * 128 + 64 + tid] = b;
    }
}

__global__ __launch_bounds__(256) void gather2_stats_k(const float* __restrict__ xa,
                                                       const float* __restrict__ xb,
                                                       const int2* __restrict__ em,
                                                       const int* __restrict__ rp,
                                                       const float* __restrict__ d2i,
                                                       const float* __restrict__ ba,
                                                       const float* __restrict__ bb,
                                                       float* __restrict__ oa,
                                                       float* __restrict__ ob,
                                                       double* __restrict__ part) {
    int tid = threadIdx.x, lane = tid & 63, w = tid >> 6;
    double sa = 0.0, sa2 = 0.0, sb = 0.0, sb2 = 0.0;
    for (int n = blockIdx.x * 4 + w; n < NN; n += NBE * 4) {
        int beg = rp[n], end = rp[n + 1];
        float selfa = d2i[n] * xa[(size_t)n * 64 + lane] + ba[lane];
        float selfb = d2i[n] * xb[(size_t)n * 64 + lane] + bb[lane];
        float acca = 0.0f, accb = 0.0f;
        for (int base = beg; base < end; base += 64) {
            int cnt = min(64, end - base);
            int2 m = make_int2(0, 0);
            if (base + lane < end) m = em[base + lane];
            int j = 0;
            for (; j + 4 <= cnt; j += 4) {
                int s0 = __shfl(m.x, j, 64),     s1 = __shfl(m.x, j + 1, 64);
                int s2 = __shfl(m.x, j + 2, 64), s3 = __shfl(m.x, j + 3, 64);
                float n0 = __int_as_float(__shfl(m.y, j, 64));
                float n1 = __int_as_float(__shfl(m.y, j + 1, 64));
                float n2 = __int_as_float(__shfl(m.y, j + 2, 64));
                float n3 = __int_as_float(__shfl(m.y, j + 3, 64));
                float a0 = xa[(size_t)s0 * 64 + lane];
                float b0 = xb[(size_t)s0 * 64 + lane];
                float a1 = xa[(size_t)s1 * 64 + lane];
                float b1 = xb[(size_t)s1 * 64 + lane];
                float a2 = xa[(size_t)s2 * 64 + lane];
                float b2 = xb[(size_t)s2 * 64 + lane];
                float a3 = xa[(size_t)s3 * 64 + lane];
                float b3 = xb[(size_t)s3 * 64 + lane];
                acca += n0 * a0; accb += n0 * b0;
                acca += n1 * a1; accb += n1 * b1;
                acca += n2 * a2; accb += n2 * b2;
                acca += n3 * a3; accb += n3 * b3;
            }
            for (; j < cnt; j++) {
                int s = __shfl(m.x, j, 64);
                float nv = __int_as_float(__shfl(m.y, j, 64));
                acca += nv * xa[(size_t)s * 64 + lane];
                accb += nv * xb[(size_t)s * 64 + lane];
            }
        }
        size_t o = (size_t)n * 64 + lane;
        float va = acca + selfa;
        float vb = accb + selfb;
        oa[o] = va;
        ob[o] = vb;
        sa += (double)va; sa2 += (double)va * (double)va;
        sb += (double)vb; sb2 += (double)vb * (double)vb;
    }
    __shared__ double l1[4][64], l2[4][64], l3[4][64], l4[4][64];
    l1[w][lane] = sa; l2[w][lane] = sa2; l3[w][lane] = sb; l4[w][lane] = sb2;
    __syncthreads();
    if (tid < 64) {
        size_t o = (size_t)blockIdx.x * 256;
        part[o + tid]       = l1[0][tid] + l1[1][tid] + l1[2][tid] + l1[3][tid];
        part[o + 64 + tid]  = l2[0][tid] + l2[1][tid] + l2[2][tid] + l2[3][tid];
        part[o + 128 + tid] = l3[0][tid] + l3[1][tid] + l3[2][tid] + l3[3][tid];
        part[o + 192 + tid] = l4[0][tid] + l4[1][tid] + l4[2][tid] + l4[3][tid];
    }
}

// ---------------- deterministic partial reduces ----------------

__global__ __launch_bounds__(256) void bn_red_k(const double* __restrict__ part,
                                                double* __restrict__ st) {
    __shared__ double tr[256];
    int t = threadIdx.x, c = blockIdx.x;     // c in [0,128)
    double s = 0.0;
    for (int b = t; b < NBE; b += 256) s += part[(size_t)b * 128 + c];
    tr[t] = s;
    __syncthreads();
    for (int off = 128; off > 0; off >>= 1) {
        if (t < off) tr[t] += tr[t + off];
        __syncthreads();
    }
    if (t == 0) st[c] = tr[0];
}

__global__ __launch_bounds__(256) void bn_red2_k(const double* __restrict__ part,
                                                 double* __restrict__ sta,
                                                 double* __restrict__ stb) {
    __shared__ double tr[256];
    int t = threadIdx.x, c = blockIdx.x;     // c in [0,256)
    double s = 0.0;
    for (int b = t; b < NBE; b += 256) s += part[(size_t)b * 256 + c];
    tr[t] = s;
    __syncthreads();
    for (int off = 128; off > 0; off >>= 1) {
        if (t < off) tr[t] += tr[t + off];
        __syncthreads();
    }
    if (t == 0) {
        if (c < 128) sta[c] = tr[0];
        else stb[c - 128] = tr[0];
    }
}

// per-block bn scale/shift preamble (c < 64)
__device__ inline void bn_ss(const double* __restrict__ st, const float* __restrict__ gam,
                             const float* __restrict__ bet, int c,
                             float* __restrict__ ssc, float* __restrict__ ssh) {
    double m = st[c] * (1.0 / NN);
    double v = st[64 + c] * (1.0 / NN) - m * m;
    float scale = (float)((double)gam[c] / sqrt(v + (double)EPSF));
    ssc[c] = scale;
    ssh[c] = bet[c] - (float)m * scale;
}

// ---------------- fused spike + bitgemm kernels (1 node per wave) ----------------
// Spike word is wave-uniform via ballot; bitgemm accumulates W rows over set
// bits in ascending-k order (identical to bitgemm_k -> bit-identical results).

// conv_lif (stateful) -> xw = spikes @ W
__global__ __launch_bounds__(256) void lif_bitgemm_k(const float* __restrict__ G,
                                                     const double* __restrict__ st,
                                                     const float* __restrict__ gam,
                                                     const float* __restrict__ bet,
                                                     float* __restrict__ vconv,
                                                     const float* __restrict__ W,
                                                     float* __restrict__ xw) {
    __shared__ float sW[4096];
    __shared__ float ssc[64], ssh[64];
    int tid = threadIdx.x;
    if (tid < 64) bn_ss(st, gam, bet, tid, ssc, ssh);
    const float4* W4 = (const float4*)W;
    float4* sW4 = (float4*)sW;
    for (int i = tid; i < 1024; i += 256) sW4[i] = W4[i];
    __syncthreads();
    int lane = tid & 63;
    size_t i = (size_t)blockIdx.x * 256 + tid;
    float v = vconv[i] + (G[i] * ssc[lane] + ssh[lane]);
    bool sp = (v - THF >= 0.0f);
    u64 m = __ballot(sp);
    vconv[i] = sp ? 0.0f : v;
    float acc = 0.0f;
    while (m) {
        int k = (int)__builtin_ctzll(m);
        m &= m - 1;
        acc += sW[k * 64 + lane];
    }
    xw[i] = acc;
}

// pos spike (stateless) -> x3 stored; xw = spikes @ W
__global__ __launch_bounds__(256) void spike_bitgemm_k(const float* __restrict__ G,
                                                       const double* __restrict__ st,
                                                       const float* __restrict__ gam,
                                                       const float* __restrict__ bet,
                                                       float* __restrict__ x3,
                                                       const float* __restrict__ W,
                                                       float* __restrict__ xw) {
    __shared__ float sW[4096];
    __shared__ float ssc[64], ssh[64];
    int tid = threadIdx.x;
    if (tid < 64) bn_ss(st, gam, bet, tid, ssc, ssh);
    const float4* W4 = (const float4*)W;
    float4* sW4 = (float4*)sW;
    for (int i = tid; i < 1024; i += 256) sW4[i] = W4[i];
    __syncthreads();
    int lane = tid & 63;
    size_t i = (size_t)blockIdx.x * 256 + tid;
    float xv = G[i] * ssc[lane] + ssh[lane];
    x3[i] = xv;
    u64 m = __ballot(xv - THF >= 0.0f);
    float acc = 0.0f;
    while (m) {
        int k = (int)__builtin_ctzll(m);
        m &= m - 1;
        acc += sW[k * 64 + lane];
    }
    xw[i] = acc;
}

// conv_lif second call: x4 stored (in-place ok), vconv updated, sbits emitted,
// two projections xwa = s@Wa, xwb = s@Wb
__global__ __launch_bounds__(256) void lif_bitgemm2_k(const float* __restrict__ F,
                                                      const double* __restrict__ st,
                                                      const float* __restrict__ gam,
                                                      const float* __restrict__ bet,
                                                      float* __restrict__ vconv,
                                                      float* __restrict__ x4,
                                                      u64* __restrict__ sbits,
                                                      const float* __restrict__ Wa,
                                                      const float* __restrict__ Wb,
                                                      float* __restrict__ xwa,
                                                      float* __restrict__ xwb) {
    __shared__ float sA[4096], sB[4096];
    __shared__ float ssc[64], ssh[64];
    int tid = threadIdx.x;
    if (tid < 64) bn_ss(st, gam, bet, tid, ssc, ssh);
    const float4* A4 = (const float4*)Wa;
    const float4* B4 = (const float4*)Wb;
    float4* sA4 = (float4*)sA;
    float4* sB4 = (float4*)sB;
    for (int i = tid; i < 1024; i += 256) { sA4[i] = A4[i]; sB4[i] = B4[i]; }
    __syncthreads();
    int lane = tid & 63;
    size_t i = (size_t)blockIdx.x * 256 + tid;
    float xv = F[i] * ssc[lane] + ssh[lane];
    x4[i] = xv;
    float v = vconv[i] + xv;
    bool sp = (v - THF >= 0.0f);
    u64 m = __ballot(sp);
    vconv[i] = sp ? 0.0f : v;
    if (lane == 0) sbits[i >> 6] = m;
    float a = 0.0f, b = 0.0f;
    while (m) {
        int k = (int)__builtin_ctzll(m);
        m &= m - 1;
        a += sA[k * 64 + lane];
        b += sB[k * 64 + lane];
    }
    xwa[i] = a;
    xwb[i] = b;
}

// q,k,v spikes + qk popcount + att bits, fused with bitgemm(W6)
__global__ __launch_bounds__(256) void qkv_att_bitgemm_k(const float* __restrict__ Gq,
                                                         const float* __restrict__ Gk,
                                                         const float* __restrict__ Gv,
                                                         const double* __restrict__ st4,
                                                         const double* __restrict__ st5,
                                                         const double* __restrict__ st6,
                                                         const float* __restrict__ gam4,
                                                         const float* __restrict__ bet4,
                                                         const float* __restrict__ gam5,
                                                         const float* __restrict__ bet5,
                                                         const float* __restrict__ gam6,
                                                         const float* __restrict__ bet6,
                                                         const float* __restrict__ W,
                                                         float* __restrict__ xw) {
    __shared__ float sW[4096];
    __shared__ float sc4[64], sh4[64], sc5[64], sh5[64], sc6[64], sh6[64];
    int tid = threadIdx.x;
    if (tid < 64) {
        bn_ss(st4, gam4, bet4, tid, sc4, sh4);
        bn_ss(st5, gam5, bet5, tid, sc5, sh5);
        bn_ss(st6, gam6, bet6, tid, sc6, sh6);
    }
    const float4* W4 = (const float4*)W;
    float4* sW4 = (float4*)sW;
    for (int i = tid; i < 1024; i += 256) sW4[i] = W4[i];
    __syncthreads();
    int lane = tid & 63;
    size_t i = (size_t)blockIdx.x * 256 + tid;
    bool qb = (Gq[i] * sc4[lane] + sh4[lane] - THF >= 0.0f);
    bool kb = (Gk[i] * sc5[lane] + sh5[lane] - THF >= 0.0f);
    bool vb = (Gv[i] * sc6[lane] + sh6[lane] - THF >= 0.0f);
    int pc = __popcll(__ballot(qb && kb));
    bool qs = ((float)pc * (1.0f / 64.0f) - ATTTH >= 0.0f);
    u64 m = __ballot(vb && qs);
    float acc = 0.0f;
    while (m) {
        int k = (int)__builtin_ctzll(m);
        m &= m - 1;
        acc += sW[k * 64 + lane];
    }
    xw[i] = acc;
}

// ---------------- remaining elementwise (with fused stats) ----------------

// F = bn(G) + x3, with fused deterministic stats partials
__global__ __launch_bounds__(256) void bn_add_stats_k(const float* __restrict__ G,
                                                      const double* __restrict__ st,
                                                      const float* __restrict__ gam,
                                                      const float* __restrict__ bet,
                                                      const float* __restrict__ x3,
                                                      float* __restrict__ F,
                                                      double* __restrict__ part) {
    __shared__ float ssc[64], ssh[64];
    int tid = threadIdx.x;
    if (tid < 64) bn_ss(st, gam, bet, tid, ssc, ssh);
    __syncthreads();
    int c = tid & 63;
    double s = 0.0, s2 = 0.0;
    for (size_t i = (size_t)blockIdx.x * 256 + tid; i < NHTOT; i += (size_t)NBE * 256) {
        float f = (G[i] * ssc[c] + ssh[c]) + x3[i];
        F[i] = f;
        s += (double)f;
        s2 += (double)f * (double)f;
    }
    __shared__ double ls[256], lq[256];
    ls[tid] = s; lq[tid] = s2;
    __syncthreads();
    if (tid < 64) {
        double a = ls[tid] + ls[tid + 64] + ls[tid + 128] + ls[tid + 192];
        double b = lq[tid] + lq[tid + 64] + lq[tid + 128] + lq[tid + 192];
        part[(size_t)blockIdx.x * 128 + tid] = a;
        part[(size_t)blockIdx.x * 128 + 64 + tid] = b;
    }
}

// tmp2 = x4 + 0.125*bn(G), with fused deterministic stats partials
__global__ __launch_bounds__(256) void bn_scale_add_stats_k(const float* __restrict__ G,
                                                            const double* __restrict__ st,
                                                            const float* __restrict__ gam,
                                                            const float* __restrict__ bet,
                                                            const float* __restrict__ x4,
                                                            float* __restrict__ tmp2,
                                                            double* __restrict__ part) {
    __shared__ float ssc[64], ssh[64];
    int tid = threadIdx.x;
    if (tid < 64) bn_ss(st, gam, bet, tid, ssc, ssh);
    __syncthreads();
    int c = tid & 63;
    double s = 0.0, s2 = 0.0;
    for (size_t i = (size_t)blockIdx.x * 256 + tid; i < NHTOT; i += (size_t)NBE * 256) {
        float f = x4[i] + 0.125f * (G[i] * ssc[c] + ssh[c]);
        tmp2[i] = f;
        s += (double)f;
        s2 += (double)f * (double)f;
    }
    __shared__ double ls[256], lq[256];
    ls[tid] = s; lq[tid] = s2;
    __syncthreads();
    if (tid < 64) {
        double a = ls[tid] + ls[tid + 64] + ls[tid + 128] + ls[tid + 192];
        double b = lq[tid] + lq[tid + 64] + lq[tid + 128] + lq[tid + 192];
        part[(size_t)blockIdx.x * 128 + tid] = a;
        part[(size_t)blockIdx.x * 128 + 64 + tid] = b;
    }
}

__global__ __launch_bounds__(256) void decode_k(const float* __restrict__ tmp2,
                                                const double* __restrict__ st,
                                                const float* __restrict__ gam,
                                                const float* __restrict__ bet,
                                                const float* __restrict__ wrow,
                                                float* __restrict__ z) {
    __shared__ float ssc[64], ssh[64];
    int tid = threadIdx.x;
    if (tid < 64) bn_ss(st, gam, bet, tid, ssc, ssh);
    __syncthreads();
    int lane = tid & 63;
    int row = blockIdx.x * 4 + (tid >> 6);
    float sv = tmp2[(size_t)row * 64 + lane] * ssc[lane] + ssh[lane];
    float p = sv * wrow[lane];
#pragma unroll
    for (int off = 32; off > 0; off >>= 1) p += __shfl_xor(p, off, 64);
    if (lane == 0) z[row] = p;
}

__global__ void wrow_k(const float* __restrict__ W_lin, float* __restrict__ wrow) {
    int h = threadIdx.x;
    if (h >= 64) return;
    float s = 0.0f;
    for (int j = 0; j < 64; j++) s += W_lin[h * 64 + j];
    wrow[h] = s;
}

// ---------------- host driver ----------------

extern "C" void kernel_launch(void* const* d_in, const int* in_sizes, int n_in,
                              void* d_out, int out_size, void* d_ws, size_t ws_size,
                              hipStream_t stream) {
    const float* x    = (const float*)d_in[0];
    const int* eidx   = (const int*)d_in[1];
    const int* emask  = (const int*)d_in[2];
    const float* Wg   = (const float*)d_in[3];
    const float* bg   = (const float*)d_in[4];
    const float* bng  = (const float*)d_in[5];
    const float* bnb  = (const float*)d_in[6];
    const float* Wlin = (const float*)d_in[7];
    float* zout = (float*)d_out;

    const int* srcp = eidx;
    const int* dstp = eidx + NE;
    const size_t NH = (size_t)NN * HH;

    // ---- workspace layout (8B-aligned chain) ----
    float* fb = (float*)d_ws;
    float* P1 = fb;
    float* P2 = P1 + NH;
    float* P3 = P2 + NH;
    float* P4 = P3 + NH;
    float* P5 = P4 + NH;
    float* vconv = P5 + NH;                      // 6*NH floats (even)
    int2* em1 = (int2*)(vconv + NH);             // NE
    int2* em2 = em1 + NE;                        // EM2CAP
    u64* sbits = (u64*)(em2 + EM2CAP);           // NN
    double* part = (double*)(sbits + NN);        // NBE*256 doubles (4 MB)
    double* stats = part + (size_t)NBE * 256;    // 18*128 doubles
    float* dis1 = (float*)(stats + 18 * 128);
    float* d21  = dis1 + NN;
    float* dis2m = d21 + NN;
    float* d22  = dis2m + NN;
    float* wrow = d22 + NN;                      // 64
    int* rp1 = (int*)(wrow + 64);                // NN+1
    int* rp2 = rp1 + NN + 2;                     // NN+1
    int* cnt1 = rp2 + NN + 2;                    // 4*NN contiguous (one memset)
    int* cnt2 = cnt1 + NN;
    int* cur1 = cnt2 + NN;
    int* cur2 = cur1 + NN;
    int* bsum = cur2 + NN;                       // SCAN_B

    hipMemsetAsync(cnt1, 0, 4 * NN * sizeof(int), stream);
    hipMemsetAsync(vconv, 0, NH * sizeof(float), stream);

    const int NB_EDGE = NE / 256;        // 6250
    const int NB_NODE = SCAN_B;          // 391
    const int NB_ROW4 = NN / 4;          // 25000
    const int NB_GEMM = NN / 32;         // 3125
    const int NB_BG   = (NN + 63) / 64;  // 1563

    wrow_k<<<1, 64, 0, stream>>>(Wlin, wrow);
    hist_k<<<NB_EDGE, 256, 0, stream>>>(dstp, emask, cnt1, cnt2);
    deg_inv2_k<<<NB_NODE, 256, 0, stream>>>(cnt1, cnt2, dis1, d21, dis2m, d22);
    scan1_k<<<NB_NODE, 256, 0, stream>>>(cnt1, rp1, bsum);
    scan2_k<<<1, 512, 0, stream>>>(bsum, rp1);
    scan3_k<<<NB_NODE, 256, 0, stream>>>(rp1, bsum);
    scan1_k<<<NB_NODE, 256, 0, stream>>>(cnt2, rp2, bsum);
    scan2_k<<<1, 512, 0, stream>>>(bsum, rp2);
    scan3_k<<<NB_NODE, 256, 0, stream>>>(rp2, bsum);
    csr_fill_k<<<NB_EDGE, 256, 0, stream>>>(srcp, dstp, emask, dis1, dis2m,
                                            rp1, rp2, cur1, cur2, em1, em2);
    seg_sort_k<<<NB_ROW4, 256, 0, stream>>>(em1, rp1);
    seg_sort_k<<<NB_ROW4, 256, 0, stream>>>(em2, rp2);

    auto enc = [&](const int2* em, const int* rp, const float* d2i, int bnbase,
                   float* zo) {
        auto ST = [&](int bni) { return stats + (bnbase + bni) * 128; };
        auto W = [&](int wi) { return Wg + wi * 4096; };
        auto BI = [&](int wi) { return bg + wi * 64; };
        auto GM = [&](int bi) { return bng + bi * 64; };
        auto BT = [&](int bi) { return bnb + bi * 64; };
        auto gatherS = [&](const float* xw, int wi, float* out, int bni) {
            gather_stats_k<<<NBE, 256, 0, stream>>>(xw, em, rp, d2i, BI(wi), out, part);
            bn_red_k<<<128, 256, 0, stream>>>(part, ST(bni));
        };

        // L0: float gemm
        gemm_k<<<NB_GEMM, 256, 0, stream>>>(x, W(0), P1);
        gatherS(P1, 0, P2, 0);
        lif_bitgemm_k<<<NB_ROW4, 256, 0, stream>>>(P2, ST(0), GM(0), BT(0),
                                                   vconv, W(1), P1);      // xw1
        // L1
        gatherS(P1, 1, P2, 1);
        spike_bitgemm_k<<<NB_ROW4, 256, 0, stream>>>(P2, ST(1), GM(1), BT(1),
                                                     P3, W(2), P1);       // x3=P3, xw2
        // pos layer
        gatherS(P1, 2, P2, 2);
        bn_add_stats_k<<<NBE, 256, 0, stream>>>(P2, ST(2), GM(2), BT(2), P3, P4, part);
        bn_red_k<<<128, 256, 0, stream>>>(part, ST(3));
        lif_bitgemm2_k<<<NB_ROW4, 256, 0, stream>>>(P4, ST(3), GM(3), BT(3),
                                                    vconv, P4, sbits,
                                                    W(3), W(4), P1, P3);  // x4=P4, xw3=P1, xw4=P3
        // q,k
        gather2_stats_k<<<NBE, 256, 0, stream>>>(P1, P3, em, rp, d2i, BI(3), BI(4),
                                                 P2, P5, part);           // Gq=P2, Gk=P5
        bn_red2_k<<<256, 256, 0, stream>>>(part, ST(4), ST(5));
        // v
        bitgemm_k<<<NB_BG, 256, 0, stream>>>(sbits, W(5), P1);
        gatherS(P1, 5, P3, 6);                                            // Gv=P3
        // att bits -> xw6
        qkv_att_bitgemm_k<<<NB_ROW4, 256, 0, stream>>>(P2, P5, P3, ST(4), ST(5), ST(6),
                                                       GM(4), BT(4), GM(5), BT(5),
                                                       GM(6), BT(6), W(6), P1);
        // att gcn
        gatherS(P1, 6, P3, 7);
        bn_scale_add_stats_k<<<NBE, 256, 0, stream>>>(P3, ST(7), GM(7), BT(7),
                                                      P4, P5, part);      // tmp2=P5
        bn_red_k<<<128, 256, 0, stream>>>(part, ST(8));
        decode_k<<<NB_ROW4, 256, 0, stream>>>(P5, ST(8), GM(8), BT(8), wrow, zo);
    };

    enc(em1, rp1, d21, 0, zout);
    enc(em2, rp2, d22, 9, zout + NN);
}

// Round 12
// 1832.702 us; speedup vs baseline: 1.3535x; 1.0167x over previous
//
#include <hip/hip_runtime.h>
#include <math.h>
#include <stdint.h>
#include <limits.h>

#define NN 100000
#define NE 1600000
#define HH 64
#define THF 0.7f
#define ATTTH 0.2f
#define EPSF 1e-5f
#define SCAN_B ((NN + 255) / 256)   // 391
#define EM2CAP 1000000
#define NBE 2048
#define NHTOT ((size_t)NN * 64)

typedef unsigned long long u64;

// ---------------- setup ----------------

__global__ void hist_k(const int* __restrict__ dst, const int* __restrict__ mask,
                       int* __restrict__ cnt_all, int* __restrict__ cnt_mask) {
    int e = blockIdx.x * 256 + threadIdx.x;
    if (e >= NE) return;
    int d = dst[e];
    atomicAdd(&cnt_all[d], 1);
    if (mask[e]) atomicAdd(&cnt_mask[d], 1);
}

__global__ void deg_inv2_k(const int* __restrict__ cnt1, const int* __restrict__ cnt2,
                           float* __restrict__ dis1, float* __restrict__ d21,
                           float* __restrict__ dis2m, float* __restrict__ d22) {
    int i = blockIdx.x * 256 + threadIdx.x;
    if (i < NN) {
        float dg1 = (float)(cnt1[i] + 1);
        dis1[i] = 1.0f / sqrtf(dg1);
        d21[i] = 1.0f / dg1;
        float dg2 = (float)(cnt2[i] + 1);
        dis2m[i] = 1.0f / sqrtf(dg2);
        d22[i] = 1.0f / dg2;
    }
}

__global__ void scan1_k(const int* __restrict__ counts, int* __restrict__ rp,
                        int* __restrict__ bsum) {
    __shared__ int ls[256];
    int i = blockIdx.x * 256 + threadIdx.x;
    int v = (i < NN) ? counts[i] : 0;
    ls[threadIdx.x] = v;
    __syncthreads();
    for (int off = 1; off < 256; off <<= 1) {
        int t = (threadIdx.x >= off) ? ls[threadIdx.x - off] : 0;
        __syncthreads();
        ls[threadIdx.x] += t;
        __syncthreads();
    }
    if (i < NN) rp[i] = ls[threadIdx.x] - v;
    if (threadIdx.x == 255) bsum[blockIdx.x] = ls[255];
}

__global__ __launch_bounds__(512) void scan2_k(int* __restrict__ bsum,
                                               int* __restrict__ rp) {
    __shared__ int ls[512];
    int i = threadIdx.x;
    int v = (i < SCAN_B) ? bsum[i] : 0;
    ls[i] = v;
    __syncthreads();
    for (int off = 1; off < 512; off <<= 1) {
        int t = (i >= off) ? ls[i - off] : 0;
        __syncthreads();
        ls[i] += t;
        __syncthreads();
    }
    if (i < SCAN_B) bsum[i] = ls[i] - v;
    if (i == SCAN_B - 1) rp[NN] = ls[i];
}

__global__ void scan3_k(int* __restrict__ rp, const int* __restrict__ bsum) {
    int i = blockIdx.x * 256 + threadIdx.x;
    if (i < NN) rp[i] += bsum[blockIdx.x];
}

__global__ void csr_fill_k(const int* __restrict__ src, const int* __restrict__ dst,
                           const int* __restrict__ mask,
                           const float* __restrict__ dis1, const float* __restrict__ dis2m,
                           const int* __restrict__ rp1, const int* __restrict__ rp2,
                           int* __restrict__ cur1, int* __restrict__ cur2,
                           int2* __restrict__ em1, int2* __restrict__ em2) {
    int e = blockIdx.x * 256 + threadIdx.x;
    if (e >= NE) return;
    int s = src[e], d = dst[e];
    float n1 = dis1[s] * dis1[d];
    int p1 = rp1[d] + atomicAdd(&cur1[d], 1);
    em1[p1] = make_int2(s, __float_as_int(n1));
    if (mask[e]) {
        float n2 = dis2m[s] * dis2m[d];
        int p2 = rp2[d] + atomicAdd(&cur2[d], 1);
        em2[p2] = make_int2(s, __float_as_int(n2));
    }
}

// sort a dst segment by src; duplicates have identical payloads.
__device__ void seg_sort_node(int2* __restrict__ em, int beg, int end,
                              int* skey, int* snrm, int lane) {
    int L = end - beg;
    if (L <= 1) return;
    if (L <= 64) {
        int k = INT_MAX; int2 pl = make_int2(0, 0);
        if (lane < L) { pl = em[beg + lane]; k = pl.x; }
        for (int r = 0; r < L; r++) {
            int mn = k;
#pragma unroll
            for (int off = 32; off > 0; off >>= 1)
                mn = min(mn, __shfl_xor(mn, off, 64));
            u64 msk = __ballot(k == mn);
            int leader = (int)__ffsll((unsigned long long)msk) - 1;
            if (lane == leader) { em[beg + r] = pl; k = INT_MAX; }
        }
    } else if (L <= 512) {
        for (int i = lane; i < L; i += 64) {
            int2 p = em[beg + i];
            skey[i] = p.x;
            snrm[i] = p.y;
        }
        for (int it = 0; it < L; it++) {
            int par = it & 1;
            for (int p = par + 2 * lane; p + 1 < L; p += 128) {
                int ka = skey[p], kb = skey[p + 1];
                if (kb < ka) {
                    skey[p] = kb; skey[p + 1] = ka;
                    int t = snrm[p]; snrm[p] = snrm[p + 1]; snrm[p + 1] = t;
                }
            }
        }
        for (int i = lane; i < L; i += 64)
            em[beg + i] = make_int2(skey[i], snrm[i]);
    }
}

#define NB_ROW4C (NN / 4)

__global__ __launch_bounds__(256) void seg_sort2_k(int2* __restrict__ em1,
                                                   const int* __restrict__ rp1,
                                                   int2* __restrict__ em2,
                                                   const int* __restrict__ rp2) {
    __shared__ int skey[4][512];
    __shared__ int snrm[4][512];
    int tid = threadIdx.x, lane = tid & 63, w = tid >> 6;
    int bid = blockIdx.x;
    if (bid < NB_ROW4C) {
        int n = bid * 4 + w;
        seg_sort_node(em1, rp1[n], rp1[n + 1], skey[w], snrm[w], lane);
    } else {
        int n = (bid - NB_ROW4C) * 4 + w;
        seg_sort_node(em2, rp2[n], rp2[n + 1], skey[w], snrm[w], lane);
    }
}

// ---------------- GEMM (float input, layer 0 only) ----------------

__global__ __launch_bounds__(256) void gemm_k(const float* __restrict__ in,
                                              const float* __restrict__ W,
                                              float* __restrict__ xw) {
    __shared__ float sW[64 * 64];
    __shared__ float sx[32 * 65];
    int tid = threadIdx.x;
    const float4* W4 = (const float4*)W;
    float4* sW4 = (float4*)sW;
    for (int i = tid; i < 1024; i += 256) sW4[i] = W4[i];
    const float* inb = in + (size_t)blockIdx.x * 2048;
    for (int i = tid; i < 2048; i += 256) sx[(i >> 6) * 65 + (i & 63)] = inb[i];
    __syncthreads();
    int cg = tid & 15, rr = tid >> 4;
    float a0 = 0, a1 = 0, a2 = 0, a3 = 0, c0 = 0, c1 = 0, c2 = 0, c3 = 0;
#pragma unroll
    for (int k = 0; k < 64; k++) {
        float4 wv = *(const float4*)&sW[k * 64 + cg * 4];
        float xa = sx[rr * 65 + k];
        float xb = sx[(rr + 16) * 65 + k];
        a0 += xa * wv.x; a1 += xa * wv.y; a2 += xa * wv.z; a3 += xa * wv.w;
        c0 += xb * wv.x; c1 += xb * wv.y; c2 += xb * wv.z; c3 += xb * wv.w;
    }
    size_t r0 = (size_t)(blockIdx.x * 32 + rr) * 64 + cg * 4;
    size_t r1 = (size_t)(blockIdx.x * 32 + rr + 16) * 64 + cg * 4;
    *(float4*)&xw[r0] = make_float4(a0, a1, a2, a3);
    *(float4*)&xw[r1] = make_float4(c0, c1, c2, c3);
}

// ---------------- standalone bit GEMM (path B only) ----------------

__global__ __launch_bounds__(256) void bitgemm_k(const u64* __restrict__ bits,
                                                 const float* __restrict__ W,
                                                 float* __restrict__ xw) {
    __shared__ float sW[64 * 64];
    int tid = threadIdx.x;
    const float4* W4 = (const float4*)W;
    float4* sW4 = (float4*)sW;
    for (int i = tid; i < 1024; i += 256) sW4[i] = W4[i];
    __syncthreads();
    int lane = tid & 63, w = tid >> 6;
    int n0 = blockIdx.x * 64 + w * 16;
    for (int t = 0; t < 16; t++) {
        int n = n0 + t;
        if (n >= NN) return;
        u64 m = bits[n];
        float acc = 0.0f;
        while (m) {
            int k = (int)__builtin_ctzll(m);
            m &= m - 1;
            acc += sW[k * 64 + lane];
        }
        xw[(size_t)n * 64 + lane] = acc;
    }
}

// ---------------- sequential stats-fused gathers (R10 numerics) ----------------

__global__ __launch_bounds__(256) void gather_stats_k(const float* __restrict__ xw,
                                                      const int2* __restrict__ em,
                                                      const int* __restrict__ rp,
                                                      const float* __restrict__ d2i,
                                                      const float* __restrict__ bias,
                                                      float* __restrict__ out,
                                                      double* __restrict__ part) {
    int tid = threadIdx.x, lane = tid & 63, w = tid >> 6;
    double ps = 0.0, pq = 0.0;
    for (int n = blockIdx.x * 4 + w; n < NN; n += NBE * 4) {
        int beg = rp[n], end = rp[n + 1];
        float self = d2i[n] * xw[(size_t)n * 64 + lane] + bias[lane];
        float acc = 0.0f;
        for (int base = beg; base < end; base += 64) {
            int cnt = min(64, end - base);
            int2 m = make_int2(0, 0);
            if (base + lane < end) m = em[base + lane];
            int j = 0;
            for (; j + 8 <= cnt; j += 8) {
                int s0 = __shfl(m.x, j, 64),     s1 = __shfl(m.x, j + 1, 64);
                int s2 = __shfl(m.x, j + 2, 64), s3 = __shfl(m.x, j + 3, 64);
                int s4 = __shfl(m.x, j + 4, 64), s5 = __shfl(m.x, j + 5, 64);
                int s6 = __shfl(m.x, j + 6, 64), s7 = __shfl(m.x, j + 7, 64);
                float n0 = __int_as_float(__shfl(m.y, j, 64));
                float n1 = __int_as_float(__shfl(m.y, j + 1, 64));
                float n2 = __int_as_float(__shfl(m.y, j + 2, 64));
                float n3 = __int_as_float(__shfl(m.y, j + 3, 64));
                float n4 = __int_as_float(__shfl(m.y, j + 4, 64));
                float n5 = __int_as_float(__shfl(m.y, j + 5, 64));
                float n6 = __int_as_float(__shfl(m.y, j + 6, 64));
                float n7 = __int_as_float(__shfl(m.y, j + 7, 64));
                float v0 = xw[(size_t)s0 * 64 + lane];
                float v1 = xw[(size_t)s1 * 64 + lane];
                float v2 = xw[(size_t)s2 * 64 + lane];
                float v3 = xw[(size_t)s3 * 64 + lane];
                float v4 = xw[(size_t)s4 * 64 + lane];
                float v5 = xw[(size_t)s5 * 64 + lane];
                float v6 = xw[(size_t)s6 * 64 + lane];
                float v7 = xw[(size_t)s7 * 64 + lane];
                acc += n0 * v0; acc += n1 * v1; acc += n2 * v2; acc += n3 * v3;
                acc += n4 * v4; acc += n5 * v5; acc += n6 * v6; acc += n7 * v7;
            }
            for (; j < cnt; j++) {
                int s = __shfl(m.x, j, 64);
                float nv = __int_as_float(__shfl(m.y, j, 64));
                acc += nv * xw[(size_t)s * 64 + lane];
            }
        }
        float o = acc + self;
        out[(size_t)n * 64 + lane] = o;
        ps += (double)o;
        pq += (double)o * (double)o;
    }
    __shared__ double ls[4][64], lq[4][64];
    ls[w][lane] = ps; lq[w][lane] = pq;
    __syncthreads();
    if (tid < 64) {
        double a = ls[0][tid] + ls[1][tid] + ls[2][tid] + ls[3][tid];
        double b = lq[0][tid] + lq[1][tid] + lq[2][tid] + lq[3][tid];
        part[(size_t)blockIdx.x * 128 + tid] = a;
        part[(size_t)blockIdx.x * 128 + 64 + tid] = b;
    }
}

__global__ __launch_bounds__(256) void gather2_stats_k(const float* __restrict__ xa,
                                                       const float* __restrict__ xb,
                                                       const int2* __restrict__ em,
                                                       const int* __restrict__ rp,
                                                       const float* __restrict__ d2i,
                                                       const float* __restrict__ ba,
                                                       const float* __restrict__ bb,
                                                       float* __restrict__ oa,
                                                       float* __restrict__ ob,
                                                       double* __restrict__ part) {
    int tid = threadIdx.x, lane = tid & 63, w = tid >> 6;
    double sA = 0.0, qA = 0.0, sB = 0.0, qB = 0.0;
    for (int n = blockIdx.x * 4 + w; n < NN; n += NBE * 4) {
        int beg = rp[n], end = rp[n + 1];
        float selfa = d2i[n] * xa[(size_t)n * 64 + lane] + ba[lane];
        float selfb = d2i[n] * xb[(size_t)n * 64 + lane] + bb[lane];
        float acca = 0.0f, accb = 0.0f;
        for (int base = beg; base < end; base += 64) {
            int cnt = min(64, end - base);
            int2 m = make_int2(0, 0);
            if (base + lane < end) m = em[base + lane];
            int j = 0;
            for (; j + 8 <= cnt; j += 8) {
#pragma unroll
                for (int u = 0; u < 8; u++) {
                    int s = __shfl(m.x, j + u, 64);
                    float nv = __int_as_float(__shfl(m.y, j + u, 64));
                    acca += nv * xa[(size_t)s * 64 + lane];
                    accb += nv * xb[(size_t)s * 64 + lane];
                }
            }
            for (; j < cnt; j++) {
                int s = __shfl(m.x, j, 64);
                float nv = __int_as_float(__shfl(m.y, j, 64));
                acca += nv * xa[(size_t)s * 64 + lane];
                accb += nv * xb[(size_t)s * 64 + lane];
            }
        }
        size_t o = (size_t)n * 64 + lane;
        float va = acca + selfa;
        float vb = accb + selfb;
        oa[o] = va;
        ob[o] = vb;
        sA += (double)va; qA += (double)va * (double)va;
        sB += (double)vb; qB += (double)vb * (double)vb;
    }
    __shared__ double l1[4][64], l2[4][64], l3[4][64], l4[4][64];
    l1[w][lane] = sA; l2[w][lane] = qA; l3[w][lane] = sB; l4[w][lane] = qB;
    __syncthreads();
    if (tid < 64) {
        size_t o = (size_t)blockIdx.x * 256;
        part[o + tid]       = l1[0][tid] + l1[1][tid] + l1[2][tid] + l1[3][tid];
        part[o + 64 + tid]  = l2[0][tid] + l2[1][tid] + l2[2][tid] + l2[3][tid];
        part[o + 128 + tid] = l3[0][tid] + l3[1][tid] + l3[2][tid] + l3[3][tid];
        part[o + 192 + tid] = l4[0][tid] + l4[1][tid] + l4[2][tid] + l4[3][tid];
    }
}

// triple gather: three independent sequential accumulators per output —
// each output bit-identical to its standalone gather.
__global__ __launch_bounds__(256) void gather3_stats_k(const float* __restrict__ xa,
                                                       const float* __restrict__ xb,
                                                       const float* __restrict__ xc,
                                                       const int2* __restrict__ em,
                                                       const int* __restrict__ rp,
                                                       const float* __restrict__ d2i,
                                                       const float* __restrict__ ba,
                                                       const float* __restrict__ bb,
                                                       const float* __restrict__ bc,
                                                       float* __restrict__ oa,
                                                       float* __restrict__ ob,
                                                       float* __restrict__ oc,
                                                       double* __restrict__ part) {
    int tid = threadIdx.x, lane = tid & 63, w = tid >> 6;
    double sA = 0.0, qA = 0.0, sB = 0.0, qB = 0.0, sC = 0.0, qC = 0.0;
    for (int n = blockIdx.x * 4 + w; n < NN; n += NBE * 4) {
        int beg = rp[n], end = rp[n + 1];
        float selfa = d2i[n] * xa[(size_t)n * 64 + lane] + ba[lane];
        float selfb = d2i[n] * xb[(size_t)n * 64 + lane] + bb[lane];
        float selfc = d2i[n] * xc[(size_t)n * 64 + lane] + bc[lane];
        float acca = 0.0f, accb = 0.0f, accc = 0.0f;
        for (int base = beg; base < end; base += 64) {
            int cnt = min(64, end - base);
            int2 m = make_int2(0, 0);
            if (base + lane < end) m = em[base + lane];
            int j = 0;
            for (; j + 4 <= cnt; j += 4) {
#pragma unroll
                for (int u = 0; u < 4; u++) {
                    int s = __shfl(m.x, j + u, 64);
                    float nv = __int_as_float(__shfl(m.y, j + u, 64));
                    acca += nv * xa[(size_t)s * 64 + lane];
                    accb += nv * xb[(size_t)s * 64 + lane];
                    accc += nv * xc[(size_t)s * 64 + lane];
                }
            }
            for (; j < cnt; j++) {
                int s = __shfl(m.x, j, 64);
                float nv = __int_as_float(__shfl(m.y, j, 64));
                acca += nv * xa[(size_t)s * 64 + lane];
                accb += nv * xb[(size_t)s * 64 + lane];
                accc += nv * xc[(size_t)s * 64 + lane];
            }
        }
        size_t o = (size_t)n * 64 + lane;
        float va = acca + selfa;
        float vb = accb + selfb;
        float vc = accc + selfc;
        oa[o] = va; ob[o] = vb; oc[o] = vc;
        sA += (double)va; qA += (double)va * (double)va;
        sB += (double)vb; qB += (double)vb * (double)vb;
        sC += (double)vc; qC += (double)vc * (double)vc;
    }
    __shared__ double l1[4][64], l2[4][64], l3[4][64], l4[4][64], l5[4][64], l6[4][64];
    l1[w][lane] = sA; l2[w][lane] = qA; l3[w][lane] = sB;
    l4[w][lane] = qB; l5[w][lane] = sC; l6[w][lane] = qC;
    __syncthreads();
    if (tid < 64) {
        size_t o = (size_t)blockIdx.x * 384;
        part[o + tid]       = l1[0][tid] + l1[1][tid] + l1[2][tid] + l1[3][tid];
        part[o + 64 + tid]  = l2[0][tid] + l2[1][tid] + l2[2][tid] + l2[3][tid];
        part[o + 128 + tid] = l3[0][tid] + l3[1][tid] + l3[2][tid] + l3[3][tid];
        part[o + 192 + tid] = l4[0][tid] + l4[1][tid] + l4[2][tid] + l4[3][tid];
        part[o + 256 + tid] = l5[0][tid] + l5[1][tid] + l5[2][tid] + l5[3][tid];
        part[o + 320 + tid] = l6[0][tid] + l6[1][tid] + l6[2][tid] + l6[3][tid];
    }
}

// ---------------- deterministic partial reduces ----------------

__global__ __launch_bounds__(256) void bn_red_k(const double* __restrict__ part,
                                                double* __restrict__ st) {
    __shared__ double tr[256];
    int t = threadIdx.x, c = blockIdx.x;
    double s = 0.0;
    for (int b = t; b < NBE; b += 256) s += part[(size_t)b * 128 + c];
    tr[t] = s;
    __syncthreads();
    for (int off = 128; off > 0; off >>= 1) {
        if (t < off) tr[t] += tr[t + off];
        __syncthreads();
    }
    if (t == 0) st[c] = tr[0];
}

__global__ __launch_bounds__(256) void bn_red2_k(const double* __restrict__ part,
                                                 double* __restrict__ sta,
                                                 double* __restrict__ stb) {
    __shared__ double tr[256];
    int t = threadIdx.x, c = blockIdx.x;
    double s = 0.0;
    for (int b = t; b < NBE; b += 256) s += part[(size_t)b * 256 + c];
    tr[t] = s;
    __syncthreads();
    for (int off = 128; off > 0; off >>= 1) {
        if (t < off) tr[t] += tr[t + off];
        __syncthreads();
    }
    if (t == 0) {
        if (c < 128) sta[c] = tr[0];
        else stb[c - 128] = tr[0];
    }
}

__global__ __launch_bounds__(256) void bn_red3_k(const double* __restrict__ part,
                                                 double* __restrict__ sta,
                                                 double* __restrict__ stb,
                                                 double* __restrict__ stc) {
    __shared__ double tr[256];
    int t = threadIdx.x, c = blockIdx.x;   // c in [0,384)
    double s = 0.0;
    for (int b = t; b < NBE; b += 256) s += part[(size_t)b * 384 + c];
    tr[t] = s;
    __syncthreads();
    for (int off = 128; off > 0; off >>= 1) {
        if (t < off) tr[t] += tr[t + off];
        __syncthreads();
    }
    if (t == 0) {
        if (c < 128) sta[c] = tr[0];
        else if (c < 256) stb[c - 128] = tr[0];
        else stc[c - 256] = tr[0];
    }
}

__device__ inline void bn_ss(const double* __restrict__ st, const float* __restrict__ gam,
                             const float* __restrict__ bet, int c,
                             float* __restrict__ ssc, float* __restrict__ ssh) {
    double m = st[c] * (1.0 / NN);
    double v = st[64 + c] * (1.0 / NN) - m * m;
    float scale = (float)((double)gam[c] / sqrt(v + (double)EPSF));
    ssc[c] = scale;
    ssh[c] = bet[c] - (float)m * scale;
}

// ---------------- fused spike + bitgemm kernels ----------------

__global__ __launch_bounds__(256) void lif_bitgemm_k(const float* __restrict__ G,
                                                     const double* __restrict__ st,
                                                     const float* __restrict__ gam,
                                                     const float* __restrict__ bet,
                                                     float* __restrict__ vconv,
                                                     const float* __restrict__ W,
                                                     float* __restrict__ xw) {
    __shared__ float sW[4096];
    __shared__ float ssc[64], ssh[64];
    int tid = threadIdx.x;
    if (tid < 64) bn_ss(st, gam, bet, tid, ssc, ssh);
    const float4* W4 = (const float4*)W;
    float4* sW4 = (float4*)sW;
    for (int i = tid; i < 1024; i += 256) sW4[i] = W4[i];
    __syncthreads();
    int lane = tid & 63;
    size_t i = (size_t)blockIdx.x * 256 + tid;
    float v = vconv[i] + (G[i] * ssc[lane] + ssh[lane]);
    bool sp = (v - THF >= 0.0f);
    u64 m = __ballot(sp);
    vconv[i] = sp ? 0.0f : v;
    float acc = 0.0f;
    while (m) {
        int k = (int)__builtin_ctzll(m);
        m &= m - 1;
        acc += sW[k * 64 + lane];
    }
    xw[i] = acc;
}

__global__ __launch_bounds__(256) void spike_bitgemm_k(const float* __restrict__ G,
                                                       const double* __restrict__ st,
                                                       const float* __restrict__ gam,
                                                       const float* __restrict__ bet,
                                                       float* __restrict__ x3,
                                                       const float* __restrict__ W,
                                                       float* __restrict__ xw) {
    __shared__ float sW[4096];
    __shared__ float ssc[64], ssh[64];
    int tid = threadIdx.x;
    if (tid < 64) bn_ss(st, gam, bet, tid, ssc, ssh);
    const float4* W4 = (const float4*)W;
    float4* sW4 = (float4*)sW;
    for (int i = tid; i < 1024; i += 256) sW4[i] = W4[i];
    __syncthreads();
    int lane = tid & 63;
    size_t i = (size_t)blockIdx.x * 256 + tid;
    float xv = G[i] * ssc[lane] + ssh[lane];
    x3[i] = xv;
    u64 m = __ballot(xv - THF >= 0.0f);
    float acc = 0.0f;
    while (m) {
        int k = (int)__builtin_ctzll(m);
        m &= m - 1;
        acc += sW[k * 64 + lane];
    }
    xw[i] = acc;
}

__global__ __launch_bounds__(256) void lif_bitgemm2_k(const float* __restrict__ F,
                                                      const double* __restrict__ st,
                                                      const float* __restrict__ gam,
                                                      const float* __restrict__ bet,
                                                      float* __restrict__ vconv,
                                                      float* __restrict__ x4,
                                                      u64* __restrict__ sbits,
                                                      const float* __restrict__ Wa,
                                                      const float* __restrict__ Wb,
                                                      float* __restrict__ xwa,
                                                      float* __restrict__ xwb) {
    __shared__ float sA[4096], sB[4096];
    __shared__ float ssc[64], ssh[64];
    int tid = threadIdx.x;
    if (tid < 64) bn_ss(st, gam, bet, tid, ssc, ssh);
    const float4* A4 = (const float4*)Wa;
    const float4* B4 = (const float4*)Wb;
    float4* sA4 = (float4*)sA;
    float4* sB4 = (float4*)sB;
    for (int i = tid; i < 1024; i += 256) { sA4[i] = A4[i]; sB4[i] = B4[i]; }
    __syncthreads();
    int lane = tid & 63;
    size_t i = (size_t)blockIdx.x * 256 + tid;
    float xv = F[i] * ssc[lane] + ssh[lane];
    x4[i] = xv;
    float v = vconv[i] + xv;
    bool sp = (v - THF >= 0.0f);
    u64 m = __ballot(sp);
    vconv[i] = sp ? 0.0f : v;
    if (lane == 0) sbits[i >> 6] = m;
    float a = 0.0f, b = 0.0f;
    while (m) {
        int k = (int)__builtin_ctzll(m);
        m &= m - 1;
        a += sA[k * 64 + lane];
        b += sB[k * 64 + lane];
    }
    xwa[i] = a;
    xwb[i] = b;
}

// triple projection (path A)
__global__ __launch_bounds__(256) void lif_bitgemm3_k(const float* __restrict__ F,
                                                      const double* __restrict__ st,
                                                      const float* __restrict__ gam,
                                                      const float* __restrict__ bet,
                                                      float* __restrict__ vconv,
                                                      float* __restrict__ x4,
                                                      const float* __restrict__ Wa,
                                                      const float* __restrict__ Wb,
                                                      const float* __restrict__ Wc,
                                                      float* __restrict__ xwa,
                                                      float* __restrict__ xwb,
                                                      float* __restrict__ xwc) {
    __shared__ float sA[4096], sB[4096], sC[4096];
    __shared__ float ssc[64], ssh[64];
    int tid = threadIdx.x;
    if (tid < 64) bn_ss(st, gam, bet, tid, ssc, ssh);
    const float4* A4 = (const float4*)Wa;
    const float4* B4 = (const float4*)Wb;
    const float4* C4 = (const float4*)Wc;
    float4* sA4 = (float4*)sA;
    float4* sB4 = (float4*)sB;
    float4* sC4 = (float4*)sC;
    for (int i = tid; i < 1024; i += 256) { sA4[i] = A4[i]; sB4[i] = B4[i]; sC4[i] = C4[i]; }
    __syncthreads();
    int lane = tid & 63;
    size_t i = (size_t)blockIdx.x * 256 + tid;
    float xv = F[i] * ssc[lane] + ssh[lane];
    x4[i] = xv;
    float v = vconv[i] + xv;
    bool sp = (v - THF >= 0.0f);
    u64 m = __ballot(sp);
    vconv[i] = sp ? 0.0f : v;
    float a = 0.0f, b = 0.0f, c = 0.0f;
    while (m) {
        int k = (int)__builtin_ctzll(m);
        m &= m - 1;
        a += sA[k * 64 + lane];
        b += sB[k * 64 + lane];
        c += sC[k * 64 + lane];
    }
    xwa[i] = a;
    xwb[i] = b;
    xwc[i] = c;
}

__global__ __launch_bounds__(256) void qkv_att_bitgemm_k(const float* __restrict__ Gq,
                                                         const float* __restrict__ Gk,
                                                         const float* __restrict__ Gv,
                                                         const double* __restrict__ st4,
                                                         const double* __restrict__ st5,
                                                         const double* __restrict__ st6,
                                                         const float* __restrict__ gam4,
                                                         const float* __restrict__ bet4,
                                                         const float* __restrict__ gam5,
                                                         const float* __restrict__ bet5,
                                                         const float* __restrict__ gam6,
                                                         const float* __restrict__ bet6,
                                                         const float* __restrict__ W,
                                                         float* __restrict__ xw) {
    __shared__ float sW[4096];
    __shared__ float sc4[64], sh4[64], sc5[64], sh5[64], sc6[64], sh6[64];
    int tid = threadIdx.x;
    if (tid < 64) {
        bn_ss(st4, gam4, bet4, tid, sc4, sh4);
        bn_ss(st5, gam5, bet5, tid, sc5, sh5);
        bn_ss(st6, gam6, bet6, tid, sc6, sh6);
    }
    const float4* W4 = (const float4*)W;
    float4* sW4 = (float4*)sW;
    for (int i = tid; i < 1024; i += 256) sW4[i] = W4[i];
    __syncthreads();
    int lane = tid & 63;
    size_t i = (size_t)blockIdx.x * 256 + tid;
    bool qb = (Gq[i] * sc4[lane] + sh4[lane] - THF >= 0.0f);
    bool kb = (Gk[i] * sc5[lane] + sh5[lane] - THF >= 0.0f);
    bool vb = (Gv[i] * sc6[lane] + sh6[lane] - THF >= 0.0f);
    int pc = __popcll(__ballot(qb && kb));
    bool qs = ((float)pc * (1.0f / 64.0f) - ATTTH >= 0.0f);
    u64 m = __ballot(vb && qs);
    float acc = 0.0f;
    while (m) {
        int k = (int)__builtin_ctzll(m);
        m &= m - 1;
        acc += sW[k * 64 + lane];
    }
    xw[i] = acc;
}

// ---------------- remaining elementwise (with fused stats) ----------------

__global__ __launch_bounds__(256) void bn_add_stats_k(const float* __restrict__ G,
                                                      const double* __restrict__ st,
                                                      const float* __restrict__ gam,
                                                      const float* __restrict__ bet,
                                                      const float* __restrict__ x3,
                                                      float* __restrict__ F,
                                                      double* __restrict__ part) {
    __shared__ float ssc[64], ssh[64];
    int tid = threadIdx.x;
    if (tid < 64) bn_ss(st, gam, bet, tid, ssc, ssh);
    __syncthreads();
    int c = tid & 63;
    double s = 0.0, s2 = 0.0;
    for (size_t i = (size_t)blockIdx.x * 256 + tid; i < NHTOT; i += (size_t)NBE * 256) {
        float f = (G[i] * ssc[c] + ssh[c]) + x3[i];
        F[i] = f;
        s += (double)f;
        s2 += (double)f * (double)f;
    }
    __shared__ double ls[256], lq[256];
    ls[tid] = s; lq[tid] = s2;
    __syncthreads();
    if (tid < 64) {
        double a = ls[tid] + ls[tid + 64] + ls[tid + 128] + ls[tid + 192];
        double b = lq[tid] + lq[tid + 64] + lq[tid + 128] + lq[tid + 192];
        part[(size_t)blockIdx.x * 128 + tid] = a;
        part[(size_t)blockIdx.x * 128 + 64 + tid] = b;
    }
}

__global__ __launch_bounds__(256) void bn_scale_add_stats_k(const float* __restrict__ G,
                                                            const double* __restrict__ st,
                                                            const float* __restrict__ gam,
                                                            const float* __restrict__ bet,
                                                            const float* __restrict__ x4,
                                                            float* __restrict__ tmp2,
                                                            double* __restrict__ part) {
    __shared__ float ssc[64], ssh[64];
    int tid = threadIdx.x;
    if (tid < 64) bn_ss(st, gam, bet, tid, ssc, ssh);
    __syncthreads();
    int c = tid & 63;
    double s = 0.0, s2 = 0.0;
    for (size_t i = (size_t)blockIdx.x * 256 + tid; i < NHTOT; i += (size_t)NBE * 256) {
        float f = x4[i] + 0.125f * (G[i] * ssc[c] + ssh[c]);
        tmp2[i] = f;
        s += (double)f;
        s2 += (double)f * (double)f;
    }
    __shared__ double ls[256], lq[256];
    ls[tid] = s; lq[tid] = s2;
    __syncthreads();
    if (tid < 64) {
        double a = ls[tid] + ls[tid + 64] + ls[tid + 128] + ls[tid + 192];
        double b = lq[tid] + lq[tid + 64] + lq[tid + 128] + lq[tid + 192];
        part[(size_t)blockIdx.x * 128 + tid] = a;
        part[(size_t)blockIdx.x * 128 + 64 + tid] = b;
    }
}

__global__ __launch_bounds__(256) void decode_k(const float* __restrict__ tmp2,
                                                const double* __restrict__ st,
                                                const float* __restrict__ gam,
                                                const float* __restrict__ bet,
                                                const float* __restrict__ wrow,
                                                float* __restrict__ z) {
    __shared__ float ssc[64], ssh[64];
    int tid = threadIdx.x;
    if (tid < 64) bn_ss(st, gam, bet, tid, ssc, ssh);
    __syncthreads();
    int lane = tid & 63;
    int row = blockIdx.x * 4 + (tid >> 6);
    float sv = tmp2[(size_t)row * 64 + lane] * ssc[lane] + ssh[lane];
    float p = sv * wrow[lane];
#pragma unroll
    for (int off = 32; off > 0; off >>= 1) p += __shfl_xor(p, off, 64);
    if (lane == 0) z[row] = p;
}

__global__ void wrow_k(const float* __restrict__ W_lin, float* __restrict__ wrow) {
    int h = threadIdx.x;
    if (h >= 64) return;
    float s = 0.0f;
    for (int j = 0; j < 64; j++) s += W_lin[h * 64 + j];
    wrow[h] = s;
}

// ---------------- host driver ----------------

extern "C" void kernel_launch(void* const* d_in, const int* in_sizes, int n_in,
                              void* d_out, int out_size, void* d_ws, size_t ws_size,
                              hipStream_t stream) {
    const float* x    = (const float*)d_in[0];
    const int* eidx   = (const int*)d_in[1];
    const int* emask  = (const int*)d_in[2];
    const float* Wg   = (const float*)d_in[3];
    const float* bg   = (const float*)d_in[4];
    const float* bng  = (const float*)d_in[5];
    const float* bnb  = (const float*)d_in[6];
    const float* Wlin = (const float*)d_in[7];
    float* zout = (float*)d_out;

    const int* srcp = eidx;
    const int* dstp = eidx + NE;
    const size_t NH = (size_t)NN * HH;

    // ---- workspace layout (float units; doubles land 8B-aligned) ----
    float* ws = (float*)d_ws;
    size_t off = 0;
    float* P1 = ws + off; off += NH;
    float* P2 = ws + off; off += NH;
    float* P3 = ws + off; off += NH;
    float* P4 = ws + off; off += NH;
    float* P5 = ws + off; off += NH;
    float* vconv = ws + off; off += NH;
    int2* em1 = (int2*)(ws + off); off += 2 * (size_t)NE;
    int2* em2 = (int2*)(ws + off); off += 2 * (size_t)EM2CAP;
    u64* sbits = (u64*)(ws + off); off += 2 * (size_t)NN;
    double* part = (double*)(ws + off); off += 2 * (size_t)NBE * 384;
    double* stats = (double*)(ws + off); off += 2 * 18 * 128;
    float* dis1 = ws + off; off += NN;
    float* d21  = ws + off; off += NN;
    float* dis2m = ws + off; off += NN;
    float* d22  = ws + off; off += NN;
    float* wrow = ws + off; off += 64;
    int* rp1 = (int*)(ws + off); off += NN + 2;
    int* rp2 = (int*)(ws + off); off += NN + 2;
    int* cnt1 = (int*)(ws + off); off += NN;
    int* cnt2 = (int*)(ws + off); off += NN;
    int* cur1 = (int*)(ws + off); off += NN;
    int* cur2 = (int*)(ws + off); off += NN;
    int* bsum = (int*)(ws + off); off += SCAN_B + 2;
    size_t needB = off * 4;
    // path-A extra buffers
    float* P6 = ws + off; off += NH;
    float* P7 = ws + off; off += NH;
    size_t needA = off * 4;
    const bool pathA = (ws_size >= needA);
    (void)needB;

    hipMemsetAsync(cnt1, 0, 4 * NN * sizeof(int), stream);
    hipMemsetAsync(vconv, 0, NH * sizeof(float), stream);

    const int NB_EDGE = NE / 256;
    const int NB_NODE = SCAN_B;
    const int NB_ROW4 = NN / 4;
    const int NB_GEMM = NN / 32;
    const int NB_BG   = (NN + 63) / 64;

    wrow_k<<<1, 64, 0, stream>>>(Wlin, wrow);
    hist_k<<<NB_EDGE, 256, 0, stream>>>(dstp, emask, cnt1, cnt2);
    deg_inv2_k<<<NB_NODE, 256, 0, stream>>>(cnt1, cnt2, dis1, d21, dis2m, d22);
    scan1_k<<<NB_NODE, 256, 0, stream>>>(cnt1, rp1, bsum);
    scan2_k<<<1, 512, 0, stream>>>(bsum, rp1);
    scan3_k<<<NB_NODE, 256, 0, stream>>>(rp1, bsum);
    scan1_k<<<NB_NODE, 256, 0, stream>>>(cnt2, rp2, bsum);
    scan2_k<<<1, 512, 0, stream>>>(bsum, rp2);
    scan3_k<<<NB_NODE, 256, 0, stream>>>(rp2, bsum);
    csr_fill_k<<<NB_EDGE, 256, 0, stream>>>(srcp, dstp, emask, dis1, dis2m,
                                            rp1, rp2, cur1, cur2, em1, em2);
    seg_sort2_k<<<2 * NB_ROW4, 256, 0, stream>>>(em1, rp1, em2, rp2);

    auto enc = [&](const int2* em, const int* rp, const float* d2i, int bnbase,
                   float* zo) {
        auto ST = [&](int bni) { return stats + (bnbase + bni) * 128; };
        auto W = [&](int wi) { return Wg + wi * 4096; };
        auto BI = [&](int wi) { return bg + wi * 64; };
        auto GM = [&](int bi) { return bng + bi * 64; };
        auto BT = [&](int bi) { return bnb + bi * 64; };
        auto gatherS = [&](const float* xw, int wi, float* out, int bni) {
            gather_stats_k<<<NBE, 256, 0, stream>>>(xw, em, rp, d2i, BI(wi), out, part);
            bn_red_k<<<128, 256, 0, stream>>>(part, ST(bni));
        };

        // L0: float gemm
        gemm_k<<<NB_GEMM, 256, 0, stream>>>(x, W(0), P1);
        gatherS(P1, 0, P2, 0);
        lif_bitgemm_k<<<NB_ROW4, 256, 0, stream>>>(P2, ST(0), GM(0), BT(0),
                                                   vconv, W(1), P1);
        // L1
        gatherS(P1, 1, P2, 1);
        spike_bitgemm_k<<<NB_ROW4, 256, 0, stream>>>(P2, ST(1), GM(1), BT(1),
                                                     P3, W(2), P1);
        // pos layer
        gatherS(P1, 2, P2, 2);
        bn_add_stats_k<<<NBE, 256, 0, stream>>>(P2, ST(2), GM(2), BT(2), P3, P4, part);
        bn_red_k<<<128, 256, 0, stream>>>(part, ST(3));

        if (pathA) {
            lif_bitgemm3_k<<<NB_ROW4, 256, 0, stream>>>(P4, ST(3), GM(3), BT(3),
                                                        vconv, P4,
                                                        W(3), W(4), W(5), P1, P2, P3);
            gather3_stats_k<<<NBE, 256, 0, stream>>>(P1, P2, P3, em, rp, d2i,
                                                     BI(3), BI(4), BI(5),
                                                     P5, P6, P7, part);
            bn_red3_k<<<384, 256, 0, stream>>>(part, ST(4), ST(5), ST(6));
            qkv_att_bitgemm_k<<<NB_ROW4, 256, 0, stream>>>(P5, P6, P7,
                                                           ST(4), ST(5), ST(6),
                                                           GM(4), BT(4), GM(5), BT(5),
                                                           GM(6), BT(6), W(6), P1);
        } else {
            lif_bitgemm2_k<<<NB_ROW4, 256, 0, stream>>>(P4, ST(3), GM(3), BT(3),
                                                        vconv, P4, sbits,
                                                        W(3), W(4), P1, P3);
            gather2_stats_k<<<NBE, 256, 0, stream>>>(P1, P3, em, rp, d2i, BI(3), BI(4),
                                                     P2, P5, part);
            bn_red2_k<<<256, 256, 0, stream>>>(part, ST(4), ST(5));
            bitgemm_k<<<NB_BG, 256, 0, stream>>>(sbits, W(5), P1);
            gatherS(P1, 5, P3, 6);
            qkv_att_bitgemm_k<<<NB_ROW4, 256, 0, stream>>>(P2, P5, P3,
                                                           ST(4), ST(5), ST(6),
                                                           GM(4), BT(4), GM(5), BT(5),
                                                           GM(6), BT(6), W(6), P1);
        }
        // att gcn
        gatherS(P1, 6, P2, 7);
        bn_scale_add_stats_k<<<NBE, 256, 0, stream>>>(P2, ST(7), GM(7), BT(7),
                                                      P4, P3, part);   // tmp2=P3
        bn_red_k<<<128, 256, 0, stream>>>(part, ST(8));
        decode_k<<<NB_ROW4, 256, 0, stream>>>(P3, ST(8), GM(8), BT(8), wrow, zo);
    };

    enc(em1, rp1, d21, 0, zout);
    enc(em2, rp2, d22, 9, zout + NN);
}

// Round 13
// 1820.446 us; speedup vs baseline: 1.3626x; 1.0067x over previous
//
#include <hip/hip_runtime.h>
#include <math.h>
#include <stdint.h>
#include <limits.h>

#define NN 100000
#define NE 1600000
#define HH 64
#define THF 0.7f
#define ATTTH 0.2f
#define EPSF 1e-5f
#define SCAN_B ((NN + 255) / 256)   // 391
#define EM2CAP 1000000
#define NBE 2048
#define NHTOT ((size_t)NN * 64)
#define NB_ROW4C (NN / 4)

typedef unsigned long long u64;

// ---------------- setup ----------------

__global__ void hist_k(const int* __restrict__ dst, const int* __restrict__ mask,
                       int* __restrict__ cnt_all, int* __restrict__ cnt_mask) {
    int e = blockIdx.x * 256 + threadIdx.x;
    if (e >= NE) return;
    int d = dst[e];
    atomicAdd(&cnt_all[d], 1);
    if (mask[e]) atomicAdd(&cnt_mask[d], 1);
}

__global__ void deg_inv2_k(const int* __restrict__ cnt1, const int* __restrict__ cnt2,
                           float* __restrict__ dis1, float* __restrict__ d21,
                           float* __restrict__ dis2m, float* __restrict__ d22) {
    int i = blockIdx.x * 256 + threadIdx.x;
    if (i < NN) {
        float dg1 = (float)(cnt1[i] + 1);
        dis1[i] = 1.0f / sqrtf(dg1);
        d21[i] = 1.0f / dg1;
        float dg2 = (float)(cnt2[i] + 1);
        dis2m[i] = 1.0f / sqrtf(dg2);
        d22[i] = 1.0f / dg2;
    }
}

__global__ void scan1_k(const int* __restrict__ counts, int* __restrict__ rp,
                        int* __restrict__ bsum) {
    __shared__ int ls[256];
    int i = blockIdx.x * 256 + threadIdx.x;
    int v = (i < NN) ? counts[i] : 0;
    ls[threadIdx.x] = v;
    __syncthreads();
    for (int off = 1; off < 256; off <<= 1) {
        int t = (threadIdx.x >= off) ? ls[threadIdx.x - off] : 0;
        __syncthreads();
        ls[threadIdx.x] += t;
        __syncthreads();
    }
    if (i < NN) rp[i] = ls[threadIdx.x] - v;
    if (threadIdx.x == 255) bsum[blockIdx.x] = ls[255];
}

__global__ __launch_bounds__(512) void scan2_k(int* __restrict__ bsum,
                                               int* __restrict__ rp) {
    __shared__ int ls[512];
    int i = threadIdx.x;
    int v = (i < SCAN_B) ? bsum[i] : 0;
    ls[i] = v;
    __syncthreads();
    for (int off = 1; off < 512; off <<= 1) {
        int t = (i >= off) ? ls[i - off] : 0;
        __syncthreads();
        ls[i] += t;
        __syncthreads();
    }
    if (i < SCAN_B) bsum[i] = ls[i] - v;
    if (i == SCAN_B - 1) rp[NN] = ls[i];
}

__global__ void scan3_k(int* __restrict__ rp, const int* __restrict__ bsum) {
    int i = blockIdx.x * 256 + threadIdx.x;
    if (i < NN) rp[i] += bsum[blockIdx.x];
}

// emA[p] = (src<<1)|mask (all edges); emB[p] = src (masked edges only)
__global__ void csr_fill_k(const int* __restrict__ src, const int* __restrict__ dst,
                           const int* __restrict__ mask,
                           const int* __restrict__ rp1, const int* __restrict__ rp2,
                           int* __restrict__ cur1, int* __restrict__ cur2,
                           int* __restrict__ emA, int* __restrict__ emB) {
    int e = blockIdx.x * 256 + threadIdx.x;
    if (e >= NE) return;
    int s = src[e], d = dst[e];
    int mk = mask[e] & 1;
    int p1 = rp1[d] + atomicAdd(&cur1[d], 1);
    emA[p1] = (s << 1) | mk;
    if (mk) {
        int p2 = rp2[d] + atomicAdd(&cur2[d], 1);
        emB[p2] = s;
    }
}

// sort int segment ascending (keys may duplicate; value IS the key)
__device__ void seg_sort_node(int* __restrict__ em, int beg, int end,
                              int* skey, int lane) {
    int L = end - beg;
    if (L <= 1) return;
    if (L <= 64) {
        int k = INT_MAX;
        if (lane < L) k = em[beg + lane];
        for (int r = 0; r < L; r++) {
            int mn = k;
#pragma unroll
            for (int off = 32; off > 0; off >>= 1)
                mn = min(mn, __shfl_xor(mn, off, 64));
            if (lane == 0) em[beg + r] = mn;
            u64 msk = __ballot(k == mn);
            int leader = (int)__ffsll((unsigned long long)msk) - 1;
            if (lane == leader) k = INT_MAX;
        }
    } else if (L <= 512) {
        for (int i = lane; i < L; i += 64) skey[i] = em[beg + i];
        for (int it = 0; it < L; it++) {
            int par = it & 1;
            for (int p = par + 2 * lane; p + 1 < L; p += 128) {
                int ka = skey[p], kb = skey[p + 1];
                if (kb < ka) { skey[p] = kb; skey[p + 1] = ka; }
            }
        }
        for (int i = lane; i < L; i += 64) em[beg + i] = skey[i];
    }
}

__global__ __launch_bounds__(256) void seg_sort2_k(int* __restrict__ emA,
                                                   const int* __restrict__ rp1,
                                                   int* __restrict__ emB,
                                                   const int* __restrict__ rp2) {
    __shared__ int skey[4][512];
    int tid = threadIdx.x, lane = tid & 63, w = tid >> 6;
    int bid = blockIdx.x;
    if (bid < NB_ROW4C) {
        int n = bid * 4 + w;
        seg_sort_node(emA, rp1[n], rp1[n + 1], skey[w], lane);
    } else {
        int n = (bid - NB_ROW4C) * 4 + w;
        seg_sort_node(emB, rp2[n], rp2[n + 1], skey[w], lane);
    }
}

// ---------------- GEMM (float input, layer 0 only) ----------------

__global__ __launch_bounds__(256) void gemm_k(const float* __restrict__ in,
                                              const float* __restrict__ W,
                                              float* __restrict__ xw) {
    __shared__ float sW[64 * 64];
    __shared__ float sx[32 * 65];
    int tid = threadIdx.x;
    const float4* W4 = (const float4*)W;
    float4* sW4 = (float4*)sW;
    for (int i = tid; i < 1024; i += 256) sW4[i] = W4[i];
    const float* inb = in + (size_t)blockIdx.x * 2048;
    for (int i = tid; i < 2048; i += 256) sx[(i >> 6) * 65 + (i & 63)] = inb[i];
    __syncthreads();
    int cg = tid & 15, rr = tid >> 4;
    float a0 = 0, a1 = 0, a2 = 0, a3 = 0, c0 = 0, c1 = 0, c2 = 0, c3 = 0;
#pragma unroll
    for (int k = 0; k < 64; k++) {
        float4 wv = *(const float4*)&sW[k * 64 + cg * 4];
        float xa = sx[rr * 65 + k];
        float xb = sx[(rr + 16) * 65 + k];
        a0 += xa * wv.x; a1 += xa * wv.y; a2 += xa * wv.z; a3 += xa * wv.w;
        c0 += xb * wv.x; c1 += xb * wv.y; c2 += xb * wv.z; c3 += xb * wv.w;
    }
    size_t r0 = (size_t)(blockIdx.x * 32 + rr) * 64 + cg * 4;
    size_t r1 = (size_t)(blockIdx.x * 32 + rr + 16) * 64 + cg * 4;
    *(float4*)&xw[r0] = make_float4(a0, a1, a2, a3);
    *(float4*)&xw[r1] = make_float4(c0, c1, c2, c3);
}

// ---------------- standalone bit GEMM (path B) ----------------

__global__ __launch_bounds__(256) void bitgemm_k(const u64* __restrict__ bits,
                                                 const float* __restrict__ W,
                                                 float* __restrict__ xw) {
    __shared__ float sW[64 * 64];
    int tid = threadIdx.x;
    const float4* W4 = (const float4*)W;
    float4* sW4 = (float4*)sW;
    for (int i = tid; i < 1024; i += 256) sW4[i] = W4[i];
    __syncthreads();
    int lane = tid & 63, w = tid >> 6;
    int n0 = blockIdx.x * 64 + w * 16;
    for (int t = 0; t < 16; t++) {
        int n = n0 + t;
        if (n >= NN) return;
        u64 m = bits[n];
        float acc = 0.0f;
        while (m) {
            int k = (int)__builtin_ctzll(m);
            m &= m - 1;
            acc += sW[k * 64 + lane];
        }
        xw[(size_t)n * 64 + lane] = acc;
    }
}

// ---------------- gathers: 4B meta, on-the-fly norms ----------------
// norm = dis[src]*dis[n] (same expression csr_fill previously stored -> same f32).
// Per-node single sequential accumulator, ascending-src order (R12 numerics).

__global__ __launch_bounds__(256) void gather_stats_k(const float* __restrict__ xw,
                                                      const int* __restrict__ em,
                                                      int shift,
                                                      const float* __restrict__ dis,
                                                      const int* __restrict__ rp,
                                                      const float* __restrict__ d2i,
                                                      const float* __restrict__ bias,
                                                      float* __restrict__ out,
                                                      double* __restrict__ part) {
    int tid = threadIdx.x, lane = tid & 63, w = tid >> 6;
    double ps = 0.0, pq = 0.0;
    for (int n = blockIdx.x * 4 + w; n < NN; n += NBE * 4) {
        int beg = rp[n], end = rp[n + 1];
        float disn = dis[n];
        float self = d2i[n] * xw[(size_t)n * 64 + lane] + bias[lane];
        float acc = 0.0f;
        for (int base = beg; base < end; base += 64) {
            int cnt = min(64, end - base);
            int m = 0; float nl = 0.0f;
            if (base + lane < end) {
                m = em[base + lane];
                nl = dis[m >> shift] * disn;
            }
            int j = 0;
            for (; j + 8 <= cnt; j += 8) {
#pragma unroll
                for (int u = 0; u < 8; u++) {
                    int s = __shfl(m, j + u, 64) >> shift;
                    float nv = __shfl(nl, j + u, 64);
                    acc += nv * xw[(size_t)s * 64 + lane];
                }
            }
            for (; j < cnt; j++) {
                int s = __shfl(m, j, 64) >> shift;
                float nv = __shfl(nl, j, 64);
                acc += nv * xw[(size_t)s * 64 + lane];
            }
        }
        float o = acc + self;
        out[(size_t)n * 64 + lane] = o;
        ps += (double)o;
        pq += (double)o * (double)o;
    }
    __shared__ double ls[4][64], lq[4][64];
    ls[w][lane] = ps; lq[w][lane] = pq;
    __syncthreads();
    if (tid < 64) {
        double a = ls[0][tid] + ls[1][tid] + ls[2][tid] + ls[3][tid];
        double b = lq[0][tid] + lq[1][tid] + lq[2][tid] + lq[3][tid];
        part[(size_t)blockIdx.x * 128 + tid] = a;
        part[(size_t)blockIdx.x * 128 + 64 + tid] = b;
    }
}

__global__ __launch_bounds__(256) void gather2_stats_k(const float* __restrict__ xa,
                                                       const float* __restrict__ xb,
                                                       const int* __restrict__ em,
                                                       int shift,
                                                       const float* __restrict__ dis,
                                                       const int* __restrict__ rp,
                                                       const float* __restrict__ d2i,
                                                       const float* __restrict__ ba,
                                                       const float* __restrict__ bb,
                                                       float* __restrict__ oa,
                                                       float* __restrict__ ob,
                                                       double* __restrict__ part) {
    int tid = threadIdx.x, lane = tid & 63, w = tid >> 6;
    double sA = 0.0, qA = 0.0, sB = 0.0, qB = 0.0;
    for (int n = blockIdx.x * 4 + w; n < NN; n += NBE * 4) {
        int beg = rp[n], end = rp[n + 1];
        float disn = dis[n];
        float selfa = d2i[n] * xa[(size_t)n * 64 + lane] + ba[lane];
        float selfb = d2i[n] * xb[(size_t)n * 64 + lane] + bb[lane];
        float acca = 0.0f, accb = 0.0f;
        for (int base = beg; base < end; base += 64) {
            int cnt = min(64, end - base);
            int m = 0; float nl = 0.0f;
            if (base + lane < end) {
                m = em[base + lane];
                nl = dis[m >> shift] * disn;
            }
            for (int j = 0; j < cnt; j++) {
                int s = __shfl(m, j, 64) >> shift;
                float nv = __shfl(nl, j, 64);
                acca += nv * xa[(size_t)s * 64 + lane];
                accb += nv * xb[(size_t)s * 64 + lane];
            }
        }
        size_t o = (size_t)n * 64 + lane;
        float va = acca + selfa;
        float vb = accb + selfb;
        oa[o] = va;
        ob[o] = vb;
        sA += (double)va; qA += (double)va * (double)va;
        sB += (double)vb; qB += (double)vb * (double)vb;
    }
    __shared__ double l1[4][64], l2[4][64], l3[4][64], l4[4][64];
    l1[w][lane] = sA; l2[w][lane] = qA; l3[w][lane] = sB; l4[w][lane] = qB;
    __syncthreads();
    if (tid < 64) {
        size_t o = (size_t)blockIdx.x * 256;
        part[o + tid]       = l1[0][tid] + l1[1][tid] + l1[2][tid] + l1[3][tid];
        part[o + 64 + tid]  = l2[0][tid] + l2[1][tid] + l2[2][tid] + l2[3][tid];
        part[o + 128 + tid] = l3[0][tid] + l3[1][tid] + l3[2][tid] + l3[3][tid];
        part[o + 192 + tid] = l4[0][tid] + l4[1][tid] + l4[2][tid] + l4[3][tid];
    }
}

__global__ __launch_bounds__(256) void gather3_stats_k(const float* __restrict__ xa,
                                                       const float* __restrict__ xb,
                                                       const float* __restrict__ xc,
                                                       const int* __restrict__ em,
                                                       int shift,
                                                       const float* __restrict__ dis,
                                                       const int* __restrict__ rp,
                                                       const float* __restrict__ d2i,
                                                       const float* __restrict__ ba,
                                                       const float* __restrict__ bb,
                                                       const float* __restrict__ bc,
                                                       float* __restrict__ oa,
                                                       float* __restrict__ ob,
                                                       float* __restrict__ oc,
                                                       double* __restrict__ part) {
    int tid = threadIdx.x, lane = tid & 63, w = tid >> 6;
    double sA = 0.0, qA = 0.0, sB = 0.0, qB = 0.0, sC = 0.0, qC = 0.0;
    for (int n = blockIdx.x * 4 + w; n < NN; n += NBE * 4) {
        int beg = rp[n], end = rp[n + 1];
        float disn = dis[n];
        float selfa = d2i[n] * xa[(size_t)n * 64 + lane] + ba[lane];
        float selfb = d2i[n] * xb[(size_t)n * 64 + lane] + bb[lane];
        float selfc = d2i[n] * xc[(size_t)n * 64 + lane] + bc[lane];
        float acca = 0.0f, accb = 0.0f, accc = 0.0f;
        for (int base = beg; base < end; base += 64) {
            int cnt = min(64, end - base);
            int m = 0; float nl = 0.0f;
            if (base + lane < end) {
                m = em[base + lane];
                nl = dis[m >> shift] * disn;
            }
            for (int j = 0; j < cnt; j++) {
                int s = __shfl(m, j, 64) >> shift;
                float nv = __shfl(nl, j, 64);
                acca += nv * xa[(size_t)s * 64 + lane];
                accb += nv * xb[(size_t)s * 64 + lane];
                accc += nv * xc[(size_t)s * 64 + lane];
            }
        }
        size_t o = (size_t)n * 64 + lane;
        float va = acca + selfa;
        float vb = accb + selfb;
        float vc = accc + selfc;
        oa[o] = va; ob[o] = vb; oc[o] = vc;
        sA += (double)va; qA += (double)va * (double)va;
        sB += (double)vb; qB += (double)vb * (double)vb;
        sC += (double)vc; qC += (double)vc * (double)vc;
    }
    __shared__ double l1[4][64], l2[4][64], l3[4][64], l4[4][64], l5[4][64], l6[4][64];
    l1[w][lane] = sA; l2[w][lane] = qA; l3[w][lane] = sB;
    l4[w][lane] = qB; l5[w][lane] = sC; l6[w][lane] = qC;
    __syncthreads();
    if (tid < 64) {
        size_t o = (size_t)blockIdx.x * 384;
        part[o + tid]       = l1[0][tid] + l1[1][tid] + l1[2][tid] + l1[3][tid];
        part[o + 64 + tid]  = l2[0][tid] + l2[1][tid] + l2[2][tid] + l2[3][tid];
        part[o + 128 + tid] = l3[0][tid] + l3[1][tid] + l3[2][tid] + l3[3][tid];
        part[o + 192 + tid] = l4[0][tid] + l4[1][tid] + l4[2][tid] + l4[3][tid];
        part[o + 256 + tid] = l5[0][tid] + l5[1][tid] + l5[2][tid] + l5[3][tid];
        part[o + 320 + tid] = l6[0][tid] + l6[1][tid] + l6[2][tid] + l6[3][tid];
    }
}

// shared L0: one emA traversal -> enc1 aggregation (all edges, norm1) and
// enc2 aggregation (mask-bit edges, norm2), sharing every xw row load.
// Skipped terms add exactly 0.0f (no-op); enc2 order = ascending src (same as emB).
__global__ __launch_bounds__(256) void sharedL0_k(const float* __restrict__ xw,
                                                  const int* __restrict__ em,
                                                  const int* __restrict__ rp,
                                                  const float* __restrict__ dis1,
                                                  const float* __restrict__ dis2m,
                                                  const float* __restrict__ d21,
                                                  const float* __restrict__ d22,
                                                  const float* __restrict__ bias,
                                                  float* __restrict__ o1,
                                                  float* __restrict__ o2,
                                                  double* __restrict__ part) {
    int tid = threadIdx.x, lane = tid & 63, w = tid >> 6;
    double sA = 0.0, qA = 0.0, sB = 0.0, qB = 0.0;
    for (int n = blockIdx.x * 4 + w; n < NN; n += NBE * 4) {
        int beg = rp[n], end = rp[n + 1];
        float disn1 = dis1[n], disn2 = dis2m[n];
        float xv = xw[(size_t)n * 64 + lane];
        float self1 = d21[n] * xv + bias[lane];
        float self2 = d22[n] * xv + bias[lane];
        float acc1 = 0.0f, acc2 = 0.0f;
        for (int base = beg; base < end; base += 64) {
            int cnt = min(64, end - base);
            int m = 0; float nl1 = 0.0f, nl2 = 0.0f;
            if (base + lane < end) {
                m = em[base + lane];
                int s = m >> 1;
                nl1 = dis1[s] * disn1;
                nl2 = dis2m[s] * disn2;
            }
            for (int j = 0; j < cnt; j++) {
                int key = __shfl(m, j, 64);
                int s = key >> 1;
                float n1 = __shfl(nl1, j, 64);
                float n2 = __shfl(nl2, j, 64);
                float v = xw[(size_t)s * 64 + lane];
                acc1 += n1 * v;
                acc2 += (key & 1) ? n2 * v : 0.0f;
            }
        }
        size_t o = (size_t)n * 64 + lane;
        float v1 = acc1 + self1;
        float v2 = acc2 + self2;
        o1[o] = v1;
        o2[o] = v2;
        sA += (double)v1; qA += (double)v1 * (double)v1;
        sB += (double)v2; qB += (double)v2 * (double)v2;
    }
    __shared__ double l1[4][64], l2[4][64], l3[4][64], l4[4][64];
    l1[w][lane] = sA; l2[w][lane] = qA; l3[w][lane] = sB; l4[w][lane] = qB;
    __syncthreads();
    if (tid < 64) {
        size_t o = (size_t)blockIdx.x * 256;
        part[o + tid]       = l1[0][tid] + l1[1][tid] + l1[2][tid] + l1[3][tid];
        part[o + 64 + tid]  = l2[0][tid] + l2[1][tid] + l2[2][tid] + l2[3][tid];
        part[o + 128 + tid] = l3[0][tid] + l3[1][tid] + l3[2][tid] + l3[3][tid];
        part[o + 192 + tid] = l4[0][tid] + l4[1][tid] + l4[2][tid] + l4[3][tid];
    }
}

// ---------------- deterministic partial reduces ----------------

__global__ __launch_bounds__(256) void bn_red_k(const double* __restrict__ part,
                                                double* __restrict__ st) {
    __shared__ double tr[256];
    int t = threadIdx.x, c = blockIdx.x;
    double s = 0.0;
    for (int b = t; b < NBE; b += 256) s += part[(size_t)b * 128 + c];
    tr[t] = s;
    __syncthreads();
    for (int off = 128; off > 0; off >>= 1) {
        if (t < off) tr[t] += tr[t + off];
        __syncthreads();
    }
    if (t == 0) st[c] = tr[0];
}

__global__ __launch_bounds__(256) void bn_red2_k(const double* __restrict__ part,
                                                 double* __restrict__ sta,
                                                 double* __restrict__ stb) {
    __shared__ double tr[256];
    int t = threadIdx.x, c = blockIdx.x;
    double s = 0.0;
    for (int b = t; b < NBE; b += 256) s += part[(size_t)b * 256 + c];
    tr[t] = s;
    __syncthreads();
    for (int off = 128; off > 0; off >>= 1) {
        if (t < off) tr[t] += tr[t + off];
        __syncthreads();
    }
    if (t == 0) {
        if (c < 128) sta[c] = tr[0];
        else stb[c - 128] = tr[0];
    }
}

__global__ __launch_bounds__(256) void bn_red3_k(const double* __restrict__ part,
                                                 double* __restrict__ sta,
                                                 double* __restrict__ stb,
                                                 double* __restrict__ stc) {
    __shared__ double tr[256];
    int t = threadIdx.x, c = blockIdx.x;
    double s = 0.0;
    for (int b = t; b < NBE; b += 256) s += part[(size_t)b * 384 + c];
    tr[t] = s;
    __syncthreads();
    for (int off = 128; off > 0; off >>= 1) {
        if (t < off) tr[t] += tr[t + off];
        __syncthreads();
    }
    if (t == 0) {
        if (c < 128) sta[c] = tr[0];
        else if (c < 256) stb[c - 128] = tr[0];
        else stc[c - 256] = tr[0];
    }
}

__device__ inline void bn_ss(const double* __restrict__ st, const float* __restrict__ gam,
                             const float* __restrict__ bet, int c,
                             float* __restrict__ ssc, float* __restrict__ ssh) {
    double m = st[c] * (1.0 / NN);
    double v = st[64 + c] * (1.0 / NN) - m * m;
    float scale = (float)((double)gam[c] / sqrt(v + (double)EPSF));
    ssc[c] = scale;
    ssh[c] = bet[c] - (float)m * scale;
}

// ---------------- fused spike + bitgemm kernels ----------------

__global__ __launch_bounds__(256) void lif_bitgemm_k(const float* __restrict__ G,
                                                     const double* __restrict__ st,
                                                     const float* __restrict__ gam,
                                                     const float* __restrict__ bet,
                                                     float* __restrict__ vconv,
                                                     const float* __restrict__ W,
                                                     float* __restrict__ xw) {
    __shared__ float sW[4096];
    __shared__ float ssc[64], ssh[64];
    int tid = threadIdx.x;
    if (tid < 64) bn_ss(st, gam, bet, tid, ssc, ssh);
    const float4* W4 = (const float4*)W;
    float4* sW4 = (float4*)sW;
    for (int i = tid; i < 1024; i += 256) sW4[i] = W4[i];
    __syncthreads();
    int lane = tid & 63;
    size_t i = (size_t)blockIdx.x * 256 + tid;
    float v = vconv[i] + (G[i] * ssc[lane] + ssh[lane]);
    bool sp = (v - THF >= 0.0f);
    u64 m = __ballot(sp);
    vconv[i] = sp ? 0.0f : v;
    float acc = 0.0f;
    while (m) {
        int k = (int)__builtin_ctzll(m);
        m &= m - 1;
        acc += sW[k * 64 + lane];
    }
    xw[i] = acc;
}

__global__ __launch_bounds__(256) void spike_bitgemm_k(const float* __restrict__ G,
                                                       const double* __restrict__ st,
                                                       const float* __restrict__ gam,
                                                       const float* __restrict__ bet,
                                                       float* __restrict__ x3,
                                                       const float* __restrict__ W,
                                                       float* __restrict__ xw) {
    __shared__ float sW[4096];
    __shared__ float ssc[64], ssh[64];
    int tid = threadIdx.x;
    if (tid < 64) bn_ss(st, gam, bet, tid, ssc, ssh);
    const float4* W4 = (const float4*)W;
    float4* sW4 = (float4*)sW;
    for (int i = tid; i < 1024; i += 256) sW4[i] = W4[i];
    __syncthreads();
    int lane = tid & 63;
    size_t i = (size_t)blockIdx.x * 256 + tid;
    float xv = G[i] * ssc[lane] + ssh[lane];
    x3[i] = xv;
    u64 m = __ballot(xv - THF >= 0.0f);
    float acc = 0.0f;
    while (m) {
        int k = (int)__builtin_ctzll(m);
        m &= m - 1;
        acc += sW[k * 64 + lane];
    }
    xw[i] = acc;
}

__global__ __launch_bounds__(256) void lif_bitgemm2_k(const float* __restrict__ F,
                                                      const double* __restrict__ st,
                                                      const float* __restrict__ gam,
                                                      const float* __restrict__ bet,
                                                      float* __restrict__ vconv,
                                                      float* __restrict__ x4,
                                                      u64* __restrict__ sbits,
                                                      const float* __restrict__ Wa,
                                                      const float* __restrict__ Wb,
                                                      float* __restrict__ xwa,
                                                      float* __restrict__ xwb) {
    __shared__ float sA[4096], sB[4096];
    __shared__ float ssc[64], ssh[64];
    int tid = threadIdx.x;
    if (tid < 64) bn_ss(st, gam, bet, tid, ssc, ssh);
    const float4* A4 = (const float4*)Wa;
    const float4* B4 = (const float4*)Wb;
    float4* sA4 = (float4*)sA;
    float4* sB4 = (float4*)sB;
    for (int i = tid; i < 1024; i += 256) { sA4[i] = A4[i]; sB4[i] = B4[i]; }
    __syncthreads();
    int lane = tid & 63;
    size_t i = (size_t)blockIdx.x * 256 + tid;
    float xv = F[i] * ssc[lane] + ssh[lane];
    x4[i] = xv;
    float v = vconv[i] + xv;
    bool sp = (v - THF >= 0.0f);
    u64 m = __ballot(sp);
    vconv[i] = sp ? 0.0f : v;
    if (lane == 0) sbits[i >> 6] = m;
    float a = 0.0f, b = 0.0f;
    while (m) {
        int k = (int)__builtin_ctzll(m);
        m &= m - 1;
        a += sA[k * 64 + lane];
        b += sB[k * 64 + lane];
    }
    xwa[i] = a;
    xwb[i] = b;
}

__global__ __launch_bounds__(256) void lif_bitgemm3_k(const float* __restrict__ F,
                                                      const double* __restrict__ st,
                                                      const float* __restrict__ gam,
                                                      const float* __restrict__ bet,
                                                      float* __restrict__ vconv,
                                                      float* __restrict__ x4,
                                                      const float* __restrict__ Wa,
                                                      const float* __restrict__ Wb,
                                                      const float* __restrict__ Wc,
                                                      float* __restrict__ xwa,
                                                      float* __restrict__ xwb,
                                                      float* __restrict__ xwc) {
    __shared__ float sA[4096], sB[4096], sC[4096];
    __shared__ float ssc[64], ssh[64];
    int tid = threadIdx.x;
    if (tid < 64) bn_ss(st, gam, bet, tid, ssc, ssh);
    const float4* A4 = (const float4*)Wa;
    const float4* B4 = (const float4*)Wb;
    const float4* C4 = (const float4*)Wc;
    float4* sA4 = (float4*)sA;
    float4* sB4 = (float4*)sB;
    float4* sC4 = (float4*)sC;
    for (int i = tid; i < 1024; i += 256) { sA4[i] = A4[i]; sB4[i] = B4[i]; sC4[i] = C4[i]; }
    __syncthreads();
    int lane = tid & 63;
    size_t i = (size_t)blockIdx.x * 256 + tid;
    float xv = F[i] * ssc[lane] + ssh[lane];
    x4[i] = xv;
    float v = vconv[i] + xv;
    bool sp = (v - THF >= 0.0f);
    u64 m = __ballot(sp);
    vconv[i] = sp ? 0.0f : v;
    float a = 0.0f, b = 0.0f, c = 0.0f;
    while (m) {
        int k = (int)__builtin_ctzll(m);
        m &= m - 1;
        a += sA[k * 64 + lane];
        b += sB[k * 64 + lane];
        c += sC[k * 64 + lane];
    }
    xwa[i] = a;
    xwb[i] = b;
    xwc[i] = c;
}

__global__ __launch_bounds__(256) void qkv_att_bitgemm_k(const float* __restrict__ Gq,
                                                         const float* __restrict__ Gk,
                                                         const float* __restrict__ Gv,
                                                         const double* __restrict__ st4,
                                                         const double* __restrict__ st5,
                                                         const double* __restrict__ st6,
                                                         const float* __restrict__ gam4,
                                                         const float* __restrict__ bet4,
                                                         const float* __restrict__ gam5,
                                                         const float* __restrict__ bet5,
                                                         const float* __restrict__ gam6,
                                                         const float* __restrict__ bet6,
                                                         const float* __restrict__ W,
                                                         float* __restrict__ xw) {
    __shared__ float sW[4096];
    __shared__ float sc4[64], sh4[64], sc5[64], sh5[64], sc6[64], sh6[64];
    int tid = threadIdx.x;
    if (tid < 64) {
        bn_ss(st4, gam4, bet4, tid, sc4, sh4);
        bn_ss(st5, gam5, bet5, tid, sc5, sh5);
        bn_ss(st6, gam6, bet6, tid, sc6, sh6);
    }
    const float4* W4 = (const float4*)W;
    float4* sW4 = (float4*)sW;
    for (int i = tid; i < 1024; i += 256) sW4[i] = W4[i];
    __syncthreads();
    int lane = tid & 63;
    size_t i = (size_t)blockIdx.x * 256 + tid;
    bool qb = (Gq[i] * sc4[lane] + sh4[lane] - THF >= 0.0f);
    bool kb = (Gk[i] * sc5[lane] + sh5[lane] - THF >= 0.0f);
    bool vb = (Gv[i] * sc6[lane] + sh6[lane] - THF >= 0.0f);
    int pc = __popcll(__ballot(qb && kb));
    bool qs = ((float)pc * (1.0f / 64.0f) - ATTTH >= 0.0f);
    u64 m = __ballot(vb && qs);
    float acc = 0.0f;
    while (m) {
        int k = (int)__builtin_ctzll(m);
        m &= m - 1;
        acc += sW[k * 64 + lane];
    }
    xw[i] = acc;
}

// ---------------- remaining elementwise (with fused stats) ----------------

__global__ __launch_bounds__(256) void bn_add_stats_k(const float* __restrict__ G,
                                                      const double* __restrict__ st,
                                                      const float* __restrict__ gam,
                                                      const float* __restrict__ bet,
                                                      const float* __restrict__ x3,
                                                      float* __restrict__ F,
                                                      double* __restrict__ part) {
    __shared__ float ssc[64], ssh[64];
    int tid = threadIdx.x;
    if (tid < 64) bn_ss(st, gam, bet, tid, ssc, ssh);
    __syncthreads();
    int c = tid & 63;
    double s = 0.0, s2 = 0.0;
    for (size_t i = (size_t)blockIdx.x * 256 + tid; i < NHTOT; i += (size_t)NBE * 256) {
        float f = (G[i] * ssc[c] + ssh[c]) + x3[i];
        F[i] = f;
        s += (double)f;
        s2 += (double)f * (double)f;
    }
    __shared__ double ls[256], lq[256];
    ls[tid] = s; lq[tid] = s2;
    __syncthreads();
    if (tid < 64) {
        double a = ls[tid] + ls[tid + 64] + ls[tid + 128] + ls[tid + 192];
        double b = lq[tid] + lq[tid + 64] + lq[tid + 128] + lq[tid + 192];
        part[(size_t)blockIdx.x * 128 + tid] = a;
        part[(size_t)blockIdx.x * 128 + 64 + tid] = b;
    }
}

__global__ __launch_bounds__(256) void bn_scale_add_stats_k(const float* __restrict__ G,
                                                            const double* __restrict__ st,
                                                            const float* __restrict__ gam,
                                                            const float* __restrict__ bet,
                                                            const float* __restrict__ x4,
                                                            float* __restrict__ tmp2,
                                                            double* __restrict__ part) {
    __shared__ float ssc[64], ssh[64];
    int tid = threadIdx.x;
    if (tid < 64) bn_ss(st, gam, bet, tid, ssc, ssh);
    __syncthreads();
    int c = tid & 63;
    double s = 0.0, s2 = 0.0;
    for (size_t i = (size_t)blockIdx.x * 256 + tid; i < NHTOT; i += (size_t)NBE * 256) {
        float f = x4[i] + 0.125f * (G[i] * ssc[c] + ssh[c]);
        tmp2[i] = f;
        s += (double)f;
        s2 += (double)f * (double)f;
    }
    __shared__ double ls[256], lq[256];
    ls[tid] = s; lq[tid] = s2;
    __syncthreads();
    if (tid < 64) {
        double a = ls[tid] + ls[tid + 64] + ls[tid + 128] + ls[tid + 192];
        double b = lq[tid] + lq[tid + 64] + lq[tid + 128] + lq[tid + 192];
        part[(size_t)blockIdx.x * 128 + tid] = a;
        part[(size_t)blockIdx.x * 128 + 64 + tid] = b;
    }
}

__global__ __launch_bounds__(256) void decode_k(const float* __restrict__ tmp2,
                                                const double* __restrict__ st,
                                                const float* __restrict__ gam,
                                                const float* __restrict__ bet,
                                                const float* __restrict__ wrow,
                                                float* __restrict__ z) {
    __shared__ float ssc[64], ssh[64];
    int tid = threadIdx.x;
    if (tid < 64) bn_ss(st, gam, bet, tid, ssc, ssh);
    __syncthreads();
    int lane = tid & 63;
    int row = blockIdx.x * 4 + (tid >> 6);
    float sv = tmp2[(size_t)row * 64 + lane] * ssc[lane] + ssh[lane];
    float p = sv * wrow[lane];
#pragma unroll
    for (int off = 32; off > 0; off >>= 1) p += __shfl_xor(p, off, 64);
    if (lane == 0) z[row] = p;
}

__global__ void wrow_k(const float* __restrict__ W_lin, float* __restrict__ wrow) {
    int h = threadIdx.x;
    if (h >= 64) return;
    float s = 0.0f;
    for (int j = 0; j < 64; j++) s += W_lin[h * 64 + j];
    wrow[h] = s;
}

// ---------------- host driver ----------------

extern "C" void kernel_launch(void* const* d_in, const int* in_sizes, int n_in,
                              void* d_out, int out_size, void* d_ws, size_t ws_size,
                              hipStream_t stream) {
    const float* x    = (const float*)d_in[0];
    const int* eidx   = (const int*)d_in[1];
    const int* emask  = (const int*)d_in[2];
    const float* Wg   = (const float*)d_in[3];
    const float* bg   = (const float*)d_in[4];
    const float* bng  = (const float*)d_in[5];
    const float* bnb  = (const float*)d_in[6];
    const float* Wlin = (const float*)d_in[7];
    float* zout = (float*)d_out;

    const int* srcp = eidx;
    const int* dstp = eidx + NE;
    const size_t NH = (size_t)NN * HH;

    // ---- workspace layout ----
    float* ws = (float*)d_ws;
    size_t off = 0;
    float* P1 = ws + off; off += NH;
    float* P2 = ws + off; off += NH;
    float* P3 = ws + off; off += NH;
    float* P4 = ws + off; off += NH;
    float* P5 = ws + off; off += NH;
    float* vconv = ws + off; off += NH;
    int* emA = (int*)(ws + off); off += NE;
    int* emB = (int*)(ws + off); off += EM2CAP;
    u64* sbits = (u64*)(ws + off); off += 2 * (size_t)NN;
    double* part = (double*)(ws + off); off += 2 * (size_t)NBE * 384;
    double* stats = (double*)(ws + off); off += 2 * 18 * 128;
    float* dis1 = ws + off; off += NN;
    float* d21  = ws + off; off += NN;
    float* dis2m = ws + off; off += NN;
    float* d22  = ws + off; off += NN;
    float* wrow = ws + off; off += 64;
    int* rp1 = (int*)(ws + off); off += NN + 2;
    int* rp2 = (int*)(ws + off); off += NN + 2;
    int* cnt1 = (int*)(ws + off); off += NN;
    int* cnt2 = (int*)(ws + off); off += NN;
    int* cur1 = (int*)(ws + off); off += NN;
    int* cur2 = (int*)(ws + off); off += NN;
    int* bsum = (int*)(ws + off); off += SCAN_B + 2;
    // tier gating
    float* P6 = ws + off; off += NH;
    float* P7 = ws + off; off += NH;
    size_t needA = off * 4;
    float* P8 = ws + off; off += NH;
    size_t needA2 = off * 4;
    const bool tA = (ws_size >= needA);
    const bool tA2 = (ws_size >= needA2);

    hipMemsetAsync(cnt1, 0, 4 * NN * sizeof(int), stream);
    hipMemsetAsync(vconv, 0, NH * sizeof(float), stream);

    const int NB_EDGE = NE / 256;
    const int NB_NODE = SCAN_B;
    const int NB_ROW4 = NN / 4;
    const int NB_GEMM = NN / 32;
    const int NB_BG   = (NN + 63) / 64;

    wrow_k<<<1, 64, 0, stream>>>(Wlin, wrow);
    hist_k<<<NB_EDGE, 256, 0, stream>>>(dstp, emask, cnt1, cnt2);
    deg_inv2_k<<<NB_NODE, 256, 0, stream>>>(cnt1, cnt2, dis1, d21, dis2m, d22);
    scan1_k<<<NB_NODE, 256, 0, stream>>>(cnt1, rp1, bsum);
    scan2_k<<<1, 512, 0, stream>>>(bsum, rp1);
    scan3_k<<<NB_NODE, 256, 0, stream>>>(rp1, bsum);
    scan1_k<<<NB_NODE, 256, 0, stream>>>(cnt2, rp2, bsum);
    scan2_k<<<1, 512, 0, stream>>>(bsum, rp2);
    scan3_k<<<NB_NODE, 256, 0, stream>>>(rp2, bsum);
    csr_fill_k<<<NB_EDGE, 256, 0, stream>>>(srcp, dstp, emask, rp1, rp2,
                                            cur1, cur2, emA, emB);
    seg_sort2_k<<<2 * NB_ROW4, 256, 0, stream>>>(emA, rp1, emB, rp2);

    auto enc = [&](const int* em, int shift, const float* dis, const int* rp,
                   const float* d2i, int bnbase, float* zo, const float* G0pre) {
        auto ST = [&](int bni) { return stats + (bnbase + bni) * 128; };
        auto W = [&](int wi) { return Wg + wi * 4096; };
        auto BI = [&](int wi) { return bg + wi * 64; };
        auto GM = [&](int bi) { return bng + bi * 64; };
        auto BT = [&](int bi) { return bnb + bi * 64; };
        auto gatherS = [&](const float* xw, int wi, float* out, int bni) {
            gather_stats_k<<<NBE, 256, 0, stream>>>(xw, em, shift, dis, rp, d2i,
                                                    BI(wi), out, part);
            bn_red_k<<<128, 256, 0, stream>>>(part, ST(bni));
        };

        const float* G0 = G0pre;
        if (!G0) {
            gemm_k<<<NB_GEMM, 256, 0, stream>>>(x, W(0), P1);
            gatherS(P1, 0, P2, 0);
            G0 = P2;
        }
        lif_bitgemm_k<<<NB_ROW4, 256, 0, stream>>>(G0, ST(0), GM(0), BT(0),
                                                   vconv, W(1), P1);
        gatherS(P1, 1, P2, 1);
        spike_bitgemm_k<<<NB_ROW4, 256, 0, stream>>>(P2, ST(1), GM(1), BT(1),
                                                     P3, W(2), P1);
        gatherS(P1, 2, P2, 2);
        bn_add_stats_k<<<NBE, 256, 0, stream>>>(P2, ST(2), GM(2), BT(2), P3, P4, part);
        bn_red_k<<<128, 256, 0, stream>>>(part, ST(3));

        if (tA) {
            lif_bitgemm3_k<<<NB_ROW4, 256, 0, stream>>>(P4, ST(3), GM(3), BT(3),
                                                        vconv, P4,
                                                        W(3), W(4), W(5), P1, P2, P3);
            gather3_stats_k<<<NBE, 256, 0, stream>>>(P1, P2, P3, em, shift, dis, rp,
                                                     d2i, BI(3), BI(4), BI(5),
                                                     P5, P6, P7, part);
            bn_red3_k<<<384, 256, 0, stream>>>(part, ST(4), ST(5), ST(6));
            qkv_att_bitgemm_k<<<NB_ROW4, 256, 0, stream>>>(P5, P6, P7,
                                                           ST(4), ST(5), ST(6),
                                                           GM(4), BT(4), GM(5), BT(5),
                                                           GM(6), BT(6), W(6), P1);
        } else {
            lif_bitgemm2_k<<<NB_ROW4, 256, 0, stream>>>(P4, ST(3), GM(3), BT(3),
                                                        vconv, P4, sbits,
                                                        W(3), W(4), P1, P3);
            gather2_stats_k<<<NBE, 256, 0, stream>>>(P1, P3, em, shift, dis, rp, d2i,
                                                     BI(3), BI(4), P2, P5, part);
            bn_red2_k<<<256, 256, 0, stream>>>(part, ST(4), ST(5));
            bitgemm_k<<<NB_BG, 256, 0, stream>>>(sbits, W(5), P1);
            gatherS(P1, 5, P3, 6);
            qkv_att_bitgemm_k<<<NB_ROW4, 256, 0, stream>>>(P2, P5, P3,
                                                           ST(4), ST(5), ST(6),
                                                           GM(4), BT(4), GM(5), BT(5),
                                                           GM(6), BT(6), W(6), P1);
        }
        gatherS(P1, 6, P2, 7);
        bn_scale_add_stats_k<<<NBE, 256, 0, stream>>>(P2, ST(7), GM(7), BT(7),
                                                      P4, P3, part);
        bn_red_k<<<128, 256, 0, stream>>>(part, ST(8));
        decode_k<<<NB_ROW4, 256, 0, stream>>>(P3, ST(8), GM(8), BT(8), wrow, zo);
    };

    if (tA2) {
        // shared L0 traversal: both encs' first aggregation in one pass
        gemm_k<<<NB_GEMM, 256, 0, stream>>>(x, Wg, P1);
        sharedL0_k<<<NBE, 256, 0, stream>>>(P1, emA, rp1, dis1, dis2m, d21, d22,
                                            bg, P2, P8, part);
        bn_red2_k<<<256, 256, 0, stream>>>(part, stats + 0 * 128, stats + 9 * 128);
        enc(emA, 1, dis1, rp1, d21, 0, zout, P2);
        enc(emB, 0, dis2m, rp2, d22, 9, zout + NN, P8);
    } else {
        enc(emA, 1, dis1, rp1, d21, 0, zout, nullptr);
        enc(emB, 0, dis2m, rp2, d22, 9, zout + NN, nullptr);
    }
}